// Round 3
// baseline (1480.934 us; speedup 1.0000x reference)
//
#include <hip/hip_runtime.h>
#include <hip/hip_bf16.h>

// ---------------------------------------------------------------------------
// Net_83674552861196 — round 8: conv1 split 2 blocks/image (occupancy fix).
//  - Round 7 counters: conv1 Occupancy 41%, VALUBusy 45%, MfmaUtil 22% —
//    latency-bound at 4 blocks/CU (35 KB LDS). Split each image's 62 output
//    rows across 2 blocks (0..31 / 32..61, input overlap 4 rows): LDS drops
//    to 19 KB -> 8 blocks/CU -> 32 waves/CU. Staging +6% (overlap rows).
//  - Split at even row 32 keeps 2x2 pool pairs intact; BN-stat rows
//    partition exactly. Named-register rotation (rule #20 fix) unchanged.
//  - Everything else unchanged from round 7.
// ---------------------------------------------------------------------------

#define TPB 256

typedef __attribute__((ext_vector_type(8))) short bf16x8;
typedef __attribute__((ext_vector_type(4))) float f32x4;
typedef __attribute__((ext_vector_type(16))) float f32x16;

__device__ __forceinline__ float bf2f(unsigned short u) {
  return __uint_as_float(((unsigned)u) << 16);
}
__device__ __forceinline__ ushort f2b(float f) {
  __hip_bfloat16 h = __float2bfloat16(f);
  return *(ushort*)&h;
}

// ---------------- K1: conv1 (MFMA) + raw-maxpool + BN statistics -----------
// out(r,pos,oc) = sum_{kh} sum_{j<20, j=kw*4+ic, ic<3} Row[r+kh][pos*4+j]*W
// Row[t][u] (u = pcol*4+ic) = x[ic][t-1][pcol-1], zero borders.
// Block = (image n, half h): h=0 -> rows 0..31 (slices t=0..35),
//                            h=1 -> rows 32..61 (slices t=32..65).
// Local slice lt = t - 32*h; both halves: row rr uses lt = rr..rr+4.
__global__ __launch_bounds__(TPB, 8) void k_conv1(
    const float* __restrict__ x, const float* __restrict__ w1c,
    const float* __restrict__ b1c, __hip_bfloat16* __restrict__ pool1,
    float* __restrict__ stats)
{
  __shared__ uint4 imgI4[1190];          // 19040 B (36 slices + read guard)
  __shared__ float sred[20];
  ushort* imgI = (ushort*)imgI4;
  const int tid = threadIdx.x;
  const int lane = tid & 63;
  const int w = tid >> 6;
  const int n = blockIdx.x >> 1;
  const int h = blockIdx.x & 1;
  const int oc = lane & 15;
  const int q = lane >> 4;
  const int c0 = w * 16;
  const int r0 = h * 32;

  {
    const uint4 z = {0u, 0u, 0u, 0u};
    for (int i = tid; i < 1190; i += TPB) imgI4[i] = z;
    if (tid < 20) sred[tid] = 0.f;
  }
  __syncthreads();

  // stage needed slices, channel-interleaved (ic slot 3 = 0)
  {
    const float* xp = x + (size_t)n * 12288;
    const int nit = h ? 528 : 560;          // (33 or 35 rows) x 16 col-groups
    const int growbase = h ? 31 : 0;
    for (int i = tid; i < nit; i += TPB) {
      const int lr = i >> 4, col0 = (i & 15) * 4;
      const int grow = growbase + lr;       // global image row
      const int lt = h ? lr : (lr + 1);     // local slice index
      const float* xr = xp + grow * 64 + col0;
      const float4 v0 = *(const float4*)(xr);
      const float4 v1 = *(const float4*)(xr + 4096);
      const float4 v2 = *(const float4*)(xr + 8192);
      ushort* d = &imgI[((size_t)lt * 66 + (col0 + 1)) * 4];
      uint2 t0, t1, t2, t3;
      t0.x = (uint)f2b(v0.x) | ((uint)f2b(v1.x) << 16); t0.y = (uint)f2b(v2.x);
      t1.x = (uint)f2b(v0.y) | ((uint)f2b(v1.y) << 16); t1.y = (uint)f2b(v2.y);
      t2.x = (uint)f2b(v0.z) | ((uint)f2b(v1.z) << 16); t2.y = (uint)f2b(v2.z);
      t3.x = (uint)f2b(v0.w) | ((uint)f2b(v1.w) << 16); t3.y = (uint)f2b(v2.w);
      *(uint2*)(d + 0)  = t0;
      *(uint2*)(d + 4)  = t1;
      *(uint2*)(d + 8)  = t2;
      *(uint2*)(d + 12) = t3;
    }
  }

  // weight B-frags: 5 kh K-steps, named registers (no arrays!).
  // slot j = kw*4+ic (j<20, ic<3 real), K padded to 32 with zeros.
  bf16x8 wf0, wf1, wf2, wf3, wf4;
#define WLOAD(dst_, kh_)                                                \
  {                                                                     \
    union { ushort u[8]; bf16x8 v; } bu_;                               \
    _Pragma("unroll")                                                   \
    for (int i = 0; i < 8; i++) {                                       \
      const int j = q * 8 + i;                                          \
      float wv = 0.f;                                                   \
      if (oc < 10 && j < 20 && (j & 3) < 3)                             \
        wv = w1c[oc * 75 + (j & 3) * 25 + (kh_) * 5 + (j >> 2)];        \
      bu_.u[i] = f2b(wv);                                               \
    }                                                                   \
    dst_ = bu_.v;                                                       \
  }
  WLOAD(wf0, 0) WLOAD(wf1, 1) WLOAD(wf2, 2) WLOAD(wf3, 3) WLOAD(wf4, 4)
#undef WLOAD
  const float bias = (oc < 10) ? b1c[oc] : 0.f;

  __syncthreads();

  const int pos_A = c0 + oc;                    // A-matrix row (output col)
  const ushort* abase = &imgI[pos_A * 4 + q * 8];
  const int pwb = (c0 >> 1) + q * 2;

#define ALOADV(dst_, lt_)                                               \
  {                                                                     \
    const ushort* p_ = abase + (lt_) * 264;                             \
    union { uint u[4]; bf16x8 v; } au_;                                 \
    const uint2 lo_ = *(const uint2*)(p_);                              \
    const uint2 hi_ = *(const uint2*)(p_ + 4);                          \
    au_.u[0] = lo_.x; au_.u[1] = lo_.y;                                 \
    au_.u[2] = hi_.x; au_.u[3] = hi_.y;                                 \
    dst_ = au_.v;                                                       \
  }

  const float vm0 = ((c0 + q * 4 + 0) < 62) ? 1.f : 0.f;
  const float vm1 = ((c0 + q * 4 + 1) < 62) ? 1.f : 0.f;
  const float vm2 = ((c0 + q * 4 + 2) < 62) ? 1.f : 0.f;
  const float vm3 = ((c0 + q * 4 + 3) < 62) ? 1.f : 0.f;

  float ts = 0.f, tss = 0.f;
  float pp0 = 0.f, pp1 = 0.f;

#define ROWSTEP(rr_, sA, sB, sC, sD, sE)                                \
  {                                                                     \
    ALOADV(sE, (rr_) + 4)                                               \
    f32x4 accA = {0.f, 0.f, 0.f, 0.f};                                  \
    f32x4 accB = {0.f, 0.f, 0.f, 0.f};                                  \
    accA = __builtin_amdgcn_mfma_f32_16x16x32_bf16(sA, wf0, accA, 0, 0, 0); \
    accB = __builtin_amdgcn_mfma_f32_16x16x32_bf16(sB, wf1, accB, 0, 0, 0); \
    accA = __builtin_amdgcn_mfma_f32_16x16x32_bf16(sC, wf2, accA, 0, 0, 0); \
    accB = __builtin_amdgcn_mfma_f32_16x16x32_bf16(sD, wf3, accB, 0, 0, 0); \
    accA = __builtin_amdgcn_mfma_f32_16x16x32_bf16(sE, wf4, accA, 0, 0, 0); \
    const float y0 = accA[0] + accB[0] + bias;                          \
    const float y1 = accA[1] + accB[1] + bias;                          \
    const float y2 = accA[2] + accB[2] + bias;                          \
    const float y3 = accA[3] + accB[3] + bias;                          \
    float t0 = y0 * vm0; ts += t0; tss = fmaf(t0, y0, tss);             \
    float t1 = y1 * vm1; ts += t1; tss = fmaf(t1, y1, tss);             \
    float t2 = y2 * vm2; ts += t2; tss = fmaf(t2, y2, tss);             \
    float t3 = y3 * vm3; ts += t3; tss = fmaf(t3, y3, tss);             \
    const float p0v = fmaxf(y0, y1), p1v = fmaxf(y2, y3);               \
    if (((rr_) & 1) == 0) {                                             \
      pp0 = p0v; pp1 = p1v;                                             \
    } else if (oc < 10) {                                               \
      const int ph_ = (r0 + (rr_)) >> 1;                                \
      __hip_bfloat16* dst2_ =                                           \
          pool1 + (size_t)n * 9610 + (size_t)(ph_ * 31) * 10 + oc;      \
      const float q0_ = fmaxf(pp0, p0v), q1_ = fmaxf(pp1, p1v);         \
      dst2_[pwb * 10] = __float2bfloat16(q0_);                          \
      if (pwb + 1 < 31) dst2_[(pwb + 1) * 10] = __float2bfloat16(q1_);  \
    }                                                                   \
  }

  bf16x8 s0, s1, s2, s3, s4;
  ALOADV(s0, 0) ALOADV(s1, 1) ALOADV(s2, 2) ALOADV(s3, 3)

  for (int rb = 0; rb < 30; rb += 5) {
    ROWSTEP(rb + 0, s0, s1, s2, s3, s4)
    ROWSTEP(rb + 1, s1, s2, s3, s4, s0)
    ROWSTEP(rb + 2, s2, s3, s4, s0, s1)
    ROWSTEP(rb + 3, s3, s4, s0, s1, s2)
    ROWSTEP(rb + 4, s4, s0, s1, s2, s3)
  }
  if (h == 0) {
    // rows 30, 31 of half 0 (register mapping back to identity after 6 turns)
    ROWSTEP(30, s0, s1, s2, s3, s4)
    ROWSTEP(31, s1, s2, s3, s4, s0)
  }
#undef ROWSTEP
#undef ALOADV

  if (oc < 10) {
    atomicAdd(&sred[oc], ts);
    atomicAdd(&sred[10 + oc], tss);
  }
  __syncthreads();
  if (tid < 20) atomicAdd(&stats[tid], sred[tid]);
}

// ---------------- K2: finalize BN scale/shift ------------------------------
__global__ void k_bnfin(const float* __restrict__ bng,
                        const float* __restrict__ bnb,
                        float* __restrict__ stats)
{
  const int c = threadIdx.x;
  if (c < 10) {
    const float Ninv = 1.f / (4096.f * 3844.f);
    const float mean = stats[c] * Ninv;
    const float var = stats[10 + c] * Ninv - mean * mean;
    const float sc = bng[c] * rsqrtf(var + 1e-5f);
    stats[20 + c] = sc;
    stats[30 + c] = bnb[c] - mean * sc;
  }
}

// ---------------- K3: conv2 on MFMA, one image per wave --------------------
// out(r,pos,oc) = sum_{kh} sum_{j<50, j=kw*10+ic} Row[r+kh][pos*10+j] * W[oc][j,kh]
// Row[t][u] (u=pw_pad*10+ic) = BN-relu(pool1[n][t-1][pw_pad-1][ic]), zero borders.
// M=pos(28,pad32), N=oc(20,pad32), K=5 x 64 (j>=50 has zero B).
__global__ __launch_bounds__(TPB, 2) void k_conv2(
    const __hip_bfloat16* __restrict__ pool1, const float* __restrict__ stats,
    const float* __restrict__ w2c, const float* __restrict__ b2c,
    __hip_bfloat16* __restrict__ featb)
{
  __shared__ ushort R[4][4][344];          // [wave-image][slot][u], 11 KB
  __shared__ float ssc[10], ssh[10];
  const int tid = threadIdx.x;
  const int w = tid >> 6, lane = tid & 63;
  const int n = blockIdx.x * 4 + w;
  const int pos = lane & 31, q = lane >> 5;
  ushort (*Rw)[344] = R[w];

  if (tid < 10) { ssc[tid] = stats[20 + tid]; ssh[tid] = stats[30 + tid]; }
  // zero border cols of own 4 slots: u in [0,10) and [320,344)
  for (int i = lane; i < 136; i += 64) {
    const int s = i / 34, uu = i - 34 * s;
    Rw[s][(uu < 10) ? uu : (310 + uu)] = 0;
  }
  // zero fc1 K-pad cols for this image
  if (lane < 60) {
    uint* z = (uint*)((ushort*)featb + (size_t)n * 4160 + 3920);
    z[lane] = 0; z[lane + 60] = 0;
  }
  __syncthreads();

  // weight B-frags in VGPRs (j = kw*10+ic)
  bf16x8 wf[20];
#pragma unroll
  for (int kk = 0; kk < 20; kk++) {
    union { ushort u[8]; bf16x8 v; } bu;
    const int s = kk >> 2;
#pragma unroll
    for (int i = 0; i < 8; i++) {
      const int j = (kk & 3) * 16 + q * 8 + i;
      float wv = 0.f;
      if ((pos < 20) && (j < 50))
        wv = w2c[pos * 250 + (j % 10) * 25 + s * 5 + (j / 10)];
      bu.u[i] = f2b(wv);
    }
    wf[kk] = bu.v;
  }
  const float bias = (pos < 20) ? b2c[pos] : 0.f;

  const ushort* pp = (const ushort*)pool1 + (size_t)n * 9610;
  const int ic0 = (2 * lane) % 10;
  const int pos_e = (pos < 28) ? pos : pos - 16;
  const int pe10q8 = pos_e * 10 + q * 8;

  uint gv0, gv1, gv2;
#define GLOAD(t)                                                        \
  {                                                                     \
    const ushort* s_ = pp + ((t) - 1) * 310;                            \
    gv0 = *(const uint*)(s_ + 2 * lane);                                \
    gv1 = *(const uint*)(s_ + 2 * (lane + 64));                         \
    gv2 = (lane < 27) ? *(const uint*)(s_ + 2 * (lane + 128)) : 0u;     \
  }
#define GS1(c_, gv_)                                                    \
  {                                                                     \
    const int u2_ = lane + 64 * c_;                                     \
    if (c_ < 2 || lane < 27) {                                          \
      const int ia_ = (ic0 + 8 * c_) % 10;                              \
      const int ib_ = (ia_ == 9) ? 0 : ia_ + 1;                         \
      float a0_ = bf2f((ushort)(gv_ & 0xffffu));                        \
      float a1_ = bf2f((ushort)(gv_ >> 16));                            \
      a0_ = fmaxf(fmaf(a0_, ssc[ia_], ssh[ia_]), 0.f);                  \
      a1_ = fmaxf(fmaf(a1_, ssc[ib_], ssh[ib_]), 0.f);                  \
      *(uint*)(dst_ + 2 * u2_) = (uint)f2b(a0_) | ((uint)f2b(a1_) << 16);\
    }                                                                   \
  }
#define GSTORE(t)                                                       \
  {                                                                     \
    ushort* dst_ = &Rw[(t) & 3][10];                                    \
    GS1(0, gv0) GS1(1, gv1) GS1(2, gv2)                                 \
  }
#define FLOAD(t, ss)                                                    \
  {                                                                     \
    const ushort* bp_ = &Rw[(t) & 3][pe10q8];                           \
    _Pragma("unroll")                                                   \
    for (int sub_ = 0; sub_ < 4; sub_++) {                              \
      union { uint u[4]; bf16x8 v; } au_;                               \
      au_.u[0] = *(const uint*)(bp_ + sub_ * 16 + 0);                   \
      au_.u[1] = *(const uint*)(bp_ + sub_ * 16 + 2);                   \
      au_.u[2] = *(const uint*)(bp_ + sub_ * 16 + 4);                   \
      au_.u[3] = *(const uint*)(bp_ + sub_ * 16 + 6);                   \
      sets[ss][sub_] = au_.v;                                           \
    }                                                                   \
  }

  bf16x8 sets[5][4];
  const bf16x8 zfrag = (short)0;
#pragma unroll
  for (int s = 0; s < 4; s++) sets[0][s] = zfrag;   // t=0 border row

  GLOAD(1) GSTORE(1)
  GLOAD(2) GSTORE(2)
  GLOAD(3) GSTORE(3)
  GLOAD(4) GSTORE(4)
  GLOAD(5)
  __asm__ __volatile__("s_waitcnt lgkmcnt(0)" ::: "memory");
  FLOAD(1, 1) FLOAD(2, 2) FLOAD(3, 3)

  float php[8];
  for (int rb = 0; rb < 30; rb += 5) {
#pragma unroll
    for (int rr = 0; rr < 5; rr++) {
      const int r = rb + rr;
      __asm__ __volatile__("s_waitcnt lgkmcnt(0)" ::: "memory");
      if (r <= 27) FLOAD(r + 4, (rr + 4) % 5)
      if (r <= 26) GSTORE(r + 5)
      if (r <= 25) GLOAD(r + 6)
      if (r < 28) {
        f32x16 accA, accB;
#pragma unroll
        for (int z = 0; z < 16; z++) { accA[z] = 0.f; accB[z] = 0.f; }
#pragma unroll
        for (int kh = 0; kh < 5; kh++) {
          const int si = (rr + kh) % 5;
#pragma unroll
          for (int sub = 0; sub < 4; sub++) {
            if (kh & 1)
              accB = __builtin_amdgcn_mfma_f32_32x32x16_bf16(
                  sets[si][sub], wf[kh * 4 + sub], accB, 0, 0, 0);
            else
              accA = __builtin_amdgcn_mfma_f32_32x32x16_bf16(
                  sets[si][sub], wf[kh * 4 + sub], accA, 0, 0, 0);
          }
        }
        float hp[8];
#pragma unroll
        for (int p = 0; p < 8; p++)
          hp[p] = fmaxf(accA[2 * p] + accB[2 * p],
                        accA[2 * p + 1] + accB[2 * p + 1]);
        if ((r & 1) == 0) {
#pragma unroll
          for (int p = 0; p < 8; p++) php[p] = hp[p];
        } else if (pos < 20) {
          const int ph = r >> 1;
          ushort* dst = (ushort*)featb + (size_t)n * 4160 + pos * 196 + ph * 14;
#pragma unroll
          for (int j = 0; j < 4; j++) {
            const int pw = 4 * j + 2 * q;
            if (pw + 1 < 14) {
              const float v0 =
                  fmaxf(fmaxf(php[2 * j], hp[2 * j]) + bias, 0.f);
              const float v1 =
                  fmaxf(fmaxf(php[2 * j + 1], hp[2 * j + 1]) + bias, 0.f);
              *(uint*)(dst + pw) = (uint)f2b(v0) | ((uint)f2b(v1) << 16);
            }
          }
        }
      }
    }
  }
#undef GLOAD
#undef GS1
#undef GSTORE
#undef FLOAD
}

// ---------------- K3b: cast ew1 -> bf16 [1024][4160] -----------------------
__global__ __launch_bounds__(TPB) void k_castw1(
    const float* __restrict__ ew1, ushort* __restrict__ w1b)
{
  const int o = blockIdx.x;
  const int tid = threadIdx.x;
  const float* srow = ew1 + (size_t)o * 3920;
  ushort* drow = w1b + (size_t)o * 4160;
  for (int i = tid; i < 1040; i += TPB) {
    const int k4 = i * 4;
    ushort4 r;
    if (k4 < 3920) {
      const float4 v = *(const float4*)(srow + k4);
      r.x = f2b(v.x); r.y = f2b(v.y); r.z = f2b(v.z); r.w = f2b(v.w);
    } else {
      r.x = 0; r.y = 0; r.z = 0; r.w = 0;
    }
    *(ushort4*)(drow + k4) = r;
  }
}

// ---------------- K4a: gate fc1 partial GEMM (atomic K-split) --------------
__global__ __launch_bounds__(TPB) void k_gate1(
    const ushort* __restrict__ featb, const float* __restrict__ gw1,
    float* __restrict__ graw)
{
  __shared__ float sf[64 * 113];
  __shared__ float sw[64 * 113];
  const int tid = threadIdx.x;
  const int r0 = blockIdx.x * 64;
  const int kz = blockIdx.y;
  const int ty = tid >> 4, tx = tid & 15;
  float acc[4][4] = {{0.f}};
  for (int c = kz; c < 35; c += 4) {
    const int k0 = c * 112;
    for (int i = tid; i < 896; i += TPB) {
      const int row = i / 14, k8 = (i - row * 14) * 8;
      uint4 v = *(const uint4*)(featb + (size_t)(r0 + row) * 4160 + k0 + k8);
      const ushort* pv = (const ushort*)&v;
      float* d = &sf[row * 113 + k8];
#pragma unroll
      for (int t = 0; t < 8; t++) d[t] = bf2f(pv[t]);
    }
    for (int i = tid; i < 1792; i += TPB) {
      const int row = i / 28, c4 = (i - row * 28) * 4;
      float4 u = *(const float4*)(gw1 + (size_t)row * 3920 + k0 + c4);
      float* e = &sw[row * 113 + c4];
      e[0] = u.x; e[1] = u.y; e[2] = u.z; e[3] = u.w;
    }
    __syncthreads();
    for (int k = 0; k < 112; k++) {
      float a_[4], w_[4];
#pragma unroll
      for (int i = 0; i < 4; i++) a_[i] = sf[(ty * 4 + i) * 113 + k];
#pragma unroll
      for (int j = 0; j < 4; j++) w_[j] = sw[(tx * 4 + j) * 113 + k];
#pragma unroll
      for (int i = 0; i < 4; i++)
#pragma unroll
        for (int j = 0; j < 4; j++) acc[i][j] = fmaf(a_[i], w_[j], acc[i][j]);
    }
    __syncthreads();
  }
#pragma unroll
  for (int i = 0; i < 4; i++)
#pragma unroll
    for (int j = 0; j < 4; j++)
      atomicAdd(&graw[(size_t)(r0 + ty * 4 + i) * 64 + tx * 4 + j], acc[i][j]);
}

// ---------------- K4b: gate logits + top2 softmax + expert counts ----------
__global__ __launch_bounds__(TPB) void k_gate2(
    const float* __restrict__ graw, const float* __restrict__ gb1,
    const float* __restrict__ gw2, const float* __restrict__ gb2,
    int* __restrict__ sel0, int* __restrict__ sel1,
    float* __restrict__ wt0, float* __restrict__ wt1, int* __restrict__ counts)
{
  __shared__ float sw2[512], sb1[64], sb2[8];
  const int tid = threadIdx.x;
  for (int i = tid; i < 512; i += TPB) sw2[i] = gw2[i];
  if (tid < 64) sb1[tid] = gb1[tid];
  if (tid < 8) sb2[tid] = gb2[tid];
  __syncthreads();
  const int r = blockIdx.x * TPB + tid;
  float l[8];
#pragma unroll
  for (int c = 0; c < 8; c++) l[c] = sb2[c];
  const float* gr = graw + (size_t)r * 64;
  for (int k = 0; k < 64; k++) {
    const float hv = fmaxf(gr[k] + sb1[k], 0.f);
#pragma unroll
    for (int c = 0; c < 8; c++) l[c] = fmaf(hv, sw2[c * 64 + k], l[c]);
  }
  float v0 = -1e30f, v1 = -1e30f; int i0 = 0, i1 = 0;
#pragma unroll
  for (int c = 0; c < 8; c++) {
    const float lv = l[c];
    if (lv > v0) { v1 = v0; i1 = i0; v0 = lv; i0 = c; }
    else if (lv > v1) { v1 = lv; i1 = c; }
  }
  const float e1 = expf(v1 - v0);
  const float inv = 1.f / (1.f + e1);
  sel0[r] = i0; sel1[r] = i1; wt0[r] = inv; wt1[r] = e1 * inv;
  atomicAdd(&counts[i0], 1);
  atomicAdd(&counts[i1], 1);
}

// ---------------- K5: padded offsets + entry-list init ---------------------
__global__ void k_prep(int* __restrict__ hdrI, int* __restrict__ entrow)
{
  const int tid = threadIdx.x;
  if (tid == 0) {
    int run = 0;
    for (int e = 0; e < 8; e++) {
      const int c = hdrI[e];
      const int pc = (c + 31) & ~31;
      hdrI[16 + e] = pc;
      hdrI[24 + e] = run;
      run += pc;
    }
    hdrI[32] = run;
  }
  if (tid >= 8 && tid < 16) hdrI[tid] = 0;
  for (int i = tid; i < 8448; i += TPB) entrow[i] = -1;
}

// ---------------- K5b: scatter rows to expert entry lists ------------------
__global__ void k_scatter(const int* __restrict__ sel0, const int* __restrict__ sel1,
                          int* __restrict__ hdrI, int* __restrict__ entrow,
                          int* __restrict__ p0, int* __restrict__ p1)
{
  const int r = blockIdx.x * TPB + threadIdx.x;
  const int e0 = sel0[r];
  int pos = atomicAdd(&hdrI[8 + e0], 1) + hdrI[24 + e0];
  entrow[pos] = r; p0[r] = pos;
  const int e1 = sel1[r];
  pos = atomicAdd(&hdrI[8 + e1], 1) + hdrI[24 + e1];
  entrow[pos] = r; p1[r] = pos;
}

// ---------------- K6: dense MFMA fc1 -> h1 bf16 [4096][1024] ---------------
__global__ __launch_bounds__(512) void k_fc1(
    const ushort* __restrict__ featb, const ushort* __restrict__ w1b,
    const float* __restrict__ eb1, __hip_bfloat16* __restrict__ h1b)
{
  __shared__ ushort As[128 * 72];
  __shared__ ushort Bs[128 * 72];
  const int tid = threadIdx.x;
  const int r0 = blockIdx.x * 128;
  const int c0 = blockIdx.y * 128;
  const int w = tid >> 6, lane = tid & 63;
  const int wr = (w >> 1) * 32, wc = (w & 1) * 64;
  const int m = lane & 15, q = lane >> 4;
  f32x4 acc[2][4];
#pragma unroll
  for (int i = 0; i < 2; i++)
#pragma unroll
    for (int j = 0; j < 4; j++) acc[i][j] = 0.f;

  for (int kc = 0; kc < 4096; kc += 64) {
#pragma unroll
    for (int i = 0; i < 2; i++) {
      const int u = tid + 512 * i;
      const int row = u >> 3, k8 = (u & 7) * 8;
      *(uint4*)(&As[row * 72 + k8]) =
          *(const uint4*)(featb + (size_t)(r0 + row) * 4160 + kc + k8);
      *(uint4*)(&Bs[row * 72 + k8]) =
          *(const uint4*)(w1b + (size_t)(c0 + row) * 4160 + kc + k8);
    }
    __syncthreads();
#pragma unroll
    for (int kk = 0; kk < 64; kk += 32) {
      bf16x8 af[2], bf[4];
#pragma unroll
      for (int t = 0; t < 2; t++)
        af[t] = *(const bf16x8*)(&As[(wr + t * 16 + m) * 72 + kk + q * 8]);
#pragma unroll
      for (int t = 0; t < 4; t++)
        bf[t] = *(const bf16x8*)(&Bs[(wc + t * 16 + m) * 72 + kk + q * 8]);
#pragma unroll
      for (int ti = 0; ti < 2; ti++)
#pragma unroll
        for (int tj = 0; tj < 4; tj++)
          acc[ti][tj] = __builtin_amdgcn_mfma_f32_16x16x32_bf16(
              af[ti], bf[tj], acc[ti][tj], 0, 0, 0);
    }
    __syncthreads();
  }
#pragma unroll
  for (int tj = 0; tj < 4; tj++) {
    const int c = c0 + wc + tj * 16 + m;
    const float bb = eb1[c];
#pragma unroll
    for (int ti = 0; ti < 2; ti++) {
      const int rbase = r0 + wr + ti * 16 + q * 4;
#pragma unroll
      for (int i = 0; i < 4; i++) {
        const float v = fmaxf(acc[ti][tj][i] + bb, 0.f);
        h1b[(size_t)(rbase + i) * 1024 + c] = __float2bfloat16(v);
      }
    }
  }
}

// ---------------- K7: dense fc2 -> h2 fp32 [4096][512] ---------------------
__global__ __launch_bounds__(TPB) void k_fc2(
    const __hip_bfloat16* __restrict__ h1b, const float* __restrict__ ew2,
    const float* __restrict__ eb2, float* __restrict__ h2)
{
  __shared__ float h1s[64 * 132];
  __shared__ ushort w2s[128 * 72];
  const int tid = threadIdx.x;
  const int r0 = blockIdx.x * 64;
  const int e = blockIdx.y;
  const ushort* hp = (const ushort*)h1b;
#pragma unroll
  for (int i = 0; i < 4; i++) {
    const int u = tid + 256 * i;
    const int row = u >> 4, k8 = (u & 15) * 8;
    uint4 v = *(const uint4*)(hp + (size_t)(r0 + row) * 1024 + e * 128 + k8);
    const ushort* pv = (const ushort*)&v;
    float* d = &h1s[row * 132 + k8];
#pragma unroll
    for (int t = 0; t < 8; t++) d[t] = bf2f(pv[t]);
  }
#pragma unroll
  for (int i = 0; i < 8; i++) {
    const int u = tid + 256 * i;
    const int nn = u >> 5, k4 = (u & 31) * 4;
    const float4 v = *(const float4*)(ew2 + (size_t)e * 8192 + nn * 128 + k4);
    w2s[(k4 + 0) * 72 + nn] = f2b(v.x);
    w2s[(k4 + 1) * 72 + nn] = f2b(v.y);
    w2s[(k4 + 2) * 72 + nn] = f2b(v.z);
    w2s[(k4 + 3) * 72 + nn] = f2b(v.w);
  }
  __syncthreads();
  const int ty = tid >> 4, tx = tid & 15;
  float acc[4][4] = {{0.f}};
  for (int k4 = 0; k4 < 32; k4++) {
    f32x4 a4[4];
#pragma unroll
    for (int i = 0; i < 4; i++)
      a4[i] = *(const f32x4*)(&h1s[(ty * 4 + i) * 132 + k4 * 4]);
#pragma unroll
    for (int kk = 0; kk < 4; kk++) {
      const ushort4 wu = *(const ushort4*)(&w2s[(k4 * 4 + kk) * 72 + tx * 4]);
      const float w0 = bf2f(wu.x), w1 = bf2f(wu.y);
      const float w2_ = bf2f(wu.z), w3 = bf2f(wu.w);
#pragma unroll
      for (int i = 0; i < 4; i++) {
        acc[i][0] = fmaf(a4[i][kk], w0, acc[i][0]);
        acc[i][1] = fmaf(a4[i][kk], w1, acc[i][1]);
        acc[i][2] = fmaf(a4[i][kk], w2_, acc[i][2]);
        acc[i][3] = fmaf(a4[i][kk], w3, acc[i][3]);
      }
    }
  }
  const f32x4 bb = *(const f32x4*)(eb2 + e * 64 + tx * 4);
#pragma unroll
  for (int i = 0; i < 4; i++) {
    f32x4 r;
#pragma unroll
    for (int j = 0; j < 4; j++) r[j] = fmaxf(acc[i][j] + bb[j], 0.f);
    *(f32x4*)(h2 + (size_t)(r0 + ty * 4 + i) * 512 + e * 64 + tx * 4) = r;
  }
}

// ---------------- K8: grouped fc3 -> eo [pos][1000] ------------------------
__global__ __launch_bounds__(TPB) void k_fc3(
    const float* __restrict__ h2, const float* __restrict__ ew3,
    const float* __restrict__ eb3, const int* __restrict__ hdrI,
    const int* __restrict__ entrow, float* __restrict__ eo)
{
  __shared__ float h2s[32 * 68];
  __shared__ float w3s[64 * 132];
  const int e = blockIdx.y;
  const int pcnt = hdrI[16 + e];
  if ((int)blockIdx.x * 32 >= pcnt) return;
  const int base = hdrI[24 + e] + blockIdx.x * 32;
  const int tid = threadIdx.x;
  for (int i = tid; i < 512; i += TPB) {
    const int row = i >> 4, k4 = (i & 15) * 4;
    const int rr = entrow[base + row];
    f32x4 v = 0.f;
    if (rr >= 0) v = *(const f32x4*)(h2 + (size_t)rr * 512 + e * 64 + k4);
    *(f32x4*)(&h2s[row * 68 + k4]) = v;
  }
  const int ty = tid >> 5, tx = tid & 31;
  const float* w3p = ew3 + (size_t)e * 64000;
  const float* b3p = eb3 + (size_t)e * 1000;
  for (int nc = 0; nc < 8; nc++) {
    const int o0 = nc * 128;
    for (int i = tid; i < 2048; i += TPB) {
      const int oo = i >> 4, k4 = (i & 15) * 4;
      const int o = o0 + oo;
      f32x4 u = 0.f;
      if (o < 1000) u = *(const f32x4*)(w3p + (size_t)o * 64 + k4);
      w3s[(k4 + 0) * 132 + oo] = u[0];
      w3s[(k4 + 1) * 132 + oo] = u[1];
      w3s[(k4 + 2) * 132 + oo] = u[2];
      w3s[(k4 + 3) * 132 + oo] = u[3];
    }
    __syncthreads();
    float acc[4][4] = {{0.f}};
    for (int k4 = 0; k4 < 16; k4++) {
      f32x4 a4[4], w4[4];
#pragma unroll
      for (int i = 0; i < 4; i++)
        a4[i] = *(const f32x4*)(&h2s[(ty * 4 + i) * 68 + k4 * 4]);
#pragma unroll
      for (int kk = 0; kk < 4; kk++)
        w4[kk] = *(const f32x4*)(&w3s[(k4 * 4 + kk) * 132 + tx * 4]);
#pragma unroll
      for (int kk = 0; kk < 4; kk++)
#pragma unroll
        for (int i = 0; i < 4; i++)
#pragma unroll
          for (int j = 0; j < 4; j++)
            acc[i][j] = fmaf(a4[i][kk], w4[kk][j], acc[i][j]);
    }
    const int o = o0 + tx * 4;
    if (o + 3 < 1000) {
      const f32x4 bb = *(const f32x4*)(b3p + o);
#pragma unroll
      for (int i = 0; i < 4; i++) {
        f32x4 r;
#pragma unroll
        for (int j = 0; j < 4; j++) r[j] = acc[i][j] + bb[j];
        *(f32x4*)(eo + (size_t)(base + ty * 4 + i) * 1000 + o) = r;
      }
    }
    __syncthreads();
  }
}

// ---------------- K9: gate-combine + log_softmax(|.|) ----------------------
__global__ __launch_bounds__(TPB) void k_out(
    const float* __restrict__ eo, const int* __restrict__ p0,
    const int* __restrict__ p1, const float* __restrict__ wt0,
    const float* __restrict__ wt1, float* __restrict__ out)
{
  __shared__ float sv[1000];
  __shared__ float sr[8];
  const int r = blockIdx.x, tid = threadIdx.x;
  const float w0 = wt0[r], w1 = wt1[r];
  const float* a = eo + (size_t)p0[r] * 1000;
  const float* b = eo + (size_t)p1[r] * 1000;
  float lmax = -3.4e38f;
  for (int o = tid; o < 1000; o += TPB) {
    const float v = fabsf(w0 * a[o] + w1 * b[o]);
    sv[o] = v;
    lmax = fmaxf(lmax, v);
  }
#pragma unroll
  for (int off = 32; off; off >>= 1) lmax = fmaxf(lmax, __shfl_down(lmax, off));
  if ((tid & 63) == 0) sr[tid >> 6] = lmax;
  __syncthreads();
  const float mx = fmaxf(fmaxf(sr[0], sr[1]), fmaxf(sr[2], sr[3]));
  float lsum = 0.f;
  for (int o = tid; o < 1000; o += TPB) lsum += expf(sv[o] - mx);
#pragma unroll
  for (int off = 32; off; off >>= 1) lsum += __shfl_down(lsum, off);
  if ((tid & 63) == 0) sr[4 + (tid >> 6)] = lsum;
  __syncthreads();
  const float lse = logf(sr[4] + sr[5] + sr[6] + sr[7]);
  const float sub = mx + lse;
  for (int o = tid; o < 1000; o += TPB)
    out[(size_t)r * 1000 + o] = sv[o] - sub;
}

// ---------------------------------------------------------------------------
extern "C" void kernel_launch(void* const* d_in, const int* in_sizes, int n_in,
                              void* d_out, int out_size, void* d_ws, size_t ws_size,
                              hipStream_t stream)
{
  (void)in_sizes; (void)n_in; (void)out_size; (void)ws_size;
  const float* x   = (const float*)d_in[0];
  const float* c1w = (const float*)d_in[1];
  const float* c1b = (const float*)d_in[2];
  const float* bng = (const float*)d_in[3];
  const float* bnb = (const float*)d_in[4];
  const float* c2w = (const float*)d_in[5];
  const float* c2b = (const float*)d_in[6];
  const float* gw1 = (const float*)d_in[7];
  const float* gb1 = (const float*)d_in[8];
  const float* gw2 = (const float*)d_in[9];
  const float* gb2 = (const float*)d_in[10];
  const float* ew1 = (const float*)d_in[11];
  const float* eb1 = (const float*)d_in[12];
  const float* ew2 = (const float*)d_in[13];
  const float* eb2 = (const float*)d_in[14];
  const float* ew3 = (const float*)d_in[15];
  const float* eb3 = (const float*)d_in[16];

  char* ws = (char*)d_ws;
  float* statsF = (float*)ws;
  int*   hdrI   = (int*)(ws + 256);
  int*   sel0   = (int*)(ws + 1024);
  int*   sel1   = (int*)(ws + 17408);
  float* wt0    = (float*)(ws + 33792);
  float* wt1    = (float*)(ws + 50176);
  int*   p0     = (int*)(ws + 66560);
  int*   p1     = (int*)(ws + 82944);
  int*   entrow = (int*)(ws + 99328);
  float* graw   = (float*)(ws + 133120);
  float* eo     = (float*)(ws + 1181696);
  __hip_bfloat16* h1b = (__hip_bfloat16*)(ws + 34973696);
  float* h2     = (float*)(ws + 43362304);
  __hip_bfloat16* pool1 = (__hip_bfloat16*)(ws + 51750912);
  __hip_bfloat16* featb = (__hip_bfloat16*)(ws + 130476032);
  ushort* w1b   = (ushort*)(ws + 164554752);

  hipMemsetAsync(ws, 0, 512, stream);
  hipMemsetAsync(graw, 0, 4096 * 64 * sizeof(float), stream);

  k_castw1 <<<1024, TPB, 0, stream>>>(ew1, w1b);
  k_conv1  <<<8192, TPB, 0, stream>>>(x, c1w, c1b, pool1, statsF);
  k_bnfin  <<<1, 64, 0, stream>>>(bng, bnb, statsF);
  k_conv2  <<<1024, TPB, 0, stream>>>(pool1, statsF, c2w, c2b, featb);
  k_gate1  <<<dim3(64, 4), TPB, 0, stream>>>((const ushort*)featb, gw1, graw);
  k_gate2  <<<16, TPB, 0, stream>>>(graw, gb1, gw2, gb2, sel0, sel1, wt0, wt1, hdrI);
  k_prep   <<<1, TPB, 0, stream>>>(hdrI, entrow);
  k_scatter<<<16, TPB, 0, stream>>>(sel0, sel1, hdrI, entrow, p0, p1);
  k_fc1    <<<dim3(32, 8), 512, 0, stream>>>((const ushort*)featb, w1b, eb1, h1b);
  k_fc2    <<<dim3(64, 8), TPB, 0, stream>>>(h1b, ew2, eb2, h2);
  k_fc3    <<<dim3(128, 8), TPB, 0, stream>>>(h2, ew3, eb3, hdrI, entrow, eo);
  k_out    <<<4096, TPB, 0, stream>>>(eo, p0, p1, wt0, wt1, (float*)d_out);
}

// Round 4
// 1246.067 us; speedup vs baseline: 1.1885x; 1.1885x over previous
//
#include <hip/hip_runtime.h>
#include <hip/hip_bf16.h>

// ---------------------------------------------------------------------------
// Net_83674552861196 — round 9: conv1 half-split with RELAXED reg budget.
//  - Round 8: __launch_bounds__(TPB,8) forced a 64-VGPR budget; demand is
//    ~60-70 incl AGPRs -> allocator spilled a hot-loop register set ->
//    1.8 GB scratch traffic (WRITE 77->1094 MB), VALUBusy 11%. Occupancy
//    DID hit 85% -- the thesis was right, the budget cliff killed it.
//  - Fix: __launch_bounds__(TPB, 6) -> 85-reg budget, no spill; LDS 19 KB
//    still allows 8 blocks/CU if regs land <=64 (round 7: 52+8). Occupancy
//    62-83% either way vs round 7's 41%. One-token change from a
//    correctness-passed kernel.
//  - Everything else unchanged from round 8.
// ---------------------------------------------------------------------------

#define TPB 256

typedef __attribute__((ext_vector_type(8))) short bf16x8;
typedef __attribute__((ext_vector_type(4))) float f32x4;
typedef __attribute__((ext_vector_type(16))) float f32x16;

__device__ __forceinline__ float bf2f(unsigned short u) {
  return __uint_as_float(((unsigned)u) << 16);
}
__device__ __forceinline__ ushort f2b(float f) {
  __hip_bfloat16 h = __float2bfloat16(f);
  return *(ushort*)&h;
}

// ---------------- K1: conv1 (MFMA) + raw-maxpool + BN statistics -----------
// out(r,pos,oc) = sum_{kh} sum_{j<20, j=kw*4+ic, ic<3} Row[r+kh][pos*4+j]*W
// Row[t][u] (u = pcol*4+ic) = x[ic][t-1][pcol-1], zero borders.
// Block = (image n, half h): h=0 -> rows 0..31 (slices t=0..35),
//                            h=1 -> rows 32..61 (slices t=32..65).
// Local slice lt = t - 32*h; both halves: row rr uses lt = rr..rr+4.
__global__ __launch_bounds__(TPB, 6) void k_conv1(
    const float* __restrict__ x, const float* __restrict__ w1c,
    const float* __restrict__ b1c, __hip_bfloat16* __restrict__ pool1,
    float* __restrict__ stats)
{
  __shared__ uint4 imgI4[1190];          // 19040 B (36 slices + read guard)
  __shared__ float sred[20];
  ushort* imgI = (ushort*)imgI4;
  const int tid = threadIdx.x;
  const int lane = tid & 63;
  const int w = tid >> 6;
  const int n = blockIdx.x >> 1;
  const int h = blockIdx.x & 1;
  const int oc = lane & 15;
  const int q = lane >> 4;
  const int c0 = w * 16;
  const int r0 = h * 32;

  {
    const uint4 z = {0u, 0u, 0u, 0u};
    for (int i = tid; i < 1190; i += TPB) imgI4[i] = z;
    if (tid < 20) sred[tid] = 0.f;
  }
  __syncthreads();

  // stage needed slices, channel-interleaved (ic slot 3 = 0)
  {
    const float* xp = x + (size_t)n * 12288;
    const int nit = h ? 528 : 560;          // (33 or 35 rows) x 16 col-groups
    const int growbase = h ? 31 : 0;
    for (int i = tid; i < nit; i += TPB) {
      const int lr = i >> 4, col0 = (i & 15) * 4;
      const int grow = growbase + lr;       // global image row
      const int lt = h ? lr : (lr + 1);     // local slice index
      const float* xr = xp + grow * 64 + col0;
      const float4 v0 = *(const float4*)(xr);
      const float4 v1 = *(const float4*)(xr + 4096);
      const float4 v2 = *(const float4*)(xr + 8192);
      ushort* d = &imgI[((size_t)lt * 66 + (col0 + 1)) * 4];
      uint2 t0, t1, t2, t3;
      t0.x = (uint)f2b(v0.x) | ((uint)f2b(v1.x) << 16); t0.y = (uint)f2b(v2.x);
      t1.x = (uint)f2b(v0.y) | ((uint)f2b(v1.y) << 16); t1.y = (uint)f2b(v2.y);
      t2.x = (uint)f2b(v0.z) | ((uint)f2b(v1.z) << 16); t2.y = (uint)f2b(v2.z);
      t3.x = (uint)f2b(v0.w) | ((uint)f2b(v1.w) << 16); t3.y = (uint)f2b(v2.w);
      *(uint2*)(d + 0)  = t0;
      *(uint2*)(d + 4)  = t1;
      *(uint2*)(d + 8)  = t2;
      *(uint2*)(d + 12) = t3;
    }
  }

  // weight B-frags: 5 kh K-steps, named registers (no arrays!).
  // slot j = kw*4+ic (j<20, ic<3 real), K padded to 32 with zeros.
  bf16x8 wf0, wf1, wf2, wf3, wf4;
#define WLOAD(dst_, kh_)                                                \
  {                                                                     \
    union { ushort u[8]; bf16x8 v; } bu_;                               \
    _Pragma("unroll")                                                   \
    for (int i = 0; i < 8; i++) {                                       \
      const int j = q * 8 + i;                                          \
      float wv = 0.f;                                                   \
      if (oc < 10 && j < 20 && (j & 3) < 3)                             \
        wv = w1c[oc * 75 + (j & 3) * 25 + (kh_) * 5 + (j >> 2)];        \
      bu_.u[i] = f2b(wv);                                               \
    }                                                                   \
    dst_ = bu_.v;                                                       \
  }
  WLOAD(wf0, 0) WLOAD(wf1, 1) WLOAD(wf2, 2) WLOAD(wf3, 3) WLOAD(wf4, 4)
#undef WLOAD
  const float bias = (oc < 10) ? b1c[oc] : 0.f;

  __syncthreads();

  const int pos_A = c0 + oc;                    // A-matrix row (output col)
  const ushort* abase = &imgI[pos_A * 4 + q * 8];
  const int pwb = (c0 >> 1) + q * 2;

#define ALOADV(dst_, lt_)                                               \
  {                                                                     \
    const ushort* p_ = abase + (lt_) * 264;                             \
    union { uint u[4]; bf16x8 v; } au_;                                 \
    const uint2 lo_ = *(const uint2*)(p_);                              \
    const uint2 hi_ = *(const uint2*)(p_ + 4);                          \
    au_.u[0] = lo_.x; au_.u[1] = lo_.y;                                 \
    au_.u[2] = hi_.x; au_.u[3] = hi_.y;                                 \
    dst_ = au_.v;                                                       \
  }

  const float vm0 = ((c0 + q * 4 + 0) < 62) ? 1.f : 0.f;
  const float vm1 = ((c0 + q * 4 + 1) < 62) ? 1.f : 0.f;
  const float vm2 = ((c0 + q * 4 + 2) < 62) ? 1.f : 0.f;
  const float vm3 = ((c0 + q * 4 + 3) < 62) ? 1.f : 0.f;

  float ts = 0.f, tss = 0.f;
  float pp0 = 0.f, pp1 = 0.f;

#define ROWSTEP(rr_, sA, sB, sC, sD, sE)                                \
  {                                                                     \
    ALOADV(sE, (rr_) + 4)                                               \
    f32x4 accA = {0.f, 0.f, 0.f, 0.f};                                  \
    f32x4 accB = {0.f, 0.f, 0.f, 0.f};                                  \
    accA = __builtin_amdgcn_mfma_f32_16x16x32_bf16(sA, wf0, accA, 0, 0, 0); \
    accB = __builtin_amdgcn_mfma_f32_16x16x32_bf16(sB, wf1, accB, 0, 0, 0); \
    accA = __builtin_amdgcn_mfma_f32_16x16x32_bf16(sC, wf2, accA, 0, 0, 0); \
    accB = __builtin_amdgcn_mfma_f32_16x16x32_bf16(sD, wf3, accB, 0, 0, 0); \
    accA = __builtin_amdgcn_mfma_f32_16x16x32_bf16(sE, wf4, accA, 0, 0, 0); \
    const float y0 = accA[0] + accB[0] + bias;                          \
    const float y1 = accA[1] + accB[1] + bias;                          \
    const float y2 = accA[2] + accB[2] + bias;                          \
    const float y3 = accA[3] + accB[3] + bias;                          \
    float t0 = y0 * vm0; ts += t0; tss = fmaf(t0, y0, tss);             \
    float t1 = y1 * vm1; ts += t1; tss = fmaf(t1, y1, tss);             \
    float t2 = y2 * vm2; ts += t2; tss = fmaf(t2, y2, tss);             \
    float t3 = y3 * vm3; ts += t3; tss = fmaf(t3, y3, tss);             \
    const float p0v = fmaxf(y0, y1), p1v = fmaxf(y2, y3);               \
    if (((rr_) & 1) == 0) {                                             \
      pp0 = p0v; pp1 = p1v;                                             \
    } else if (oc < 10) {                                               \
      const int ph_ = (r0 + (rr_)) >> 1;                                \
      __hip_bfloat16* dst2_ =                                           \
          pool1 + (size_t)n * 9610 + (size_t)(ph_ * 31) * 10 + oc;      \
      const float q0_ = fmaxf(pp0, p0v), q1_ = fmaxf(pp1, p1v);         \
      dst2_[pwb * 10] = __float2bfloat16(q0_);                          \
      if (pwb + 1 < 31) dst2_[(pwb + 1) * 10] = __float2bfloat16(q1_);  \
    }                                                                   \
  }

  bf16x8 s0, s1, s2, s3, s4;
  ALOADV(s0, 0) ALOADV(s1, 1) ALOADV(s2, 2) ALOADV(s3, 3)

  for (int rb = 0; rb < 30; rb += 5) {
    ROWSTEP(rb + 0, s0, s1, s2, s3, s4)
    ROWSTEP(rb + 1, s1, s2, s3, s4, s0)
    ROWSTEP(rb + 2, s2, s3, s4, s0, s1)
    ROWSTEP(rb + 3, s3, s4, s0, s1, s2)
    ROWSTEP(rb + 4, s4, s0, s1, s2, s3)
  }
  if (h == 0) {
    // rows 30, 31 of half 0 (register mapping back to identity after 6 turns)
    ROWSTEP(30, s0, s1, s2, s3, s4)
    ROWSTEP(31, s1, s2, s3, s4, s0)
  }
#undef ROWSTEP
#undef ALOADV

  if (oc < 10) {
    atomicAdd(&sred[oc], ts);
    atomicAdd(&sred[10 + oc], tss);
  }
  __syncthreads();
  if (tid < 20) atomicAdd(&stats[tid], sred[tid]);
}

// ---------------- K2: finalize BN scale/shift ------------------------------
__global__ void k_bnfin(const float* __restrict__ bng,
                        const float* __restrict__ bnb,
                        float* __restrict__ stats)
{
  const int c = threadIdx.x;
  if (c < 10) {
    const float Ninv = 1.f / (4096.f * 3844.f);
    const float mean = stats[c] * Ninv;
    const float var = stats[10 + c] * Ninv - mean * mean;
    const float sc = bng[c] * rsqrtf(var + 1e-5f);
    stats[20 + c] = sc;
    stats[30 + c] = bnb[c] - mean * sc;
  }
}

// ---------------- K3: conv2 on MFMA, one image per wave --------------------
// out(r,pos,oc) = sum_{kh} sum_{j<50, j=kw*10+ic} Row[r+kh][pos*10+j] * W[oc][j,kh]
// Row[t][u] (u=pw_pad*10+ic) = BN-relu(pool1[n][t-1][pw_pad-1][ic]), zero borders.
// M=pos(28,pad32), N=oc(20,pad32), K=5 x 64 (j>=50 has zero B).
__global__ __launch_bounds__(TPB, 2) void k_conv2(
    const __hip_bfloat16* __restrict__ pool1, const float* __restrict__ stats,
    const float* __restrict__ w2c, const float* __restrict__ b2c,
    __hip_bfloat16* __restrict__ featb)
{
  __shared__ ushort R[4][4][344];          // [wave-image][slot][u], 11 KB
  __shared__ float ssc[10], ssh[10];
  const int tid = threadIdx.x;
  const int w = tid >> 6, lane = tid & 63;
  const int n = blockIdx.x * 4 + w;
  const int pos = lane & 31, q = lane >> 5;
  ushort (*Rw)[344] = R[w];

  if (tid < 10) { ssc[tid] = stats[20 + tid]; ssh[tid] = stats[30 + tid]; }
  // zero border cols of own 4 slots: u in [0,10) and [320,344)
  for (int i = lane; i < 136; i += 64) {
    const int s = i / 34, uu = i - 34 * s;
    Rw[s][(uu < 10) ? uu : (310 + uu)] = 0;
  }
  // zero fc1 K-pad cols for this image
  if (lane < 60) {
    uint* z = (uint*)((ushort*)featb + (size_t)n * 4160 + 3920);
    z[lane] = 0; z[lane + 60] = 0;
  }
  __syncthreads();

  // weight B-frags in VGPRs (j = kw*10+ic)
  bf16x8 wf[20];
#pragma unroll
  for (int kk = 0; kk < 20; kk++) {
    union { ushort u[8]; bf16x8 v; } bu;
    const int s = kk >> 2;
#pragma unroll
    for (int i = 0; i < 8; i++) {
      const int j = (kk & 3) * 16 + q * 8 + i;
      float wv = 0.f;
      if ((pos < 20) && (j < 50))
        wv = w2c[pos * 250 + (j % 10) * 25 + s * 5 + (j / 10)];
      bu.u[i] = f2b(wv);
    }
    wf[kk] = bu.v;
  }
  const float bias = (pos < 20) ? b2c[pos] : 0.f;

  const ushort* pp = (const ushort*)pool1 + (size_t)n * 9610;
  const int ic0 = (2 * lane) % 10;
  const int pos_e = (pos < 28) ? pos : pos - 16;
  const int pe10q8 = pos_e * 10 + q * 8;

  uint gv0, gv1, gv2;
#define GLOAD(t)                                                        \
  {                                                                     \
    const ushort* s_ = pp + ((t) - 1) * 310;                            \
    gv0 = *(const uint*)(s_ + 2 * lane);                                \
    gv1 = *(const uint*)(s_ + 2 * (lane + 64));                         \
    gv2 = (lane < 27) ? *(const uint*)(s_ + 2 * (lane + 128)) : 0u;     \
  }
#define GS1(c_, gv_)                                                    \
  {                                                                     \
    const int u2_ = lane + 64 * c_;                                     \
    if (c_ < 2 || lane < 27) {                                          \
      const int ia_ = (ic0 + 8 * c_) % 10;                              \
      const int ib_ = (ia_ == 9) ? 0 : ia_ + 1;                         \
      float a0_ = bf2f((ushort)(gv_ & 0xffffu));                        \
      float a1_ = bf2f((ushort)(gv_ >> 16));                            \
      a0_ = fmaxf(fmaf(a0_, ssc[ia_], ssh[ia_]), 0.f);                  \
      a1_ = fmaxf(fmaf(a1_, ssc[ib_], ssh[ib_]), 0.f);                  \
      *(uint*)(dst_ + 2 * u2_) = (uint)f2b(a0_) | ((uint)f2b(a1_) << 16);\
    }                                                                   \
  }
#define GSTORE(t)                                                       \
  {                                                                     \
    ushort* dst_ = &Rw[(t) & 3][10];                                    \
    GS1(0, gv0) GS1(1, gv1) GS1(2, gv2)                                 \
  }
#define FLOAD(t, ss)                                                    \
  {                                                                     \
    const ushort* bp_ = &Rw[(t) & 3][pe10q8];                           \
    _Pragma("unroll")                                                   \
    for (int sub_ = 0; sub_ < 4; sub_++) {                              \
      union { uint u[4]; bf16x8 v; } au_;                               \
      au_.u[0] = *(const uint*)(bp_ + sub_ * 16 + 0);                   \
      au_.u[1] = *(const uint*)(bp_ + sub_ * 16 + 2);                   \
      au_.u[2] = *(const uint*)(bp_ + sub_ * 16 + 4);                   \
      au_.u[3] = *(const uint*)(bp_ + sub_ * 16 + 6);                   \
      sets[ss][sub_] = au_.v;                                           \
    }                                                                   \
  }

  bf16x8 sets[5][4];
  const bf16x8 zfrag = (short)0;
#pragma unroll
  for (int s = 0; s < 4; s++) sets[0][s] = zfrag;   // t=0 border row

  GLOAD(1) GSTORE(1)
  GLOAD(2) GSTORE(2)
  GLOAD(3) GSTORE(3)
  GLOAD(4) GSTORE(4)
  GLOAD(5)
  __asm__ __volatile__("s_waitcnt lgkmcnt(0)" ::: "memory");
  FLOAD(1, 1) FLOAD(2, 2) FLOAD(3, 3)

  float php[8];
  for (int rb = 0; rb < 30; rb += 5) {
#pragma unroll
    for (int rr = 0; rr < 5; rr++) {
      const int r = rb + rr;
      __asm__ __volatile__("s_waitcnt lgkmcnt(0)" ::: "memory");
      if (r <= 27) FLOAD(r + 4, (rr + 4) % 5)
      if (r <= 26) GSTORE(r + 5)
      if (r <= 25) GLOAD(r + 6)
      if (r < 28) {
        f32x16 accA, accB;
#pragma unroll
        for (int z = 0; z < 16; z++) { accA[z] = 0.f; accB[z] = 0.f; }
#pragma unroll
        for (int kh = 0; kh < 5; kh++) {
          const int si = (rr + kh) % 5;
#pragma unroll
          for (int sub = 0; sub < 4; sub++) {
            if (kh & 1)
              accB = __builtin_amdgcn_mfma_f32_32x32x16_bf16(
                  sets[si][sub], wf[kh * 4 + sub], accB, 0, 0, 0);
            else
              accA = __builtin_amdgcn_mfma_f32_32x32x16_bf16(
                  sets[si][sub], wf[kh * 4 + sub], accA, 0, 0, 0);
          }
        }
        float hp[8];
#pragma unroll
        for (int p = 0; p < 8; p++)
          hp[p] = fmaxf(accA[2 * p] + accB[2 * p],
                        accA[2 * p + 1] + accB[2 * p + 1]);
        if ((r & 1) == 0) {
#pragma unroll
          for (int p = 0; p < 8; p++) php[p] = hp[p];
        } else if (pos < 20) {
          const int ph = r >> 1;
          ushort* dst = (ushort*)featb + (size_t)n * 4160 + pos * 196 + ph * 14;
#pragma unroll
          for (int j = 0; j < 4; j++) {
            const int pw = 4 * j + 2 * q;
            if (pw + 1 < 14) {
              const float v0 =
                  fmaxf(fmaxf(php[2 * j], hp[2 * j]) + bias, 0.f);
              const float v1 =
                  fmaxf(fmaxf(php[2 * j + 1], hp[2 * j + 1]) + bias, 0.f);
              *(uint*)(dst + pw) = (uint)f2b(v0) | ((uint)f2b(v1) << 16);
            }
          }
        }
      }
    }
  }
#undef GLOAD
#undef GS1
#undef GSTORE
#undef FLOAD
}

// ---------------- K3b: cast ew1 -> bf16 [1024][4160] -----------------------
__global__ __launch_bounds__(TPB) void k_castw1(
    const float* __restrict__ ew1, ushort* __restrict__ w1b)
{
  const int o = blockIdx.x;
  const int tid = threadIdx.x;
  const float* srow = ew1 + (size_t)o * 3920;
  ushort* drow = w1b + (size_t)o * 4160;
  for (int i = tid; i < 1040; i += TPB) {
    const int k4 = i * 4;
    ushort4 r;
    if (k4 < 3920) {
      const float4 v = *(const float4*)(srow + k4);
      r.x = f2b(v.x); r.y = f2b(v.y); r.z = f2b(v.z); r.w = f2b(v.w);
    } else {
      r.x = 0; r.y = 0; r.z = 0; r.w = 0;
    }
    *(ushort4*)(drow + k4) = r;
  }
}

// ---------------- K4a: gate fc1 partial GEMM (atomic K-split) --------------
__global__ __launch_bounds__(TPB) void k_gate1(
    const ushort* __restrict__ featb, const float* __restrict__ gw1,
    float* __restrict__ graw)
{
  __shared__ float sf[64 * 113];
  __shared__ float sw[64 * 113];
  const int tid = threadIdx.x;
  const int r0 = blockIdx.x * 64;
  const int kz = blockIdx.y;
  const int ty = tid >> 4, tx = tid & 15;
  float acc[4][4] = {{0.f}};
  for (int c = kz; c < 35; c += 4) {
    const int k0 = c * 112;
    for (int i = tid; i < 896; i += TPB) {
      const int row = i / 14, k8 = (i - row * 14) * 8;
      uint4 v = *(const uint4*)(featb + (size_t)(r0 + row) * 4160 + k0 + k8);
      const ushort* pv = (const ushort*)&v;
      float* d = &sf[row * 113 + k8];
#pragma unroll
      for (int t = 0; t < 8; t++) d[t] = bf2f(pv[t]);
    }
    for (int i = tid; i < 1792; i += TPB) {
      const int row = i / 28, c4 = (i - row * 28) * 4;
      float4 u = *(const float4*)(gw1 + (size_t)row * 3920 + k0 + c4);
      float* e = &sw[row * 113 + c4];
      e[0] = u.x; e[1] = u.y; e[2] = u.z; e[3] = u.w;
    }
    __syncthreads();
    for (int k = 0; k < 112; k++) {
      float a_[4], w_[4];
#pragma unroll
      for (int i = 0; i < 4; i++) a_[i] = sf[(ty * 4 + i) * 113 + k];
#pragma unroll
      for (int j = 0; j < 4; j++) w_[j] = sw[(tx * 4 + j) * 113 + k];
#pragma unroll
      for (int i = 0; i < 4; i++)
#pragma unroll
        for (int j = 0; j < 4; j++) acc[i][j] = fmaf(a_[i], w_[j], acc[i][j]);
    }
    __syncthreads();
  }
#pragma unroll
  for (int i = 0; i < 4; i++)
#pragma unroll
    for (int j = 0; j < 4; j++)
      atomicAdd(&graw[(size_t)(r0 + ty * 4 + i) * 64 + tx * 4 + j], acc[i][j]);
}

// ---------------- K4b: gate logits + top2 softmax + expert counts ----------
__global__ __launch_bounds__(TPB) void k_gate2(
    const float* __restrict__ graw, const float* __restrict__ gb1,
    const float* __restrict__ gw2, const float* __restrict__ gb2,
    int* __restrict__ sel0, int* __restrict__ sel1,
    float* __restrict__ wt0, float* __restrict__ wt1, int* __restrict__ counts)
{
  __shared__ float sw2[512], sb1[64], sb2[8];
  const int tid = threadIdx.x;
  for (int i = tid; i < 512; i += TPB) sw2[i] = gw2[i];
  if (tid < 64) sb1[tid] = gb1[tid];
  if (tid < 8) sb2[tid] = gb2[tid];
  __syncthreads();
  const int r = blockIdx.x * TPB + tid;
  float l[8];
#pragma unroll
  for (int c = 0; c < 8; c++) l[c] = sb2[c];
  const float* gr = graw + (size_t)r * 64;
  for (int k = 0; k < 64; k++) {
    const float hv = fmaxf(gr[k] + sb1[k], 0.f);
#pragma unroll
    for (int c = 0; c < 8; c++) l[c] = fmaf(hv, sw2[c * 64 + k], l[c]);
  }
  float v0 = -1e30f, v1 = -1e30f; int i0 = 0, i1 = 0;
#pragma unroll
  for (int c = 0; c < 8; c++) {
    const float lv = l[c];
    if (lv > v0) { v1 = v0; i1 = i0; v0 = lv; i0 = c; }
    else if (lv > v1) { v1 = lv; i1 = c; }
  }
  const float e1 = expf(v1 - v0);
  const float inv = 1.f / (1.f + e1);
  sel0[r] = i0; sel1[r] = i1; wt0[r] = inv; wt1[r] = e1 * inv;
  atomicAdd(&counts[i0], 1);
  atomicAdd(&counts[i1], 1);
}

// ---------------- K5: padded offsets + entry-list init ---------------------
__global__ void k_prep(int* __restrict__ hdrI, int* __restrict__ entrow)
{
  const int tid = threadIdx.x;
  if (tid == 0) {
    int run = 0;
    for (int e = 0; e < 8; e++) {
      const int c = hdrI[e];
      const int pc = (c + 31) & ~31;
      hdrI[16 + e] = pc;
      hdrI[24 + e] = run;
      run += pc;
    }
    hdrI[32] = run;
  }
  if (tid >= 8 && tid < 16) hdrI[tid] = 0;
  for (int i = tid; i < 8448; i += TPB) entrow[i] = -1;
}

// ---------------- K5b: scatter rows to expert entry lists ------------------
__global__ void k_scatter(const int* __restrict__ sel0, const int* __restrict__ sel1,
                          int* __restrict__ hdrI, int* __restrict__ entrow,
                          int* __restrict__ p0, int* __restrict__ p1)
{
  const int r = blockIdx.x * TPB + threadIdx.x;
  const int e0 = sel0[r];
  int pos = atomicAdd(&hdrI[8 + e0], 1) + hdrI[24 + e0];
  entrow[pos] = r; p0[r] = pos;
  const int e1 = sel1[r];
  pos = atomicAdd(&hdrI[8 + e1], 1) + hdrI[24 + e1];
  entrow[pos] = r; p1[r] = pos;
}

// ---------------- K6: dense MFMA fc1 -> h1 bf16 [4096][1024] ---------------
__global__ __launch_bounds__(512) void k_fc1(
    const ushort* __restrict__ featb, const ushort* __restrict__ w1b,
    const float* __restrict__ eb1, __hip_bfloat16* __restrict__ h1b)
{
  __shared__ ushort As[128 * 72];
  __shared__ ushort Bs[128 * 72];
  const int tid = threadIdx.x;
  const int r0 = blockIdx.x * 128;
  const int c0 = blockIdx.y * 128;
  const int w = tid >> 6, lane = tid & 63;
  const int wr = (w >> 1) * 32, wc = (w & 1) * 64;
  const int m = lane & 15, q = lane >> 4;
  f32x4 acc[2][4];
#pragma unroll
  for (int i = 0; i < 2; i++)
#pragma unroll
    for (int j = 0; j < 4; j++) acc[i][j] = 0.f;

  for (int kc = 0; kc < 4096; kc += 64) {
#pragma unroll
    for (int i = 0; i < 2; i++) {
      const int u = tid + 512 * i;
      const int row = u >> 3, k8 = (u & 7) * 8;
      *(uint4*)(&As[row * 72 + k8]) =
          *(const uint4*)(featb + (size_t)(r0 + row) * 4160 + kc + k8);
      *(uint4*)(&Bs[row * 72 + k8]) =
          *(const uint4*)(w1b + (size_t)(c0 + row) * 4160 + kc + k8);
    }
    __syncthreads();
#pragma unroll
    for (int kk = 0; kk < 64; kk += 32) {
      bf16x8 af[2], bf[4];
#pragma unroll
      for (int t = 0; t < 2; t++)
        af[t] = *(const bf16x8*)(&As[(wr + t * 16 + m) * 72 + kk + q * 8]);
#pragma unroll
      for (int t = 0; t < 4; t++)
        bf[t] = *(const bf16x8*)(&Bs[(wc + t * 16 + m) * 72 + kk + q * 8]);
#pragma unroll
      for (int ti = 0; ti < 2; ti++)
#pragma unroll
        for (int tj = 0; tj < 4; tj++)
          acc[ti][tj] = __builtin_amdgcn_mfma_f32_16x16x32_bf16(
              af[ti], bf[tj], acc[ti][tj], 0, 0, 0);
    }
    __syncthreads();
  }
#pragma unroll
  for (int tj = 0; tj < 4; tj++) {
    const int c = c0 + wc + tj * 16 + m;
    const float bb = eb1[c];
#pragma unroll
    for (int ti = 0; ti < 2; ti++) {
      const int rbase = r0 + wr + ti * 16 + q * 4;
#pragma unroll
      for (int i = 0; i < 4; i++) {
        const float v = fmaxf(acc[ti][tj][i] + bb, 0.f);
        h1b[(size_t)(rbase + i) * 1024 + c] = __float2bfloat16(v);
      }
    }
  }
}

// ---------------- K7: dense fc2 -> h2 fp32 [4096][512] ---------------------
__global__ __launch_bounds__(TPB) void k_fc2(
    const __hip_bfloat16* __restrict__ h1b, const float* __restrict__ ew2,
    const float* __restrict__ eb2, float* __restrict__ h2)
{
  __shared__ float h1s[64 * 132];
  __shared__ ushort w2s[128 * 72];
  const int tid = threadIdx.x;
  const int r0 = blockIdx.x * 64;
  const int e = blockIdx.y;
  const ushort* hp = (const ushort*)h1b;
#pragma unroll
  for (int i = 0; i < 4; i++) {
    const int u = tid + 256 * i;
    const int row = u >> 4, k8 = (u & 15) * 8;
    uint4 v = *(const uint4*)(hp + (size_t)(r0 + row) * 1024 + e * 128 + k8);
    const ushort* pv = (const ushort*)&v;
    float* d = &h1s[row * 132 + k8];
#pragma unroll
    for (int t = 0; t < 8; t++) d[t] = bf2f(pv[t]);
  }
#pragma unroll
  for (int i = 0; i < 8; i++) {
    const int u = tid + 256 * i;
    const int nn = u >> 5, k4 = (u & 31) * 4;
    const float4 v = *(const float4*)(ew2 + (size_t)e * 8192 + nn * 128 + k4);
    w2s[(k4 + 0) * 72 + nn] = f2b(v.x);
    w2s[(k4 + 1) * 72 + nn] = f2b(v.y);
    w2s[(k4 + 2) * 72 + nn] = f2b(v.z);
    w2s[(k4 + 3) * 72 + nn] = f2b(v.w);
  }
  __syncthreads();
  const int ty = tid >> 4, tx = tid & 15;
  float acc[4][4] = {{0.f}};
  for (int k4 = 0; k4 < 32; k4++) {
    f32x4 a4[4];
#pragma unroll
    for (int i = 0; i < 4; i++)
      a4[i] = *(const f32x4*)(&h1s[(ty * 4 + i) * 132 + k4 * 4]);
#pragma unroll
    for (int kk = 0; kk < 4; kk++) {
      const ushort4 wu = *(const ushort4*)(&w2s[(k4 * 4 + kk) * 72 + tx * 4]);
      const float w0 = bf2f(wu.x), w1 = bf2f(wu.y);
      const float w2_ = bf2f(wu.z), w3 = bf2f(wu.w);
#pragma unroll
      for (int i = 0; i < 4; i++) {
        acc[i][0] = fmaf(a4[i][kk], w0, acc[i][0]);
        acc[i][1] = fmaf(a4[i][kk], w1, acc[i][1]);
        acc[i][2] = fmaf(a4[i][kk], w2_, acc[i][2]);
        acc[i][3] = fmaf(a4[i][kk], w3, acc[i][3]);
      }
    }
  }
  const f32x4 bb = *(const f32x4*)(eb2 + e * 64 + tx * 4);
#pragma unroll
  for (int i = 0; i < 4; i++) {
    f32x4 r;
#pragma unroll
    for (int j = 0; j < 4; j++) r[j] = fmaxf(acc[i][j] + bb[j], 0.f);
    *(f32x4*)(h2 + (size_t)(r0 + ty * 4 + i) * 512 + e * 64 + tx * 4) = r;
  }
}

// ---------------- K8: grouped fc3 -> eo [pos][1000] ------------------------
__global__ __launch_bounds__(TPB) void k_fc3(
    const float* __restrict__ h2, const float* __restrict__ ew3,
    const float* __restrict__ eb3, const int* __restrict__ hdrI,
    const int* __restrict__ entrow, float* __restrict__ eo)
{
  __shared__ float h2s[32 * 68];
  __shared__ float w3s[64 * 132];
  const int e = blockIdx.y;
  const int pcnt = hdrI[16 + e];
  if ((int)blockIdx.x * 32 >= pcnt) return;
  const int base = hdrI[24 + e] + blockIdx.x * 32;
  const int tid = threadIdx.x;
  for (int i = tid; i < 512; i += TPB) {
    const int row = i >> 4, k4 = (i & 15) * 4;
    const int rr = entrow[base + row];
    f32x4 v = 0.f;
    if (rr >= 0) v = *(const f32x4*)(h2 + (size_t)rr * 512 + e * 64 + k4);
    *(f32x4*)(&h2s[row * 68 + k4]) = v;
  }
  const int ty = tid >> 5, tx = tid & 31;
  const float* w3p = ew3 + (size_t)e * 64000;
  const float* b3p = eb3 + (size_t)e * 1000;
  for (int nc = 0; nc < 8; nc++) {
    const int o0 = nc * 128;
    for (int i = tid; i < 2048; i += TPB) {
      const int oo = i >> 4, k4 = (i & 15) * 4;
      const int o = o0 + oo;
      f32x4 u = 0.f;
      if (o < 1000) u = *(const f32x4*)(w3p + (size_t)o * 64 + k4);
      w3s[(k4 + 0) * 132 + oo] = u[0];
      w3s[(k4 + 1) * 132 + oo] = u[1];
      w3s[(k4 + 2) * 132 + oo] = u[2];
      w3s[(k4 + 3) * 132 + oo] = u[3];
    }
    __syncthreads();
    float acc[4][4] = {{0.f}};
    for (int k4 = 0; k4 < 16; k4++) {
      f32x4 a4[4], w4[4];
#pragma unroll
      for (int i = 0; i < 4; i++)
        a4[i] = *(const f32x4*)(&h2s[(ty * 4 + i) * 68 + k4 * 4]);
#pragma unroll
      for (int kk = 0; kk < 4; kk++)
        w4[kk] = *(const f32x4*)(&w3s[(k4 * 4 + kk) * 132 + tx * 4]);
#pragma unroll
      for (int kk = 0; kk < 4; kk++)
#pragma unroll
        for (int i = 0; i < 4; i++)
#pragma unroll
          for (int j = 0; j < 4; j++)
            acc[i][j] = fmaf(a4[i][kk], w4[kk][j], acc[i][j]);
    }
    const int o = o0 + tx * 4;
    if (o + 3 < 1000) {
      const f32x4 bb = *(const f32x4*)(b3p + o);
#pragma unroll
      for (int i = 0; i < 4; i++) {
        f32x4 r;
#pragma unroll
        for (int j = 0; j < 4; j++) r[j] = acc[i][j] + bb[j];
        *(f32x4*)(eo + (size_t)(base + ty * 4 + i) * 1000 + o) = r;
      }
    }
    __syncthreads();
  }
}

// ---------------- K9: gate-combine + log_softmax(|.|) ----------------------
__global__ __launch_bounds__(TPB) void k_out(
    const float* __restrict__ eo, const int* __restrict__ p0,
    const int* __restrict__ p1, const float* __restrict__ wt0,
    const float* __restrict__ wt1, float* __restrict__ out)
{
  __shared__ float sv[1000];
  __shared__ float sr[8];
  const int r = blockIdx.x, tid = threadIdx.x;
  const float w0 = wt0[r], w1 = wt1[r];
  const float* a = eo + (size_t)p0[r] * 1000;
  const float* b = eo + (size_t)p1[r] * 1000;
  float lmax = -3.4e38f;
  for (int o = tid; o < 1000; o += TPB) {
    const float v = fabsf(w0 * a[o] + w1 * b[o]);
    sv[o] = v;
    lmax = fmaxf(lmax, v);
  }
#pragma unroll
  for (int off = 32; off; off >>= 1) lmax = fmaxf(lmax, __shfl_down(lmax, off));
  if ((tid & 63) == 0) sr[tid >> 6] = lmax;
  __syncthreads();
  const float mx = fmaxf(fmaxf(sr[0], sr[1]), fmaxf(sr[2], sr[3]));
  float lsum = 0.f;
  for (int o = tid; o < 1000; o += TPB) lsum += expf(sv[o] - mx);
#pragma unroll
  for (int off = 32; off; off >>= 1) lsum += __shfl_down(lsum, off);
  if ((tid & 63) == 0) sr[4 + (tid >> 6)] = lsum;
  __syncthreads();
  const float lse = logf(sr[4] + sr[5] + sr[6] + sr[7]);
  const float sub = mx + lse;
  for (int o = tid; o < 1000; o += TPB)
    out[(size_t)r * 1000 + o] = sv[o] - sub;
}

// ---------------------------------------------------------------------------
extern "C" void kernel_launch(void* const* d_in, const int* in_sizes, int n_in,
                              void* d_out, int out_size, void* d_ws, size_t ws_size,
                              hipStream_t stream)
{
  (void)in_sizes; (void)n_in; (void)out_size; (void)ws_size;
  const float* x   = (const float*)d_in[0];
  const float* c1w = (const float*)d_in[1];
  const float* c1b = (const float*)d_in[2];
  const float* bng = (const float*)d_in[3];
  const float* bnb = (const float*)d_in[4];
  const float* c2w = (const float*)d_in[5];
  const float* c2b = (const float*)d_in[6];
  const float* gw1 = (const float*)d_in[7];
  const float* gb1 = (const float*)d_in[8];
  const float* gw2 = (const float*)d_in[9];
  const float* gb2 = (const float*)d_in[10];
  const float* ew1 = (const float*)d_in[11];
  const float* eb1 = (const float*)d_in[12];
  const float* ew2 = (const float*)d_in[13];
  const float* eb2 = (const float*)d_in[14];
  const float* ew3 = (const float*)d_in[15];
  const float* eb3 = (const float*)d_in[16];

  char* ws = (char*)d_ws;
  float* statsF = (float*)ws;
  int*   hdrI   = (int*)(ws + 256);
  int*   sel0   = (int*)(ws + 1024);
  int*   sel1   = (int*)(ws + 17408);
  float* wt0    = (float*)(ws + 33792);
  float* wt1    = (float*)(ws + 50176);
  int*   p0     = (int*)(ws + 66560);
  int*   p1     = (int*)(ws + 82944);
  int*   entrow = (int*)(ws + 99328);
  float* graw   = (float*)(ws + 133120);
  float* eo     = (float*)(ws + 1181696);
  __hip_bfloat16* h1b = (__hip_bfloat16*)(ws + 34973696);
  float* h2     = (float*)(ws + 43362304);
  __hip_bfloat16* pool1 = (__hip_bfloat16*)(ws + 51750912);
  __hip_bfloat16* featb = (__hip_bfloat16*)(ws + 130476032);
  ushort* w1b   = (ushort*)(ws + 164554752);

  hipMemsetAsync(ws, 0, 512, stream);
  hipMemsetAsync(graw, 0, 4096 * 64 * sizeof(float), stream);

  k_castw1 <<<1024, TPB, 0, stream>>>(ew1, w1b);
  k_conv1  <<<8192, TPB, 0, stream>>>(x, c1w, c1b, pool1, statsF);
  k_bnfin  <<<1, 64, 0, stream>>>(bng, bnb, statsF);
  k_conv2  <<<1024, TPB, 0, stream>>>(pool1, statsF, c2w, c2b, featb);
  k_gate1  <<<dim3(64, 4), TPB, 0, stream>>>((const ushort*)featb, gw1, graw);
  k_gate2  <<<16, TPB, 0, stream>>>(graw, gb1, gw2, gb2, sel0, sel1, wt0, wt1, hdrI);
  k_prep   <<<1, TPB, 0, stream>>>(hdrI, entrow);
  k_scatter<<<16, TPB, 0, stream>>>(sel0, sel1, hdrI, entrow, p0, p1);
  k_fc1    <<<dim3(32, 8), 512, 0, stream>>>((const ushort*)featb, w1b, eb1, h1b);
  k_fc2    <<<dim3(64, 8), TPB, 0, stream>>>(h1b, ew2, eb2, h2);
  k_fc3    <<<dim3(128, 8), TPB, 0, stream>>>(h2, ew3, eb3, hdrI, entrow, eo);
  k_out    <<<4096, TPB, 0, stream>>>(eo, p0, p1, wt0, wt1, (float*)d_out);
}

// Round 5
// 1126.618 us; speedup vs baseline: 1.3145x; 1.1060x over previous
//
#include <hip/hip_runtime.h>
#include <hip/hip_bf16.h>

// ---------------------------------------------------------------------------
// Net_83674552861196 — round 10: conv1 half-split + RELAXED bounds (4).
//  - Rounds 8/9 diagnosis: forcing waves/EU floor 8 (budget 64) or 6
//    (budget 80) makes the gfx950 allocator split the unified file evenly
//    into Arch/Acc halves when MFMA is present: VGPR_Count landed at
//    budget/2 (32/40) < ~55 arch demand -> hot-loop spill -> 1.5 GB
//    scratch traffic. The floor is NOT what sets achieved occupancy;
//    actual allocation is. Round 7 (bounds 4, budget 128) allocated
//    52 arch + 8 acc = 60 -> HW allows 8 waves/EU from registers.
//  - Fix: keep the 19 KB half-split LDS (8 blocks/CU possible) and use
//    bounds 4 so the allocator has headroom: no spill, occupancy rises
//    naturally to ~8 blocks/CU via the small LDS footprint.
//  - Everything else unchanged from round 9.
// ---------------------------------------------------------------------------

#define TPB 256

typedef __attribute__((ext_vector_type(8))) short bf16x8;
typedef __attribute__((ext_vector_type(4))) float f32x4;
typedef __attribute__((ext_vector_type(16))) float f32x16;

__device__ __forceinline__ float bf2f(unsigned short u) {
  return __uint_as_float(((unsigned)u) << 16);
}
__device__ __forceinline__ ushort f2b(float f) {
  __hip_bfloat16 h = __float2bfloat16(f);
  return *(ushort*)&h;
}

// ---------------- K1: conv1 (MFMA) + raw-maxpool + BN statistics -----------
// out(r,pos,oc) = sum_{kh} sum_{j<20, j=kw*4+ic, ic<3} Row[r+kh][pos*4+j]*W
// Row[t][u] (u = pcol*4+ic) = x[ic][t-1][pcol-1], zero borders.
// Block = (image n, half h): h=0 -> rows 0..31 (slices t=0..35),
//                            h=1 -> rows 32..61 (slices t=32..65).
// Local slice lt = t - 32*h; both halves: row rr uses lt = rr..rr+4.
__global__ __launch_bounds__(TPB, 4) void k_conv1(
    const float* __restrict__ x, const float* __restrict__ w1c,
    const float* __restrict__ b1c, __hip_bfloat16* __restrict__ pool1,
    float* __restrict__ stats)
{
  __shared__ uint4 imgI4[1190];          // 19040 B (36 slices + read guard)
  __shared__ float sred[20];
  ushort* imgI = (ushort*)imgI4;
  const int tid = threadIdx.x;
  const int lane = tid & 63;
  const int w = tid >> 6;
  const int n = blockIdx.x >> 1;
  const int h = blockIdx.x & 1;
  const int oc = lane & 15;
  const int q = lane >> 4;
  const int c0 = w * 16;
  const int r0 = h * 32;

  {
    const uint4 z = {0u, 0u, 0u, 0u};
    for (int i = tid; i < 1190; i += TPB) imgI4[i] = z;
    if (tid < 20) sred[tid] = 0.f;
  }
  __syncthreads();

  // stage needed slices, channel-interleaved (ic slot 3 = 0)
  {
    const float* xp = x + (size_t)n * 12288;
    const int nit = h ? 528 : 560;          // (33 or 35 rows) x 16 col-groups
    const int growbase = h ? 31 : 0;
    for (int i = tid; i < nit; i += TPB) {
      const int lr = i >> 4, col0 = (i & 15) * 4;
      const int grow = growbase + lr;       // global image row
      const int lt = h ? lr : (lr + 1);     // local slice index
      const float* xr = xp + grow * 64 + col0;
      const float4 v0 = *(const float4*)(xr);
      const float4 v1 = *(const float4*)(xr + 4096);
      const float4 v2 = *(const float4*)(xr + 8192);
      ushort* d = &imgI[((size_t)lt * 66 + (col0 + 1)) * 4];
      uint2 t0, t1, t2, t3;
      t0.x = (uint)f2b(v0.x) | ((uint)f2b(v1.x) << 16); t0.y = (uint)f2b(v2.x);
      t1.x = (uint)f2b(v0.y) | ((uint)f2b(v1.y) << 16); t1.y = (uint)f2b(v2.y);
      t2.x = (uint)f2b(v0.z) | ((uint)f2b(v1.z) << 16); t2.y = (uint)f2b(v2.z);
      t3.x = (uint)f2b(v0.w) | ((uint)f2b(v1.w) << 16); t3.y = (uint)f2b(v2.w);
      *(uint2*)(d + 0)  = t0;
      *(uint2*)(d + 4)  = t1;
      *(uint2*)(d + 8)  = t2;
      *(uint2*)(d + 12) = t3;
    }
  }

  // weight B-frags: 5 kh K-steps, named registers (no arrays!).
  // slot j = kw*4+ic (j<20, ic<3 real), K padded to 32 with zeros.
  bf16x8 wf0, wf1, wf2, wf3, wf4;
#define WLOAD(dst_, kh_)                                                \
  {                                                                     \
    union { ushort u[8]; bf16x8 v; } bu_;                               \
    _Pragma("unroll")                                                   \
    for (int i = 0; i < 8; i++) {                                       \
      const int j = q * 8 + i;                                          \
      float wv = 0.f;                                                   \
      if (oc < 10 && j < 20 && (j & 3) < 3)                             \
        wv = w1c[oc * 75 + (j & 3) * 25 + (kh_) * 5 + (j >> 2)];        \
      bu_.u[i] = f2b(wv);                                               \
    }                                                                   \
    dst_ = bu_.v;                                                       \
  }
  WLOAD(wf0, 0) WLOAD(wf1, 1) WLOAD(wf2, 2) WLOAD(wf3, 3) WLOAD(wf4, 4)
#undef WLOAD
  const float bias = (oc < 10) ? b1c[oc] : 0.f;

  __syncthreads();

  const int pos_A = c0 + oc;                    // A-matrix row (output col)
  const ushort* abase = &imgI[pos_A * 4 + q * 8];
  const int pwb = (c0 >> 1) + q * 2;

#define ALOADV(dst_, lt_)                                               \
  {                                                                     \
    const ushort* p_ = abase + (lt_) * 264;                             \
    union { uint u[4]; bf16x8 v; } au_;                                 \
    const uint2 lo_ = *(const uint2*)(p_);                              \
    const uint2 hi_ = *(const uint2*)(p_ + 4);                          \
    au_.u[0] = lo_.x; au_.u[1] = lo_.y;                                 \
    au_.u[2] = hi_.x; au_.u[3] = hi_.y;                                 \
    dst_ = au_.v;                                                       \
  }

  const float vm0 = ((c0 + q * 4 + 0) < 62) ? 1.f : 0.f;
  const float vm1 = ((c0 + q * 4 + 1) < 62) ? 1.f : 0.f;
  const float vm2 = ((c0 + q * 4 + 2) < 62) ? 1.f : 0.f;
  const float vm3 = ((c0 + q * 4 + 3) < 62) ? 1.f : 0.f;

  float ts = 0.f, tss = 0.f;
  float pp0 = 0.f, pp1 = 0.f;

#define ROWSTEP(rr_, sA, sB, sC, sD, sE)                                \
  {                                                                     \
    ALOADV(sE, (rr_) + 4)                                               \
    f32x4 accA = {0.f, 0.f, 0.f, 0.f};                                  \
    f32x4 accB = {0.f, 0.f, 0.f, 0.f};                                  \
    accA = __builtin_amdgcn_mfma_f32_16x16x32_bf16(sA, wf0, accA, 0, 0, 0); \
    accB = __builtin_amdgcn_mfma_f32_16x16x32_bf16(sB, wf1, accB, 0, 0, 0); \
    accA = __builtin_amdgcn_mfma_f32_16x16x32_bf16(sC, wf2, accA, 0, 0, 0); \
    accB = __builtin_amdgcn_mfma_f32_16x16x32_bf16(sD, wf3, accB, 0, 0, 0); \
    accA = __builtin_amdgcn_mfma_f32_16x16x32_bf16(sE, wf4, accA, 0, 0, 0); \
    const float y0 = accA[0] + accB[0] + bias;                          \
    const float y1 = accA[1] + accB[1] + bias;                          \
    const float y2 = accA[2] + accB[2] + bias;                          \
    const float y3 = accA[3] + accB[3] + bias;                          \
    float t0 = y0 * vm0; ts += t0; tss = fmaf(t0, y0, tss);             \
    float t1 = y1 * vm1; ts += t1; tss = fmaf(t1, y1, tss);             \
    float t2 = y2 * vm2; ts += t2; tss = fmaf(t2, y2, tss);             \
    float t3 = y3 * vm3; ts += t3; tss = fmaf(t3, y3, tss);             \
    const float p0v = fmaxf(y0, y1), p1v = fmaxf(y2, y3);               \
    if (((rr_) & 1) == 0) {                                             \
      pp0 = p0v; pp1 = p1v;                                             \
    } else if (oc < 10) {                                               \
      const int ph_ = (r0 + (rr_)) >> 1;                                \
      __hip_bfloat16* dst2_ =                                           \
          pool1 + (size_t)n * 9610 + (size_t)(ph_ * 31) * 10 + oc;      \
      const float q0_ = fmaxf(pp0, p0v), q1_ = fmaxf(pp1, p1v);         \
      dst2_[pwb * 10] = __float2bfloat16(q0_);                          \
      if (pwb + 1 < 31) dst2_[(pwb + 1) * 10] = __float2bfloat16(q1_);  \
    }                                                                   \
  }

  bf16x8 s0, s1, s2, s3, s4;
  ALOADV(s0, 0) ALOADV(s1, 1) ALOADV(s2, 2) ALOADV(s3, 3)

  for (int rb = 0; rb < 30; rb += 5) {
    ROWSTEP(rb + 0, s0, s1, s2, s3, s4)
    ROWSTEP(rb + 1, s1, s2, s3, s4, s0)
    ROWSTEP(rb + 2, s2, s3, s4, s0, s1)
    ROWSTEP(rb + 3, s3, s4, s0, s1, s2)
    ROWSTEP(rb + 4, s4, s0, s1, s2, s3)
  }
  if (h == 0) {
    // rows 30, 31 of half 0 (register mapping back to identity after 6 turns)
    ROWSTEP(30, s0, s1, s2, s3, s4)
    ROWSTEP(31, s1, s2, s3, s4, s0)
  }
#undef ROWSTEP
#undef ALOADV

  if (oc < 10) {
    atomicAdd(&sred[oc], ts);
    atomicAdd(&sred[10 + oc], tss);
  }
  __syncthreads();
  if (tid < 20) atomicAdd(&stats[tid], sred[tid]);
}

// ---------------- K2: finalize BN scale/shift ------------------------------
__global__ void k_bnfin(const float* __restrict__ bng,
                        const float* __restrict__ bnb,
                        float* __restrict__ stats)
{
  const int c = threadIdx.x;
  if (c < 10) {
    const float Ninv = 1.f / (4096.f * 3844.f);
    const float mean = stats[c] * Ninv;
    const float var = stats[10 + c] * Ninv - mean * mean;
    const float sc = bng[c] * rsqrtf(var + 1e-5f);
    stats[20 + c] = sc;
    stats[30 + c] = bnb[c] - mean * sc;
  }
}

// ---------------- K3: conv2 on MFMA, one image per wave --------------------
// out(r,pos,oc) = sum_{kh} sum_{j<50, j=kw*10+ic} Row[r+kh][pos*10+j] * W[oc][j,kh]
// Row[t][u] (u=pw_pad*10+ic) = BN-relu(pool1[n][t-1][pw_pad-1][ic]), zero borders.
// M=pos(28,pad32), N=oc(20,pad32), K=5 x 64 (j>=50 has zero B).
__global__ __launch_bounds__(TPB, 2) void k_conv2(
    const __hip_bfloat16* __restrict__ pool1, const float* __restrict__ stats,
    const float* __restrict__ w2c, const float* __restrict__ b2c,
    __hip_bfloat16* __restrict__ featb)
{
  __shared__ ushort R[4][4][344];          // [wave-image][slot][u], 11 KB
  __shared__ float ssc[10], ssh[10];
  const int tid = threadIdx.x;
  const int w = tid >> 6, lane = tid & 63;
  const int n = blockIdx.x * 4 + w;
  const int pos = lane & 31, q = lane >> 5;
  ushort (*Rw)[344] = R[w];

  if (tid < 10) { ssc[tid] = stats[20 + tid]; ssh[tid] = stats[30 + tid]; }
  // zero border cols of own 4 slots: u in [0,10) and [320,344)
  for (int i = lane; i < 136; i += 64) {
    const int s = i / 34, uu = i - 34 * s;
    Rw[s][(uu < 10) ? uu : (310 + uu)] = 0;
  }
  // zero fc1 K-pad cols for this image
  if (lane < 60) {
    uint* z = (uint*)((ushort*)featb + (size_t)n * 4160 + 3920);
    z[lane] = 0; z[lane + 60] = 0;
  }
  __syncthreads();

  // weight B-frags in VGPRs (j = kw*10+ic)
  bf16x8 wf[20];
#pragma unroll
  for (int kk = 0; kk < 20; kk++) {
    union { ushort u[8]; bf16x8 v; } bu;
    const int s = kk >> 2;
#pragma unroll
    for (int i = 0; i < 8; i++) {
      const int j = (kk & 3) * 16 + q * 8 + i;
      float wv = 0.f;
      if ((pos < 20) && (j < 50))
        wv = w2c[pos * 250 + (j % 10) * 25 + s * 5 + (j / 10)];
      bu.u[i] = f2b(wv);
    }
    wf[kk] = bu.v;
  }
  const float bias = (pos < 20) ? b2c[pos] : 0.f;

  const ushort* pp = (const ushort*)pool1 + (size_t)n * 9610;
  const int ic0 = (2 * lane) % 10;
  const int pos_e = (pos < 28) ? pos : pos - 16;
  const int pe10q8 = pos_e * 10 + q * 8;

  uint gv0, gv1, gv2;
#define GLOAD(t)                                                        \
  {                                                                     \
    const ushort* s_ = pp + ((t) - 1) * 310;                            \
    gv0 = *(const uint*)(s_ + 2 * lane);                                \
    gv1 = *(const uint*)(s_ + 2 * (lane + 64));                         \
    gv2 = (lane < 27) ? *(const uint*)(s_ + 2 * (lane + 128)) : 0u;     \
  }
#define GS1(c_, gv_)                                                    \
  {                                                                     \
    const int u2_ = lane + 64 * c_;                                     \
    if (c_ < 2 || lane < 27) {                                          \
      const int ia_ = (ic0 + 8 * c_) % 10;                              \
      const int ib_ = (ia_ == 9) ? 0 : ia_ + 1;                         \
      float a0_ = bf2f((ushort)(gv_ & 0xffffu));                        \
      float a1_ = bf2f((ushort)(gv_ >> 16));                            \
      a0_ = fmaxf(fmaf(a0_, ssc[ia_], ssh[ia_]), 0.f);                  \
      a1_ = fmaxf(fmaf(a1_, ssc[ib_], ssh[ib_]), 0.f);                  \
      *(uint*)(dst_ + 2 * u2_) = (uint)f2b(a0_) | ((uint)f2b(a1_) << 16);\
    }                                                                   \
  }
#define GSTORE(t)                                                       \
  {                                                                     \
    ushort* dst_ = &Rw[(t) & 3][10];                                    \
    GS1(0, gv0) GS1(1, gv1) GS1(2, gv2)                                 \
  }
#define FLOAD(t, ss)                                                    \
  {                                                                     \
    const ushort* bp_ = &Rw[(t) & 3][pe10q8];                           \
    _Pragma("unroll")                                                   \
    for (int sub_ = 0; sub_ < 4; sub_++) {                              \
      union { uint u[4]; bf16x8 v; } au_;                               \
      au_.u[0] = *(const uint*)(bp_ + sub_ * 16 + 0);                   \
      au_.u[1] = *(const uint*)(bp_ + sub_ * 16 + 2);                   \
      au_.u[2] = *(const uint*)(bp_ + sub_ * 16 + 4);                   \
      au_.u[3] = *(const uint*)(bp_ + sub_ * 16 + 6);                   \
      sets[ss][sub_] = au_.v;                                           \
    }                                                                   \
  }

  bf16x8 sets[5][4];
  const bf16x8 zfrag = (short)0;
#pragma unroll
  for (int s = 0; s < 4; s++) sets[0][s] = zfrag;   // t=0 border row

  GLOAD(1) GSTORE(1)
  GLOAD(2) GSTORE(2)
  GLOAD(3) GSTORE(3)
  GLOAD(4) GSTORE(4)
  GLOAD(5)
  __asm__ __volatile__("s_waitcnt lgkmcnt(0)" ::: "memory");
  FLOAD(1, 1) FLOAD(2, 2) FLOAD(3, 3)

  float php[8];
  for (int rb = 0; rb < 30; rb += 5) {
#pragma unroll
    for (int rr = 0; rr < 5; rr++) {
      const int r = rb + rr;
      __asm__ __volatile__("s_waitcnt lgkmcnt(0)" ::: "memory");
      if (r <= 27) FLOAD(r + 4, (rr + 4) % 5)
      if (r <= 26) GSTORE(r + 5)
      if (r <= 25) GLOAD(r + 6)
      if (r < 28) {
        f32x16 accA, accB;
#pragma unroll
        for (int z = 0; z < 16; z++) { accA[z] = 0.f; accB[z] = 0.f; }
#pragma unroll
        for (int kh = 0; kh < 5; kh++) {
          const int si = (rr + kh) % 5;
#pragma unroll
          for (int sub = 0; sub < 4; sub++) {
            if (kh & 1)
              accB = __builtin_amdgcn_mfma_f32_32x32x16_bf16(
                  sets[si][sub], wf[kh * 4 + sub], accB, 0, 0, 0);
            else
              accA = __builtin_amdgcn_mfma_f32_32x32x16_bf16(
                  sets[si][sub], wf[kh * 4 + sub], accA, 0, 0, 0);
          }
        }
        float hp[8];
#pragma unroll
        for (int p = 0; p < 8; p++)
          hp[p] = fmaxf(accA[2 * p] + accB[2 * p],
                        accA[2 * p + 1] + accB[2 * p + 1]);
        if ((r & 1) == 0) {
#pragma unroll
          for (int p = 0; p < 8; p++) php[p] = hp[p];
        } else if (pos < 20) {
          const int ph = r >> 1;
          ushort* dst = (ushort*)featb + (size_t)n * 4160 + pos * 196 + ph * 14;
#pragma unroll
          for (int j = 0; j < 4; j++) {
            const int pw = 4 * j + 2 * q;
            if (pw + 1 < 14) {
              const float v0 =
                  fmaxf(fmaxf(php[2 * j], hp[2 * j]) + bias, 0.f);
              const float v1 =
                  fmaxf(fmaxf(php[2 * j + 1], hp[2 * j + 1]) + bias, 0.f);
              *(uint*)(dst + pw) = (uint)f2b(v0) | ((uint)f2b(v1) << 16);
            }
          }
        }
      }
    }
  }
#undef GLOAD
#undef GS1
#undef GSTORE
#undef FLOAD
}

// ---------------- K3b: cast ew1 -> bf16 [1024][4160] -----------------------
__global__ __launch_bounds__(TPB) void k_castw1(
    const float* __restrict__ ew1, ushort* __restrict__ w1b)
{
  const int o = blockIdx.x;
  const int tid = threadIdx.x;
  const float* srow = ew1 + (size_t)o * 3920;
  ushort* drow = w1b + (size_t)o * 4160;
  for (int i = tid; i < 1040; i += TPB) {
    const int k4 = i * 4;
    ushort4 r;
    if (k4 < 3920) {
      const float4 v = *(const float4*)(srow + k4);
      r.x = f2b(v.x); r.y = f2b(v.y); r.z = f2b(v.z); r.w = f2b(v.w);
    } else {
      r.x = 0; r.y = 0; r.z = 0; r.w = 0;
    }
    *(ushort4*)(drow + k4) = r;
  }
}

// ---------------- K4a: gate fc1 partial GEMM (atomic K-split) --------------
__global__ __launch_bounds__(TPB) void k_gate1(
    const ushort* __restrict__ featb, const float* __restrict__ gw1,
    float* __restrict__ graw)
{
  __shared__ float sf[64 * 113];
  __shared__ float sw[64 * 113];
  const int tid = threadIdx.x;
  const int r0 = blockIdx.x * 64;
  const int kz = blockIdx.y;
  const int ty = tid >> 4, tx = tid & 15;
  float acc[4][4] = {{0.f}};
  for (int c = kz; c < 35; c += 4) {
    const int k0 = c * 112;
    for (int i = tid; i < 896; i += TPB) {
      const int row = i / 14, k8 = (i - row * 14) * 8;
      uint4 v = *(const uint4*)(featb + (size_t)(r0 + row) * 4160 + k0 + k8);
      const ushort* pv = (const ushort*)&v;
      float* d = &sf[row * 113 + k8];
#pragma unroll
      for (int t = 0; t < 8; t++) d[t] = bf2f(pv[t]);
    }
    for (int i = tid; i < 1792; i += TPB) {
      const int row = i / 28, c4 = (i - row * 28) * 4;
      float4 u = *(const float4*)(gw1 + (size_t)row * 3920 + k0 + c4);
      float* e = &sw[row * 113 + c4];
      e[0] = u.x; e[1] = u.y; e[2] = u.z; e[3] = u.w;
    }
    __syncthreads();
    for (int k = 0; k < 112; k++) {
      float a_[4], w_[4];
#pragma unroll
      for (int i = 0; i < 4; i++) a_[i] = sf[(ty * 4 + i) * 113 + k];
#pragma unroll
      for (int j = 0; j < 4; j++) w_[j] = sw[(tx * 4 + j) * 113 + k];
#pragma unroll
      for (int i = 0; i < 4; i++)
#pragma unroll
        for (int j = 0; j < 4; j++) acc[i][j] = fmaf(a_[i], w_[j], acc[i][j]);
    }
    __syncthreads();
  }
#pragma unroll
  for (int i = 0; i < 4; i++)
#pragma unroll
    for (int j = 0; j < 4; j++)
      atomicAdd(&graw[(size_t)(r0 + ty * 4 + i) * 64 + tx * 4 + j], acc[i][j]);
}

// ---------------- K4b: gate logits + top2 softmax + expert counts ----------
__global__ __launch_bounds__(TPB) void k_gate2(
    const float* __restrict__ graw, const float* __restrict__ gb1,
    const float* __restrict__ gw2, const float* __restrict__ gb2,
    int* __restrict__ sel0, int* __restrict__ sel1,
    float* __restrict__ wt0, float* __restrict__ wt1, int* __restrict__ counts)
{
  __shared__ float sw2[512], sb1[64], sb2[8];
  const int tid = threadIdx.x;
  for (int i = tid; i < 512; i += TPB) sw2[i] = gw2[i];
  if (tid < 64) sb1[tid] = gb1[tid];
  if (tid < 8) sb2[tid] = gb2[tid];
  __syncthreads();
  const int r = blockIdx.x * TPB + tid;
  float l[8];
#pragma unroll
  for (int c = 0; c < 8; c++) l[c] = sb2[c];
  const float* gr = graw + (size_t)r * 64;
  for (int k = 0; k < 64; k++) {
    const float hv = fmaxf(gr[k] + sb1[k], 0.f);
#pragma unroll
    for (int c = 0; c < 8; c++) l[c] = fmaf(hv, sw2[c * 64 + k], l[c]);
  }
  float v0 = -1e30f, v1 = -1e30f; int i0 = 0, i1 = 0;
#pragma unroll
  for (int c = 0; c < 8; c++) {
    const float lv = l[c];
    if (lv > v0) { v1 = v0; i1 = i0; v0 = lv; i0 = c; }
    else if (lv > v1) { v1 = lv; i1 = c; }
  }
  const float e1 = expf(v1 - v0);
  const float inv = 1.f / (1.f + e1);
  sel0[r] = i0; sel1[r] = i1; wt0[r] = inv; wt1[r] = e1 * inv;
  atomicAdd(&counts[i0], 1);
  atomicAdd(&counts[i1], 1);
}

// ---------------- K5: padded offsets + entry-list init ---------------------
__global__ void k_prep(int* __restrict__ hdrI, int* __restrict__ entrow)
{
  const int tid = threadIdx.x;
  if (tid == 0) {
    int run = 0;
    for (int e = 0; e < 8; e++) {
      const int c = hdrI[e];
      const int pc = (c + 31) & ~31;
      hdrI[16 + e] = pc;
      hdrI[24 + e] = run;
      run += pc;
    }
    hdrI[32] = run;
  }
  if (tid >= 8 && tid < 16) hdrI[tid] = 0;
  for (int i = tid; i < 8448; i += TPB) entrow[i] = -1;
}

// ---------------- K5b: scatter rows to expert entry lists ------------------
__global__ void k_scatter(const int* __restrict__ sel0, const int* __restrict__ sel1,
                          int* __restrict__ hdrI, int* __restrict__ entrow,
                          int* __restrict__ p0, int* __restrict__ p1)
{
  const int r = blockIdx.x * TPB + threadIdx.x;
  const int e0 = sel0[r];
  int pos = atomicAdd(&hdrI[8 + e0], 1) + hdrI[24 + e0];
  entrow[pos] = r; p0[r] = pos;
  const int e1 = sel1[r];
  pos = atomicAdd(&hdrI[8 + e1], 1) + hdrI[24 + e1];
  entrow[pos] = r; p1[r] = pos;
}

// ---------------- K6: dense MFMA fc1 -> h1 bf16 [4096][1024] ---------------
__global__ __launch_bounds__(512) void k_fc1(
    const ushort* __restrict__ featb, const ushort* __restrict__ w1b,
    const float* __restrict__ eb1, __hip_bfloat16* __restrict__ h1b)
{
  __shared__ ushort As[128 * 72];
  __shared__ ushort Bs[128 * 72];
  const int tid = threadIdx.x;
  const int r0 = blockIdx.x * 128;
  const int c0 = blockIdx.y * 128;
  const int w = tid >> 6, lane = tid & 63;
  const int wr = (w >> 1) * 32, wc = (w & 1) * 64;
  const int m = lane & 15, q = lane >> 4;
  f32x4 acc[2][4];
#pragma unroll
  for (int i = 0; i < 2; i++)
#pragma unroll
    for (int j = 0; j < 4; j++) acc[i][j] = 0.f;

  for (int kc = 0; kc < 4096; kc += 64) {
#pragma unroll
    for (int i = 0; i < 2; i++) {
      const int u = tid + 512 * i;
      const int row = u >> 3, k8 = (u & 7) * 8;
      *(uint4*)(&As[row * 72 + k8]) =
          *(const uint4*)(featb + (size_t)(r0 + row) * 4160 + kc + k8);
      *(uint4*)(&Bs[row * 72 + k8]) =
          *(const uint4*)(w1b + (size_t)(c0 + row) * 4160 + kc + k8);
    }
    __syncthreads();
#pragma unroll
    for (int kk = 0; kk < 64; kk += 32) {
      bf16x8 af[2], bf[4];
#pragma unroll
      for (int t = 0; t < 2; t++)
        af[t] = *(const bf16x8*)(&As[(wr + t * 16 + m) * 72 + kk + q * 8]);
#pragma unroll
      for (int t = 0; t < 4; t++)
        bf[t] = *(const bf16x8*)(&Bs[(wc + t * 16 + m) * 72 + kk + q * 8]);
#pragma unroll
      for (int ti = 0; ti < 2; ti++)
#pragma unroll
        for (int tj = 0; tj < 4; tj++)
          acc[ti][tj] = __builtin_amdgcn_mfma_f32_16x16x32_bf16(
              af[ti], bf[tj], acc[ti][tj], 0, 0, 0);
    }
    __syncthreads();
  }
#pragma unroll
  for (int tj = 0; tj < 4; tj++) {
    const int c = c0 + wc + tj * 16 + m;
    const float bb = eb1[c];
#pragma unroll
    for (int ti = 0; ti < 2; ti++) {
      const int rbase = r0 + wr + ti * 16 + q * 4;
#pragma unroll
      for (int i = 0; i < 4; i++) {
        const float v = fmaxf(acc[ti][tj][i] + bb, 0.f);
        h1b[(size_t)(rbase + i) * 1024 + c] = __float2bfloat16(v);
      }
    }
  }
}

// ---------------- K7: dense fc2 -> h2 fp32 [4096][512] ---------------------
__global__ __launch_bounds__(TPB) void k_fc2(
    const __hip_bfloat16* __restrict__ h1b, const float* __restrict__ ew2,
    const float* __restrict__ eb2, float* __restrict__ h2)
{
  __shared__ float h1s[64 * 132];
  __shared__ ushort w2s[128 * 72];
  const int tid = threadIdx.x;
  const int r0 = blockIdx.x * 64;
  const int e = blockIdx.y;
  const ushort* hp = (const ushort*)h1b;
#pragma unroll
  for (int i = 0; i < 4; i++) {
    const int u = tid + 256 * i;
    const int row = u >> 4, k8 = (u & 15) * 8;
    uint4 v = *(const uint4*)(hp + (size_t)(r0 + row) * 1024 + e * 128 + k8);
    const ushort* pv = (const ushort*)&v;
    float* d = &h1s[row * 132 + k8];
#pragma unroll
    for (int t = 0; t < 8; t++) d[t] = bf2f(pv[t]);
  }
#pragma unroll
  for (int i = 0; i < 8; i++) {
    const int u = tid + 256 * i;
    const int nn = u >> 5, k4 = (u & 31) * 4;
    const float4 v = *(const float4*)(ew2 + (size_t)e * 8192 + nn * 128 + k4);
    w2s[(k4 + 0) * 72 + nn] = f2b(v.x);
    w2s[(k4 + 1) * 72 + nn] = f2b(v.y);
    w2s[(k4 + 2) * 72 + nn] = f2b(v.z);
    w2s[(k4 + 3) * 72 + nn] = f2b(v.w);
  }
  __syncthreads();
  const int ty = tid >> 4, tx = tid & 15;
  float acc[4][4] = {{0.f}};
  for (int k4 = 0; k4 < 32; k4++) {
    f32x4 a4[4];
#pragma unroll
    for (int i = 0; i < 4; i++)
      a4[i] = *(const f32x4*)(&h1s[(ty * 4 + i) * 132 + k4 * 4]);
#pragma unroll
    for (int kk = 0; kk < 4; kk++) {
      const ushort4 wu = *(const ushort4*)(&w2s[(k4 * 4 + kk) * 72 + tx * 4]);
      const float w0 = bf2f(wu.x), w1 = bf2f(wu.y);
      const float w2_ = bf2f(wu.z), w3 = bf2f(wu.w);
#pragma unroll
      for (int i = 0; i < 4; i++) {
        acc[i][0] = fmaf(a4[i][kk], w0, acc[i][0]);
        acc[i][1] = fmaf(a4[i][kk], w1, acc[i][1]);
        acc[i][2] = fmaf(a4[i][kk], w2_, acc[i][2]);
        acc[i][3] = fmaf(a4[i][kk], w3, acc[i][3]);
      }
    }
  }
  const f32x4 bb = *(const f32x4*)(eb2 + e * 64 + tx * 4);
#pragma unroll
  for (int i = 0; i < 4; i++) {
    f32x4 r;
#pragma unroll
    for (int j = 0; j < 4; j++) r[j] = fmaxf(acc[i][j] + bb[j], 0.f);
    *(f32x4*)(h2 + (size_t)(r0 + ty * 4 + i) * 512 + e * 64 + tx * 4) = r;
  }
}

// ---------------- K8: grouped fc3 -> eo [pos][1000] ------------------------
__global__ __launch_bounds__(TPB) void k_fc3(
    const float* __restrict__ h2, const float* __restrict__ ew3,
    const float* __restrict__ eb3, const int* __restrict__ hdrI,
    const int* __restrict__ entrow, float* __restrict__ eo)
{
  __shared__ float h2s[32 * 68];
  __shared__ float w3s[64 * 132];
  const int e = blockIdx.y;
  const int pcnt = hdrI[16 + e];
  if ((int)blockIdx.x * 32 >= pcnt) return;
  const int base = hdrI[24 + e] + blockIdx.x * 32;
  const int tid = threadIdx.x;
  for (int i = tid; i < 512; i += TPB) {
    const int row = i >> 4, k4 = (i & 15) * 4;
    const int rr = entrow[base + row];
    f32x4 v = 0.f;
    if (rr >= 0) v = *(const f32x4*)(h2 + (size_t)rr * 512 + e * 64 + k4);
    *(f32x4*)(&h2s[row * 68 + k4]) = v;
  }
  const int ty = tid >> 5, tx = tid & 31;
  const float* w3p = ew3 + (size_t)e * 64000;
  const float* b3p = eb3 + (size_t)e * 1000;
  for (int nc = 0; nc < 8; nc++) {
    const int o0 = nc * 128;
    for (int i = tid; i < 2048; i += TPB) {
      const int oo = i >> 4, k4 = (i & 15) * 4;
      const int o = o0 + oo;
      f32x4 u = 0.f;
      if (o < 1000) u = *(const f32x4*)(w3p + (size_t)o * 64 + k4);
      w3s[(k4 + 0) * 132 + oo] = u[0];
      w3s[(k4 + 1) * 132 + oo] = u[1];
      w3s[(k4 + 2) * 132 + oo] = u[2];
      w3s[(k4 + 3) * 132 + oo] = u[3];
    }
    __syncthreads();
    float acc[4][4] = {{0.f}};
    for (int k4 = 0; k4 < 16; k4++) {
      f32x4 a4[4], w4[4];
#pragma unroll
      for (int i = 0; i < 4; i++)
        a4[i] = *(const f32x4*)(&h2s[(ty * 4 + i) * 68 + k4 * 4]);
#pragma unroll
      for (int kk = 0; kk < 4; kk++)
        w4[kk] = *(const f32x4*)(&w3s[(k4 * 4 + kk) * 132 + tx * 4]);
#pragma unroll
      for (int kk = 0; kk < 4; kk++)
#pragma unroll
        for (int i = 0; i < 4; i++)
#pragma unroll
          for (int j = 0; j < 4; j++)
            acc[i][j] = fmaf(a4[i][kk], w4[kk][j], acc[i][j]);
    }
    const int o = o0 + tx * 4;
    if (o + 3 < 1000) {
      const f32x4 bb = *(const f32x4*)(b3p + o);
#pragma unroll
      for (int i = 0; i < 4; i++) {
        f32x4 r;
#pragma unroll
        for (int j = 0; j < 4; j++) r[j] = acc[i][j] + bb[j];
        *(f32x4*)(eo + (size_t)(base + ty * 4 + i) * 1000 + o) = r;
      }
    }
    __syncthreads();
  }
}

// ---------------- K9: gate-combine + log_softmax(|.|) ----------------------
__global__ __launch_bounds__(TPB) void k_out(
    const float* __restrict__ eo, const int* __restrict__ p0,
    const int* __restrict__ p1, const float* __restrict__ wt0,
    const float* __restrict__ wt1, float* __restrict__ out)
{
  __shared__ float sv[1000];
  __shared__ float sr[8];
  const int r = blockIdx.x, tid = threadIdx.x;
  const float w0 = wt0[r], w1 = wt1[r];
  const float* a = eo + (size_t)p0[r] * 1000;
  const float* b = eo + (size_t)p1[r] * 1000;
  float lmax = -3.4e38f;
  for (int o = tid; o < 1000; o += TPB) {
    const float v = fabsf(w0 * a[o] + w1 * b[o]);
    sv[o] = v;
    lmax = fmaxf(lmax, v);
  }
#pragma unroll
  for (int off = 32; off; off >>= 1) lmax = fmaxf(lmax, __shfl_down(lmax, off));
  if ((tid & 63) == 0) sr[tid >> 6] = lmax;
  __syncthreads();
  const float mx = fmaxf(fmaxf(sr[0], sr[1]), fmaxf(sr[2], sr[3]));
  float lsum = 0.f;
  for (int o = tid; o < 1000; o += TPB) lsum += expf(sv[o] - mx);
#pragma unroll
  for (int off = 32; off; off >>= 1) lsum += __shfl_down(lsum, off);
  if ((tid & 63) == 0) sr[4 + (tid >> 6)] = lsum;
  __syncthreads();
  const float lse = logf(sr[4] + sr[5] + sr[6] + sr[7]);
  const float sub = mx + lse;
  for (int o = tid; o < 1000; o += TPB)
    out[(size_t)r * 1000 + o] = sv[o] - sub;
}

// ---------------------------------------------------------------------------
extern "C" void kernel_launch(void* const* d_in, const int* in_sizes, int n_in,
                              void* d_out, int out_size, void* d_ws, size_t ws_size,
                              hipStream_t stream)
{
  (void)in_sizes; (void)n_in; (void)out_size; (void)ws_size;
  const float* x   = (const float*)d_in[0];
  const float* c1w = (const float*)d_in[1];
  const float* c1b = (const float*)d_in[2];
  const float* bng = (const float*)d_in[3];
  const float* bnb = (const float*)d_in[4];
  const float* c2w = (const float*)d_in[5];
  const float* c2b = (const float*)d_in[6];
  const float* gw1 = (const float*)d_in[7];
  const float* gb1 = (const float*)d_in[8];
  const float* gw2 = (const float*)d_in[9];
  const float* gb2 = (const float*)d_in[10];
  const float* ew1 = (const float*)d_in[11];
  const float* eb1 = (const float*)d_in[12];
  const float* ew2 = (const float*)d_in[13];
  const float* eb2 = (const float*)d_in[14];
  const float* ew3 = (const float*)d_in[15];
  const float* eb3 = (const float*)d_in[16];

  char* ws = (char*)d_ws;
  float* statsF = (float*)ws;
  int*   hdrI   = (int*)(ws + 256);
  int*   sel0   = (int*)(ws + 1024);
  int*   sel1   = (int*)(ws + 17408);
  float* wt0    = (float*)(ws + 33792);
  float* wt1    = (float*)(ws + 50176);
  int*   p0     = (int*)(ws + 66560);
  int*   p1     = (int*)(ws + 82944);
  int*   entrow = (int*)(ws + 99328);
  float* graw   = (float*)(ws + 133120);
  float* eo     = (float*)(ws + 1181696);
  __hip_bfloat16* h1b = (__hip_bfloat16*)(ws + 34973696);
  float* h2     = (float*)(ws + 43362304);
  __hip_bfloat16* pool1 = (__hip_bfloat16*)(ws + 51750912);
  __hip_bfloat16* featb = (__hip_bfloat16*)(ws + 130476032);
  ushort* w1b   = (ushort*)(ws + 164554752);

  hipMemsetAsync(ws, 0, 512, stream);
  hipMemsetAsync(graw, 0, 4096 * 64 * sizeof(float), stream);

  k_castw1 <<<1024, TPB, 0, stream>>>(ew1, w1b);
  k_conv1  <<<8192, TPB, 0, stream>>>(x, c1w, c1b, pool1, statsF);
  k_bnfin  <<<1, 64, 0, stream>>>(bng, bnb, statsF);
  k_conv2  <<<1024, TPB, 0, stream>>>(pool1, statsF, c2w, c2b, featb);
  k_gate1  <<<dim3(64, 4), TPB, 0, stream>>>((const ushort*)featb, gw1, graw);
  k_gate2  <<<16, TPB, 0, stream>>>(graw, gb1, gw2, gb2, sel0, sel1, wt0, wt1, hdrI);
  k_prep   <<<1, TPB, 0, stream>>>(hdrI, entrow);
  k_scatter<<<16, TPB, 0, stream>>>(sel0, sel1, hdrI, entrow, p0, p1);
  k_fc1    <<<dim3(32, 8), 512, 0, stream>>>((const ushort*)featb, w1b, eb1, h1b);
  k_fc2    <<<dim3(64, 8), TPB, 0, stream>>>(h1b, ew2, eb2, h2);
  k_fc3    <<<dim3(128, 8), TPB, 0, stream>>>(h2, ew3, eb3, hdrI, entrow, eo);
  k_out    <<<4096, TPB, 0, stream>>>(eo, p0, p1, wt0, wt1, (float*)d_out);
}

// Round 6
// 1119.425 us; speedup vs baseline: 1.3229x; 1.0064x over previous
//
#include <hip/hip_runtime.h>
#include <hip/hip_bf16.h>

// ---------------------------------------------------------------------------
// Net_83674552861196 — round 11: conv1 half-split in ROUND-7 register shape.
//  - Rounds 8/9/10: half-split with runtime staging loop + if(h) tail kept
//    tripping the allocator (VGPR_Count = budget/2, 0.4-1.8 GB spill).
//    Round 7's full-image kernel (same bounds 4) allocated 52 regs, no
//    spill -- the spill tracks the irregular control flow, not the split.
//  - This round: identical control flow for BOTH halves. h0 = rows 0..31,
//    h1 = rows 30..61 (32 rows each, 2-row overlap). Static staging (3
//    predicated unrolled iterations, 35 rows -> 36 slices, 19 KB LDS).
//    Peeled first 5-row block masks the duplicate rows' BN-stats for h1
//    (hm = h?0:1 on ROWSTEP instances 0,1); pool writes of overlap rows
//    are bitwise-identical duplicates (benign). Tail rows 30,31
//    unconditional for both halves, same named-register rotation.
//  - 19 KB LDS -> 8 blocks/CU; expected no spill at bounds 4.
//  - Everything else unchanged.
// ---------------------------------------------------------------------------

#define TPB 256

typedef __attribute__((ext_vector_type(8))) short bf16x8;
typedef __attribute__((ext_vector_type(4))) float f32x4;
typedef __attribute__((ext_vector_type(16))) float f32x16;

__device__ __forceinline__ float bf2f(unsigned short u) {
  return __uint_as_float(((unsigned)u) << 16);
}
__device__ __forceinline__ ushort f2b(float f) {
  __hip_bfloat16 h = __float2bfloat16(f);
  return *(ushort*)&h;
}

// ---------------- K1: conv1 (MFMA) + raw-maxpool + BN statistics -----------
// out(r,pos,oc) = sum_{kh} sum_{j<20, j=kw*4+ic, ic<3} Row[t][pos*4+j]*W
// Block = (image n, half h): h0 rows 0..31 (t 0..35, lt = t),
//                            h1 rows 30..61 (t 30..65, lt = t-30).
// Staged image rows: grow = lr + 29*h (lr 0..34), lt = lr + 1 - h.
// lt0 (h0) and lt35 (h1) are zero borders (memset).
__global__ __launch_bounds__(TPB, 4) void k_conv1(
    const float* __restrict__ x, const float* __restrict__ w1c,
    const float* __restrict__ b1c, __hip_bfloat16* __restrict__ pool1,
    float* __restrict__ stats)
{
  __shared__ uint4 imgI4[1190];          // 19040 B (36 slices + read guard)
  __shared__ float sred[20];
  ushort* imgI = (ushort*)imgI4;
  const int tid = threadIdx.x;
  const int lane = tid & 63;
  const int w = tid >> 6;
  const int n = blockIdx.x >> 1;
  const int h = blockIdx.x & 1;
  const int oc = lane & 15;
  const int q = lane >> 4;
  const int c0 = w * 16;
  const int r0 = h * 30;
  const float hm = h ? 0.f : 1.f;        // stats mask for duplicate rows

  {
    const uint4 z = {0u, 0u, 0u, 0u};
    for (int i = tid; i < 1190; i += TPB) imgI4[i] = z;
    if (tid < 20) sred[tid] = 0.f;
  }
  __syncthreads();

  // stage 35 rows, channel-interleaved (ic slot 3 = 0); static + predicated
  {
    const float* xp = x + (size_t)n * 12288;
    const int h29 = 29 * h;
#pragma unroll
    for (int it = 0; it < 3; it++) {
      const int g = tid + 256 * it;            // need g < 560
      if (g < 560) {
        const int lr = g >> 4, col0 = (g & 15) * 4;
        const int grow = lr + h29;             // global image row
        const int lt = lr + 1 - h;             // local slice index
        const float* xr = xp + grow * 64 + col0;
        const float4 v0 = *(const float4*)(xr);
        const float4 v1 = *(const float4*)(xr + 4096);
        const float4 v2 = *(const float4*)(xr + 8192);
        ushort* d = &imgI[((size_t)lt * 66 + (col0 + 1)) * 4];
        uint2 t0, t1, t2, t3;
        t0.x = (uint)f2b(v0.x) | ((uint)f2b(v1.x) << 16); t0.y = (uint)f2b(v2.x);
        t1.x = (uint)f2b(v0.y) | ((uint)f2b(v1.y) << 16); t1.y = (uint)f2b(v2.y);
        t2.x = (uint)f2b(v0.z) | ((uint)f2b(v1.z) << 16); t2.y = (uint)f2b(v2.z);
        t3.x = (uint)f2b(v0.w) | ((uint)f2b(v1.w) << 16); t3.y = (uint)f2b(v2.w);
        *(uint2*)(d + 0)  = t0;
        *(uint2*)(d + 4)  = t1;
        *(uint2*)(d + 8)  = t2;
        *(uint2*)(d + 12) = t3;
      }
    }
  }

  // weight B-frags: 5 kh K-steps, named registers (no arrays!).
  // slot j = kw*4+ic (j<20, ic<3 real), K padded to 32 with zeros.
  bf16x8 wf0, wf1, wf2, wf3, wf4;
#define WLOAD(dst_, kh_)                                                \
  {                                                                     \
    union { ushort u[8]; bf16x8 v; } bu_;                               \
    _Pragma("unroll")                                                   \
    for (int i = 0; i < 8; i++) {                                       \
      const int j = q * 8 + i;                                          \
      float wv = 0.f;                                                   \
      if (oc < 10 && j < 20 && (j & 3) < 3)                             \
        wv = w1c[oc * 75 + (j & 3) * 25 + (kh_) * 5 + (j >> 2)];        \
      bu_.u[i] = f2b(wv);                                               \
    }                                                                   \
    dst_ = bu_.v;                                                       \
  }
  WLOAD(wf0, 0) WLOAD(wf1, 1) WLOAD(wf2, 2) WLOAD(wf3, 3) WLOAD(wf4, 4)
#undef WLOAD
  const float bias = (oc < 10) ? b1c[oc] : 0.f;

  __syncthreads();

  const int pos_A = c0 + oc;                    // A-matrix row (output col)
  const ushort* abase = &imgI[pos_A * 4 + q * 8];
  const int pwb = (c0 >> 1) + q * 2;

#define ALOADV(dst_, lt_)                                               \
  {                                                                     \
    const ushort* p_ = abase + (lt_) * 264;                             \
    union { uint u[4]; bf16x8 v; } au_;                                 \
    const uint2 lo_ = *(const uint2*)(p_);                              \
    const uint2 hi_ = *(const uint2*)(p_ + 4);                          \
    au_.u[0] = lo_.x; au_.u[1] = lo_.y;                                 \
    au_.u[2] = hi_.x; au_.u[3] = hi_.y;                                 \
    dst_ = au_.v;                                                       \
  }

  const float vm0 = ((c0 + q * 4 + 0) < 62) ? 1.f : 0.f;
  const float vm1 = ((c0 + q * 4 + 1) < 62) ? 1.f : 0.f;
  const float vm2 = ((c0 + q * 4 + 2) < 62) ? 1.f : 0.f;
  const float vm3 = ((c0 + q * 4 + 3) < 62) ? 1.f : 0.f;

  float ts = 0.f, tss = 0.f;
  float pp0 = 0.f, pp1 = 0.f;

#define ROWSTEP(rr_, SM_, sA, sB, sC, sD, sE)                           \
  {                                                                     \
    ALOADV(sE, (rr_) + 4)                                               \
    f32x4 accA = {0.f, 0.f, 0.f, 0.f};                                  \
    f32x4 accB = {0.f, 0.f, 0.f, 0.f};                                  \
    accA = __builtin_amdgcn_mfma_f32_16x16x32_bf16(sA, wf0, accA, 0, 0, 0); \
    accB = __builtin_amdgcn_mfma_f32_16x16x32_bf16(sB, wf1, accB, 0, 0, 0); \
    accA = __builtin_amdgcn_mfma_f32_16x16x32_bf16(sC, wf2, accA, 0, 0, 0); \
    accB = __builtin_amdgcn_mfma_f32_16x16x32_bf16(sD, wf3, accB, 0, 0, 0); \
    accA = __builtin_amdgcn_mfma_f32_16x16x32_bf16(sE, wf4, accA, 0, 0, 0); \
    const float y0 = accA[0] + accB[0] + bias;                          \
    const float y1 = accA[1] + accB[1] + bias;                          \
    const float y2 = accA[2] + accB[2] + bias;                          \
    const float y3 = accA[3] + accB[3] + bias;                          \
    float t0 = y0 * vm0 * (SM_); ts += t0; tss = fmaf(t0, y0, tss);     \
    float t1 = y1 * vm1 * (SM_); ts += t1; tss = fmaf(t1, y1, tss);    \
    float t2 = y2 * vm2 * (SM_); ts += t2; tss = fmaf(t2, y2, tss);    \
    float t3 = y3 * vm3 * (SM_); ts += t3; tss = fmaf(t3, y3, tss);    \
    const float p0v = fmaxf(y0, y1), p1v = fmaxf(y2, y3);               \
    if (((rr_) & 1) == 0) {                                             \
      pp0 = p0v; pp1 = p1v;                                             \
    } else if (oc < 10) {                                               \
      const int ph_ = (r0 + (rr_)) >> 1;                                \
      __hip_bfloat16* dst2_ =                                           \
          pool1 + (size_t)n * 9610 + (size_t)(ph_ * 31) * 10 + oc;      \
      const float q0_ = fmaxf(pp0, p0v), q1_ = fmaxf(pp1, p1v);         \
      dst2_[pwb * 10] = __float2bfloat16(q0_);                          \
      if (pwb + 1 < 31) dst2_[(pwb + 1) * 10] = __float2bfloat16(q1_);  \
    }                                                                   \
  }

  bf16x8 s0, s1, s2, s3, s4;
  ALOADV(s0, 0) ALOADV(s1, 1) ALOADV(s2, 2) ALOADV(s3, 3)

  // peeled first block: rows 0,1 are global rows 30,31 for h1 -> stats
  // masked by hm (they are counted by h0's rows 30,31)
  ROWSTEP(0, hm, s0, s1, s2, s3, s4)
  ROWSTEP(1, hm, s1, s2, s3, s4, s0)
  ROWSTEP(2, 1.f, s2, s3, s4, s0, s1)
  ROWSTEP(3, 1.f, s3, s4, s0, s1, s2)
  ROWSTEP(4, 1.f, s4, s0, s1, s2, s3)

  for (int rb = 5; rb < 30; rb += 5) {
    ROWSTEP(rb + 0, 1.f, s0, s1, s2, s3, s4)
    ROWSTEP(rb + 1, 1.f, s1, s2, s3, s4, s0)
    ROWSTEP(rb + 2, 1.f, s2, s3, s4, s0, s1)
    ROWSTEP(rb + 3, 1.f, s3, s4, s0, s1, s2)
    ROWSTEP(rb + 4, 1.f, s4, s0, s1, s2, s3)
  }
  // rows 30, 31 (register mapping identity after 6 turns)
  ROWSTEP(30, 1.f, s0, s1, s2, s3, s4)
  ROWSTEP(31, 1.f, s1, s2, s3, s4, s0)
#undef ROWSTEP
#undef ALOADV

  if (oc < 10) {
    atomicAdd(&sred[oc], ts);
    atomicAdd(&sred[10 + oc], tss);
  }
  __syncthreads();
  if (tid < 20) atomicAdd(&stats[tid], sred[tid]);
}

// ---------------- K2: finalize BN scale/shift ------------------------------
__global__ void k_bnfin(const float* __restrict__ bng,
                        const float* __restrict__ bnb,
                        float* __restrict__ stats)
{
  const int c = threadIdx.x;
  if (c < 10) {
    const float Ninv = 1.f / (4096.f * 3844.f);
    const float mean = stats[c] * Ninv;
    const float var = stats[10 + c] * Ninv - mean * mean;
    const float sc = bng[c] * rsqrtf(var + 1e-5f);
    stats[20 + c] = sc;
    stats[30 + c] = bnb[c] - mean * sc;
  }
}

// ---------------- K3: conv2 on MFMA, one image per wave --------------------
// out(r,pos,oc) = sum_{kh} sum_{j<50, j=kw*10+ic} Row[r+kh][pos*10+j] * W[oc][j,kh]
// Row[t][u] (u=pw_pad*10+ic) = BN-relu(pool1[n][t-1][pw_pad-1][ic]), zero borders.
// M=pos(28,pad32), N=oc(20,pad32), K=5 x 64 (j>=50 has zero B).
__global__ __launch_bounds__(TPB, 2) void k_conv2(
    const __hip_bfloat16* __restrict__ pool1, const float* __restrict__ stats,
    const float* __restrict__ w2c, const float* __restrict__ b2c,
    __hip_bfloat16* __restrict__ featb)
{
  __shared__ ushort R[4][4][344];          // [wave-image][slot][u], 11 KB
  __shared__ float ssc[10], ssh[10];
  const int tid = threadIdx.x;
  const int w = tid >> 6, lane = tid & 63;
  const int n = blockIdx.x * 4 + w;
  const int pos = lane & 31, q = lane >> 5;
  ushort (*Rw)[344] = R[w];

  if (tid < 10) { ssc[tid] = stats[20 + tid]; ssh[tid] = stats[30 + tid]; }
  // zero border cols of own 4 slots: u in [0,10) and [320,344)
  for (int i = lane; i < 136; i += 64) {
    const int s = i / 34, uu = i - 34 * s;
    Rw[s][(uu < 10) ? uu : (310 + uu)] = 0;
  }
  // zero fc1 K-pad cols for this image
  if (lane < 60) {
    uint* z = (uint*)((ushort*)featb + (size_t)n * 4160 + 3920);
    z[lane] = 0; z[lane + 60] = 0;
  }
  __syncthreads();

  // weight B-frags in VGPRs (j = kw*10+ic)
  bf16x8 wf[20];
#pragma unroll
  for (int kk = 0; kk < 20; kk++) {
    union { ushort u[8]; bf16x8 v; } bu;
    const int s = kk >> 2;
#pragma unroll
    for (int i = 0; i < 8; i++) {
      const int j = (kk & 3) * 16 + q * 8 + i;
      float wv = 0.f;
      if ((pos < 20) && (j < 50))
        wv = w2c[pos * 250 + (j % 10) * 25 + s * 5 + (j / 10)];
      bu.u[i] = f2b(wv);
    }
    wf[kk] = bu.v;
  }
  const float bias = (pos < 20) ? b2c[pos] : 0.f;

  const ushort* pp = (const ushort*)pool1 + (size_t)n * 9610;
  const int ic0 = (2 * lane) % 10;
  const int pos_e = (pos < 28) ? pos : pos - 16;
  const int pe10q8 = pos_e * 10 + q * 8;

  uint gv0, gv1, gv2;
#define GLOAD(t)                                                        \
  {                                                                     \
    const ushort* s_ = pp + ((t) - 1) * 310;                            \
    gv0 = *(const uint*)(s_ + 2 * lane);                                \
    gv1 = *(const uint*)(s_ + 2 * (lane + 64));                         \
    gv2 = (lane < 27) ? *(const uint*)(s_ + 2 * (lane + 128)) : 0u;     \
  }
#define GS1(c_, gv_)                                                    \
  {                                                                     \
    const int u2_ = lane + 64 * c_;                                     \
    if (c_ < 2 || lane < 27) {                                          \
      const int ia_ = (ic0 + 8 * c_) % 10;                              \
      const int ib_ = (ia_ == 9) ? 0 : ia_ + 1;                         \
      float a0_ = bf2f((ushort)(gv_ & 0xffffu));                        \
      float a1_ = bf2f((ushort)(gv_ >> 16));                            \
      a0_ = fmaxf(fmaf(a0_, ssc[ia_], ssh[ia_]), 0.f);                  \
      a1_ = fmaxf(fmaf(a1_, ssc[ib_], ssh[ib_]), 0.f);                  \
      *(uint*)(dst_ + 2 * u2_) = (uint)f2b(a0_) | ((uint)f2b(a1_) << 16);\
    }                                                                   \
  }
#define GSTORE(t)                                                       \
  {                                                                     \
    ushort* dst_ = &Rw[(t) & 3][10];                                    \
    GS1(0, gv0) GS1(1, gv1) GS1(2, gv2)                                 \
  }
#define FLOAD(t, ss)                                                    \
  {                                                                     \
    const ushort* bp_ = &Rw[(t) & 3][pe10q8];                           \
    _Pragma("unroll")                                                   \
    for (int sub_ = 0; sub_ < 4; sub_++) {                              \
      union { uint u[4]; bf16x8 v; } au_;                               \
      au_.u[0] = *(const uint*)(bp_ + sub_ * 16 + 0);                   \
      au_.u[1] = *(const uint*)(bp_ + sub_ * 16 + 2);                   \
      au_.u[2] = *(const uint*)(bp_ + sub_ * 16 + 4);                   \
      au_.u[3] = *(const uint*)(bp_ + sub_ * 16 + 6);                   \
      sets[ss][sub_] = au_.v;                                           \
    }                                                                   \
  }

  bf16x8 sets[5][4];
  const bf16x8 zfrag = (short)0;
#pragma unroll
  for (int s = 0; s < 4; s++) sets[0][s] = zfrag;   // t=0 border row

  GLOAD(1) GSTORE(1)
  GLOAD(2) GSTORE(2)
  GLOAD(3) GSTORE(3)
  GLOAD(4) GSTORE(4)
  GLOAD(5)
  __asm__ __volatile__("s_waitcnt lgkmcnt(0)" ::: "memory");
  FLOAD(1, 1) FLOAD(2, 2) FLOAD(3, 3)

  float php[8];
  for (int rb = 0; rb < 30; rb += 5) {
#pragma unroll
    for (int rr = 0; rr < 5; rr++) {
      const int r = rb + rr;
      __asm__ __volatile__("s_waitcnt lgkmcnt(0)" ::: "memory");
      if (r <= 27) FLOAD(r + 4, (rr + 4) % 5)
      if (r <= 26) GSTORE(r + 5)
      if (r <= 25) GLOAD(r + 6)
      if (r < 28) {
        f32x16 accA, accB;
#pragma unroll
        for (int z = 0; z < 16; z++) { accA[z] = 0.f; accB[z] = 0.f; }
#pragma unroll
        for (int kh = 0; kh < 5; kh++) {
          const int si = (rr + kh) % 5;
#pragma unroll
          for (int sub = 0; sub < 4; sub++) {
            if (kh & 1)
              accB = __builtin_amdgcn_mfma_f32_32x32x16_bf16(
                  sets[si][sub], wf[kh * 4 + sub], accB, 0, 0, 0);
            else
              accA = __builtin_amdgcn_mfma_f32_32x32x16_bf16(
                  sets[si][sub], wf[kh * 4 + sub], accA, 0, 0, 0);
          }
        }
        float hp[8];
#pragma unroll
        for (int p = 0; p < 8; p++)
          hp[p] = fmaxf(accA[2 * p] + accB[2 * p],
                        accA[2 * p + 1] + accB[2 * p + 1]);
        if ((r & 1) == 0) {
#pragma unroll
          for (int p = 0; p < 8; p++) php[p] = hp[p];
        } else if (pos < 20) {
          const int ph = r >> 1;
          ushort* dst = (ushort*)featb + (size_t)n * 4160 + pos * 196 + ph * 14;
#pragma unroll
          for (int j = 0; j < 4; j++) {
            const int pw = 4 * j + 2 * q;
            if (pw + 1 < 14) {
              const float v0 =
                  fmaxf(fmaxf(php[2 * j], hp[2 * j]) + bias, 0.f);
              const float v1 =
                  fmaxf(fmaxf(php[2 * j + 1], hp[2 * j + 1]) + bias, 0.f);
              *(uint*)(dst + pw) = (uint)f2b(v0) | ((uint)f2b(v1) << 16);
            }
          }
        }
      }
    }
  }
#undef GLOAD
#undef GS1
#undef GSTORE
#undef FLOAD
}

// ---------------- K3b: cast ew1 -> bf16 [1024][4160] -----------------------
__global__ __launch_bounds__(TPB) void k_castw1(
    const float* __restrict__ ew1, ushort* __restrict__ w1b)
{
  const int o = blockIdx.x;
  const int tid = threadIdx.x;
  const float* srow = ew1 + (size_t)o * 3920;
  ushort* drow = w1b + (size_t)o * 4160;
  for (int i = tid; i < 1040; i += TPB) {
    const int k4 = i * 4;
    ushort4 r;
    if (k4 < 3920) {
      const float4 v = *(const float4*)(srow + k4);
      r.x = f2b(v.x); r.y = f2b(v.y); r.z = f2b(v.z); r.w = f2b(v.w);
    } else {
      r.x = 0; r.y = 0; r.z = 0; r.w = 0;
    }
    *(ushort4*)(drow + k4) = r;
  }
}

// ---------------- K4a: gate fc1 partial GEMM (atomic K-split) --------------
__global__ __launch_bounds__(TPB) void k_gate1(
    const ushort* __restrict__ featb, const float* __restrict__ gw1,
    float* __restrict__ graw)
{
  __shared__ float sf[64 * 113];
  __shared__ float sw[64 * 113];
  const int tid = threadIdx.x;
  const int r0 = blockIdx.x * 64;
  const int kz = blockIdx.y;
  const int ty = tid >> 4, tx = tid & 15;
  float acc[4][4] = {{0.f}};
  for (int c = kz; c < 35; c += 4) {
    const int k0 = c * 112;
    for (int i = tid; i < 896; i += TPB) {
      const int row = i / 14, k8 = (i - row * 14) * 8;
      uint4 v = *(const uint4*)(featb + (size_t)(r0 + row) * 4160 + k0 + k8);
      const ushort* pv = (const ushort*)&v;
      float* d = &sf[row * 113 + k8];
#pragma unroll
      for (int t = 0; t < 8; t++) d[t] = bf2f(pv[t]);
    }
    for (int i = tid; i < 1792; i += TPB) {
      const int row = i / 28, c4 = (i - row * 28) * 4;
      float4 u = *(const float4*)(gw1 + (size_t)row * 3920 + k0 + c4);
      float* e = &sw[row * 113 + c4];
      e[0] = u.x; e[1] = u.y; e[2] = u.z; e[3] = u.w;
    }
    __syncthreads();
    for (int k = 0; k < 112; k++) {
      float a_[4], w_[4];
#pragma unroll
      for (int i = 0; i < 4; i++) a_[i] = sf[(ty * 4 + i) * 113 + k];
#pragma unroll
      for (int j = 0; j < 4; j++) w_[j] = sw[(tx * 4 + j) * 113 + k];
#pragma unroll
      for (int i = 0; i < 4; i++)
#pragma unroll
        for (int j = 0; j < 4; j++) acc[i][j] = fmaf(a_[i], w_[j], acc[i][j]);
    }
    __syncthreads();
  }
#pragma unroll
  for (int i = 0; i < 4; i++)
#pragma unroll
    for (int j = 0; j < 4; j++)
      atomicAdd(&graw[(size_t)(r0 + ty * 4 + i) * 64 + tx * 4 + j], acc[i][j]);
}

// ---------------- K4b: gate logits + top2 softmax + expert counts ----------
__global__ __launch_bounds__(TPB) void k_gate2(
    const float* __restrict__ graw, const float* __restrict__ gb1,
    const float* __restrict__ gw2, const float* __restrict__ gb2,
    int* __restrict__ sel0, int* __restrict__ sel1,
    float* __restrict__ wt0, float* __restrict__ wt1, int* __restrict__ counts)
{
  __shared__ float sw2[512], sb1[64], sb2[8];
  const int tid = threadIdx.x;
  for (int i = tid; i < 512; i += TPB) sw2[i] = gw2[i];
  if (tid < 64) sb1[tid] = gb1[tid];
  if (tid < 8) sb2[tid] = gb2[tid];
  __syncthreads();
  const int r = blockIdx.x * TPB + tid;
  float l[8];
#pragma unroll
  for (int c = 0; c < 8; c++) l[c] = sb2[c];
  const float* gr = graw + (size_t)r * 64;
  for (int k = 0; k < 64; k++) {
    const float hv = fmaxf(gr[k] + sb1[k], 0.f);
#pragma unroll
    for (int c = 0; c < 8; c++) l[c] = fmaf(hv, sw2[c * 64 + k], l[c]);
  }
  float v0 = -1e30f, v1 = -1e30f; int i0 = 0, i1 = 0;
#pragma unroll
  for (int c = 0; c < 8; c++) {
    const float lv = l[c];
    if (lv > v0) { v1 = v0; i1 = i0; v0 = lv; i0 = c; }
    else if (lv > v1) { v1 = lv; i1 = c; }
  }
  const float e1 = expf(v1 - v0);
  const float inv = 1.f / (1.f + e1);
  sel0[r] = i0; sel1[r] = i1; wt0[r] = inv; wt1[r] = e1 * inv;
  atomicAdd(&counts[i0], 1);
  atomicAdd(&counts[i1], 1);
}

// ---------------- K5: padded offsets + entry-list init ---------------------
__global__ void k_prep(int* __restrict__ hdrI, int* __restrict__ entrow)
{
  const int tid = threadIdx.x;
  if (tid == 0) {
    int run = 0;
    for (int e = 0; e < 8; e++) {
      const int c = hdrI[e];
      const int pc = (c + 31) & ~31;
      hdrI[16 + e] = pc;
      hdrI[24 + e] = run;
      run += pc;
    }
    hdrI[32] = run;
  }
  if (tid >= 8 && tid < 16) hdrI[tid] = 0;
  for (int i = tid; i < 8448; i += TPB) entrow[i] = -1;
}

// ---------------- K5b: scatter rows to expert entry lists ------------------
__global__ void k_scatter(const int* __restrict__ sel0, const int* __restrict__ sel1,
                          int* __restrict__ hdrI, int* __restrict__ entrow,
                          int* __restrict__ p0, int* __restrict__ p1)
{
  const int r = blockIdx.x * TPB + threadIdx.x;
  const int e0 = sel0[r];
  int pos = atomicAdd(&hdrI[8 + e0], 1) + hdrI[24 + e0];
  entrow[pos] = r; p0[r] = pos;
  const int e1 = sel1[r];
  pos = atomicAdd(&hdrI[8 + e1], 1) + hdrI[24 + e1];
  entrow[pos] = r; p1[r] = pos;
}

// ---------------- K6: dense MFMA fc1 -> h1 bf16 [4096][1024] ---------------
__global__ __launch_bounds__(512) void k_fc1(
    const ushort* __restrict__ featb, const ushort* __restrict__ w1b,
    const float* __restrict__ eb1, __hip_bfloat16* __restrict__ h1b)
{
  __shared__ ushort As[128 * 72];
  __shared__ ushort Bs[128 * 72];
  const int tid = threadIdx.x;
  const int r0 = blockIdx.x * 128;
  const int c0 = blockIdx.y * 128;
  const int w = tid >> 6, lane = tid & 63;
  const int wr = (w >> 1) * 32, wc = (w & 1) * 64;
  const int m = lane & 15, q = lane >> 4;
  f32x4 acc[2][4];
#pragma unroll
  for (int i = 0; i < 2; i++)
#pragma unroll
    for (int j = 0; j < 4; j++) acc[i][j] = 0.f;

  for (int kc = 0; kc < 4096; kc += 64) {
#pragma unroll
    for (int i = 0; i < 2; i++) {
      const int u = tid + 512 * i;
      const int row = u >> 3, k8 = (u & 7) * 8;
      *(uint4*)(&As[row * 72 + k8]) =
          *(const uint4*)(featb + (size_t)(r0 + row) * 4160 + kc + k8);
      *(uint4*)(&Bs[row * 72 + k8]) =
          *(const uint4*)(w1b + (size_t)(c0 + row) * 4160 + kc + k8);
    }
    __syncthreads();
#pragma unroll
    for (int kk = 0; kk < 64; kk += 32) {
      bf16x8 af[2], bf[4];
#pragma unroll
      for (int t = 0; t < 2; t++)
        af[t] = *(const bf16x8*)(&As[(wr + t * 16 + m) * 72 + kk + q * 8]);
#pragma unroll
      for (int t = 0; t < 4; t++)
        bf[t] = *(const bf16x8*)(&Bs[(wc + t * 16 + m) * 72 + kk + q * 8]);
#pragma unroll
      for (int ti = 0; ti < 2; ti++)
#pragma unroll
        for (int tj = 0; tj < 4; tj++)
          acc[ti][tj] = __builtin_amdgcn_mfma_f32_16x16x32_bf16(
              af[ti], bf[tj], acc[ti][tj], 0, 0, 0);
    }
    __syncthreads();
  }
#pragma unroll
  for (int tj = 0; tj < 4; tj++) {
    const int c = c0 + wc + tj * 16 + m;
    const float bb = eb1[c];
#pragma unroll
    for (int ti = 0; ti < 2; ti++) {
      const int rbase = r0 + wr + ti * 16 + q * 4;
#pragma unroll
      for (int i = 0; i < 4; i++) {
        const float v = fmaxf(acc[ti][tj][i] + bb, 0.f);
        h1b[(size_t)(rbase + i) * 1024 + c] = __float2bfloat16(v);
      }
    }
  }
}

// ---------------- K7: dense fc2 -> h2 fp32 [4096][512] ---------------------
__global__ __launch_bounds__(TPB) void k_fc2(
    const __hip_bfloat16* __restrict__ h1b, const float* __restrict__ ew2,
    const float* __restrict__ eb2, float* __restrict__ h2)
{
  __shared__ float h1s[64 * 132];
  __shared__ ushort w2s[128 * 72];
  const int tid = threadIdx.x;
  const int r0 = blockIdx.x * 64;
  const int e = blockIdx.y;
  const ushort* hp = (const ushort*)h1b;
#pragma unroll
  for (int i = 0; i < 4; i++) {
    const int u = tid + 256 * i;
    const int row = u >> 4, k8 = (u & 15) * 8;
    uint4 v = *(const uint4*)(hp + (size_t)(r0 + row) * 1024 + e * 128 + k8);
    const ushort* pv = (const ushort*)&v;
    float* d = &h1s[row * 132 + k8];
#pragma unroll
    for (int t = 0; t < 8; t++) d[t] = bf2f(pv[t]);
  }
#pragma unroll
  for (int i = 0; i < 8; i++) {
    const int u = tid + 256 * i;
    const int nn = u >> 5, k4 = (u & 31) * 4;
    const float4 v = *(const float4*)(ew2 + (size_t)e * 8192 + nn * 128 + k4);
    w2s[(k4 + 0) * 72 + nn] = f2b(v.x);
    w2s[(k4 + 1) * 72 + nn] = f2b(v.y);
    w2s[(k4 + 2) * 72 + nn] = f2b(v.z);
    w2s[(k4 + 3) * 72 + nn] = f2b(v.w);
  }
  __syncthreads();
  const int ty = tid >> 4, tx = tid & 15;
  float acc[4][4] = {{0.f}};
  for (int k4 = 0; k4 < 32; k4++) {
    f32x4 a4[4];
#pragma unroll
    for (int i = 0; i < 4; i++)
      a4[i] = *(const f32x4*)(&h1s[(ty * 4 + i) * 132 + k4 * 4]);
#pragma unroll
    for (int kk = 0; kk < 4; kk++) {
      const ushort4 wu = *(const ushort4*)(&w2s[(k4 * 4 + kk) * 72 + tx * 4]);
      const float w0 = bf2f(wu.x), w1 = bf2f(wu.y);
      const float w2_ = bf2f(wu.z), w3 = bf2f(wu.w);
#pragma unroll
      for (int i = 0; i < 4; i++) {
        acc[i][0] = fmaf(a4[i][kk], w0, acc[i][0]);
        acc[i][1] = fmaf(a4[i][kk], w1, acc[i][1]);
        acc[i][2] = fmaf(a4[i][kk], w2_, acc[i][2]);
        acc[i][3] = fmaf(a4[i][kk], w3, acc[i][3]);
      }
    }
  }
  const f32x4 bb = *(const f32x4*)(eb2 + e * 64 + tx * 4);
#pragma unroll
  for (int i = 0; i < 4; i++) {
    f32x4 r;
#pragma unroll
    for (int j = 0; j < 4; j++) r[j] = fmaxf(acc[i][j] + bb[j], 0.f);
    *(f32x4*)(h2 + (size_t)(r0 + ty * 4 + i) * 512 + e * 64 + tx * 4) = r;
  }
}

// ---------------- K8: grouped fc3 -> eo [pos][1000] ------------------------
__global__ __launch_bounds__(TPB) void k_fc3(
    const float* __restrict__ h2, const float* __restrict__ ew3,
    const float* __restrict__ eb3, const int* __restrict__ hdrI,
    const int* __restrict__ entrow, float* __restrict__ eo)
{
  __shared__ float h2s[32 * 68];
  __shared__ float w3s[64 * 132];
  const int e = blockIdx.y;
  const int pcnt = hdrI[16 + e];
  if ((int)blockIdx.x * 32 >= pcnt) return;
  const int base = hdrI[24 + e] + blockIdx.x * 32;
  const int tid = threadIdx.x;
  for (int i = tid; i < 512; i += TPB) {
    const int row = i >> 4, k4 = (i & 15) * 4;
    const int rr = entrow[base + row];
    f32x4 v = 0.f;
    if (rr >= 0) v = *(const f32x4*)(h2 + (size_t)rr * 512 + e * 64 + k4);
    *(f32x4*)(&h2s[row * 68 + k4]) = v;
  }
  const int ty = tid >> 5, tx = tid & 31;
  const float* w3p = ew3 + (size_t)e * 64000;
  const float* b3p = eb3 + (size_t)e * 1000;
  for (int nc = 0; nc < 8; nc++) {
    const int o0 = nc * 128;
    for (int i = tid; i < 2048; i += TPB) {
      const int oo = i >> 4, k4 = (i & 15) * 4;
      const int o = o0 + oo;
      f32x4 u = 0.f;
      if (o < 1000) u = *(const f32x4*)(w3p + (size_t)o * 64 + k4);
      w3s[(k4 + 0) * 132 + oo] = u[0];
      w3s[(k4 + 1) * 132 + oo] = u[1];
      w3s[(k4 + 2) * 132 + oo] = u[2];
      w3s[(k4 + 3) * 132 + oo] = u[3];
    }
    __syncthreads();
    float acc[4][4] = {{0.f}};
    for (int k4 = 0; k4 < 16; k4++) {
      f32x4 a4[4], w4[4];
#pragma unroll
      for (int i = 0; i < 4; i++)
        a4[i] = *(const f32x4*)(&h2s[(ty * 4 + i) * 68 + k4 * 4]);
#pragma unroll
      for (int kk = 0; kk < 4; kk++)
        w4[kk] = *(const f32x4*)(&w3s[(k4 * 4 + kk) * 132 + tx * 4]);
#pragma unroll
      for (int kk = 0; kk < 4; kk++)
#pragma unroll
        for (int i = 0; i < 4; i++)
#pragma unroll
          for (int j = 0; j < 4; j++)
            acc[i][j] = fmaf(a4[i][kk], w4[kk][j], acc[i][j]);
    }
    const int o = o0 + tx * 4;
    if (o + 3 < 1000) {
      const f32x4 bb = *(const f32x4*)(b3p + o);
#pragma unroll
      for (int i = 0; i < 4; i++) {
        f32x4 r;
#pragma unroll
        for (int j = 0; j < 4; j++) r[j] = acc[i][j] + bb[j];
        *(f32x4*)(eo + (size_t)(base + ty * 4 + i) * 1000 + o) = r;
      }
    }
    __syncthreads();
  }
}

// ---------------- K9: gate-combine + log_softmax(|.|) ----------------------
__global__ __launch_bounds__(TPB) void k_out(
    const float* __restrict__ eo, const int* __restrict__ p0,
    const int* __restrict__ p1, const float* __restrict__ wt0,
    const float* __restrict__ wt1, float* __restrict__ out)
{
  __shared__ float sv[1000];
  __shared__ float sr[8];
  const int r = blockIdx.x, tid = threadIdx.x;
  const float w0 = wt0[r], w1 = wt1[r];
  const float* a = eo + (size_t)p0[r] * 1000;
  const float* b = eo + (size_t)p1[r] * 1000;
  float lmax = -3.4e38f;
  for (int o = tid; o < 1000; o += TPB) {
    const float v = fabsf(w0 * a[o] + w1 * b[o]);
    sv[o] = v;
    lmax = fmaxf(lmax, v);
  }
#pragma unroll
  for (int off = 32; off; off >>= 1) lmax = fmaxf(lmax, __shfl_down(lmax, off));
  if ((tid & 63) == 0) sr[tid >> 6] = lmax;
  __syncthreads();
  const float mx = fmaxf(fmaxf(sr[0], sr[1]), fmaxf(sr[2], sr[3]));
  float lsum = 0.f;
  for (int o = tid; o < 1000; o += TPB) lsum += expf(sv[o] - mx);
#pragma unroll
  for (int off = 32; off; off >>= 1) lsum += __shfl_down(lsum, off);
  if ((tid & 63) == 0) sr[4 + (tid >> 6)] = lsum;
  __syncthreads();
  const float lse = logf(sr[4] + sr[5] + sr[6] + sr[7]);
  const float sub = mx + lse;
  for (int o = tid; o < 1000; o += TPB)
    out[(size_t)r * 1000 + o] = sv[o] - sub;
}

// ---------------------------------------------------------------------------
extern "C" void kernel_launch(void* const* d_in, const int* in_sizes, int n_in,
                              void* d_out, int out_size, void* d_ws, size_t ws_size,
                              hipStream_t stream)
{
  (void)in_sizes; (void)n_in; (void)out_size; (void)ws_size;
  const float* x   = (const float*)d_in[0];
  const float* c1w = (const float*)d_in[1];
  const float* c1b = (const float*)d_in[2];
  const float* bng = (const float*)d_in[3];
  const float* bnb = (const float*)d_in[4];
  const float* c2w = (const float*)d_in[5];
  const float* c2b = (const float*)d_in[6];
  const float* gw1 = (const float*)d_in[7];
  const float* gb1 = (const float*)d_in[8];
  const float* gw2 = (const float*)d_in[9];
  const float* gb2 = (const float*)d_in[10];
  const float* ew1 = (const float*)d_in[11];
  const float* eb1 = (const float*)d_in[12];
  const float* ew2 = (const float*)d_in[13];
  const float* eb2 = (const float*)d_in[14];
  const float* ew3 = (const float*)d_in[15];
  const float* eb3 = (const float*)d_in[16];

  char* ws = (char*)d_ws;
  float* statsF = (float*)ws;
  int*   hdrI   = (int*)(ws + 256);
  int*   sel0   = (int*)(ws + 1024);
  int*   sel1   = (int*)(ws + 17408);
  float* wt0    = (float*)(ws + 33792);
  float* wt1    = (float*)(ws + 50176);
  int*   p0     = (int*)(ws + 66560);
  int*   p1     = (int*)(ws + 82944);
  int*   entrow = (int*)(ws + 99328);
  float* graw   = (float*)(ws + 133120);
  float* eo     = (float*)(ws + 1181696);
  __hip_bfloat16* h1b = (__hip_bfloat16*)(ws + 34973696);
  float* h2     = (float*)(ws + 43362304);
  __hip_bfloat16* pool1 = (__hip_bfloat16*)(ws + 51750912);
  __hip_bfloat16* featb = (__hip_bfloat16*)(ws + 130476032);
  ushort* w1b   = (ushort*)(ws + 164554752);

  hipMemsetAsync(ws, 0, 512, stream);
  hipMemsetAsync(graw, 0, 4096 * 64 * sizeof(float), stream);

  k_castw1 <<<1024, TPB, 0, stream>>>(ew1, w1b);
  k_conv1  <<<8192, TPB, 0, stream>>>(x, c1w, c1b, pool1, statsF);
  k_bnfin  <<<1, 64, 0, stream>>>(bng, bnb, statsF);
  k_conv2  <<<1024, TPB, 0, stream>>>(pool1, statsF, c2w, c2b, featb);
  k_gate1  <<<dim3(64, 4), TPB, 0, stream>>>((const ushort*)featb, gw1, graw);
  k_gate2  <<<16, TPB, 0, stream>>>(graw, gb1, gw2, gb2, sel0, sel1, wt0, wt1, hdrI);
  k_prep   <<<1, TPB, 0, stream>>>(hdrI, entrow);
  k_scatter<<<16, TPB, 0, stream>>>(sel0, sel1, hdrI, entrow, p0, p1);
  k_fc1    <<<dim3(32, 8), 512, 0, stream>>>((const ushort*)featb, w1b, eb1, h1b);
  k_fc2    <<<dim3(64, 8), TPB, 0, stream>>>(h1b, ew2, eb2, h2);
  k_fc3    <<<dim3(128, 8), TPB, 0, stream>>>(h2, ew3, eb3, hdrI, entrow, eo);
  k_out    <<<4096, TPB, 0, stream>>>(eo, p0, p1, wt0, wt1, (float*)d_out);
}

// Round 7
// 905.276 us; speedup vs baseline: 1.6359x; 1.2366x over previous
//
#include <hip/hip_runtime.h>
#include <hip/hip_bf16.h>

// ---------------------------------------------------------------------------
// Net_83674552861196 — round 12: REVERT conv1 to round-7 exact kernel.
//  - Rounds 8-11 (half-split occupancy experiments) all tripped a register
//    cliff: with MFMA present, any forced waves/EU floor OR h-dependent
//    staging addressing made the allocator split the unified file
//    (VGPR_Count = budget/2 = 32/40/64), spilling the hot loop to scratch
//    (0.4-1.8 GB HBM round-trips). Pre-committed abort: plain revert.
//  - k_conv1 below is byte-identical to the round-7 version that measured
//    155 us, 52 VGPR, no spill (FETCH 98 MB / WRITE 77 MB). Grid 4096.
//  - Lesson recorded: conv1 sits at a register cliff; occupancy for it must
//    come from LDS reduction WITHOUT new address arithmetic, or not at all.
//  - Everything else unchanged.
// ---------------------------------------------------------------------------

#define TPB 256

typedef __attribute__((ext_vector_type(8))) short bf16x8;
typedef __attribute__((ext_vector_type(4))) float f32x4;
typedef __attribute__((ext_vector_type(16))) float f32x16;

__device__ __forceinline__ float bf2f(unsigned short u) {
  return __uint_as_float(((unsigned)u) << 16);
}
__device__ __forceinline__ ushort f2b(float f) {
  __hip_bfloat16 h = __float2bfloat16(f);
  return *(ushort*)&h;
}

// ---------------- K1: conv1 (MFMA) + raw-maxpool + BN statistics -----------
// out(r,pos,oc) = sum_{kh} sum_{j<20, j=kw*4+ic, ic<3} Row[r+kh][pos*4+j]*W
// Row[t][u] (u = pcol*4+ic) = x[ic][t-1][pcol-1], zero borders.
__global__ __launch_bounds__(TPB, 4) void k_conv1(
    const float* __restrict__ x, const float* __restrict__ w1c,
    const float* __restrict__ b1c, __hip_bfloat16* __restrict__ pool1,
    float* __restrict__ stats)
{
  __shared__ uint4 imgI4[2183];          // 34928 B (incl. read-overrun guard)
  __shared__ float sred[20];
  ushort* imgI = (ushort*)imgI4;
  const int tid = threadIdx.x;
  const int lane = tid & 63;
  const int w = tid >> 6;
  const int n = blockIdx.x;
  const int oc = lane & 15;
  const int q = lane >> 4;
  const int c0 = w * 16;

  {
    const uint4 z = {0u, 0u, 0u, 0u};
    for (int i = tid; i < 2183; i += TPB) imgI4[i] = z;
    if (tid < 20) sred[tid] = 0.f;
  }
  __syncthreads();

  // stage image: rows 1..64, cols 1..64, channel-interleaved (ic slot 3 = 0)
  {
    const float* xp = x + (size_t)n * 12288;
#pragma unroll
    for (int it = 0; it < 4; it++) {
      const int g = tid + 256 * it;              // 0..1023
      const int row = g >> 4, col0 = (g & 15) * 4;
      const float4 v0 = *(const float4*)(xp + row * 64 + col0);
      const float4 v1 = *(const float4*)(xp + 4096 + row * 64 + col0);
      const float4 v2 = *(const float4*)(xp + 8192 + row * 64 + col0);
      ushort* d = &imgI[((row + 1) * 66 + (col0 + 1)) * 4];
      uint2 t0, t1, t2, t3;
      t0.x = (uint)f2b(v0.x) | ((uint)f2b(v1.x) << 16); t0.y = (uint)f2b(v2.x);
      t1.x = (uint)f2b(v0.y) | ((uint)f2b(v1.y) << 16); t1.y = (uint)f2b(v2.y);
      t2.x = (uint)f2b(v0.z) | ((uint)f2b(v1.z) << 16); t2.y = (uint)f2b(v2.z);
      t3.x = (uint)f2b(v0.w) | ((uint)f2b(v1.w) << 16); t3.y = (uint)f2b(v2.w);
      *(uint2*)(d + 0)  = t0;
      *(uint2*)(d + 4)  = t1;
      *(uint2*)(d + 8)  = t2;
      *(uint2*)(d + 12) = t3;
    }
  }

  // weight B-frags: 5 kh K-steps, named registers (no arrays!).
  // slot j = kw*4+ic (j<20, ic<3 real), K padded to 32 with zeros.
  bf16x8 wf0, wf1, wf2, wf3, wf4;
#define WLOAD(dst_, kh_)                                                \
  {                                                                     \
    union { ushort u[8]; bf16x8 v; } bu_;                               \
    _Pragma("unroll")                                                   \
    for (int i = 0; i < 8; i++) {                                       \
      const int j = q * 8 + i;                                          \
      float wv = 0.f;                                                   \
      if (oc < 10 && j < 20 && (j & 3) < 3)                             \
        wv = w1c[oc * 75 + (j & 3) * 25 + (kh_) * 5 + (j >> 2)];        \
      bu_.u[i] = f2b(wv);                                               \
    }                                                                   \
    dst_ = bu_.v;                                                       \
  }
  WLOAD(wf0, 0) WLOAD(wf1, 1) WLOAD(wf2, 2) WLOAD(wf3, 3) WLOAD(wf4, 4)
#undef WLOAD
  const float bias = (oc < 10) ? b1c[oc] : 0.f;

  __syncthreads();

  const int pos_A = c0 + oc;                    // A-matrix row (output col)
  const ushort* abase = &imgI[pos_A * 4 + q * 8];
  const int pwb = (c0 >> 1) + q * 2;

#define ALOADV(dst_, t_)                                                \
  {                                                                     \
    const ushort* p_ = abase + (t_) * 264;                              \
    union { uint u[4]; bf16x8 v; } au_;                                 \
    const uint2 lo_ = *(const uint2*)(p_);                              \
    const uint2 hi_ = *(const uint2*)(p_ + 4);                          \
    au_.u[0] = lo_.x; au_.u[1] = lo_.y;                                 \
    au_.u[2] = hi_.x; au_.u[3] = hi_.y;                                 \
    dst_ = au_.v;                                                       \
  }

  const float vm0 = ((c0 + q * 4 + 0) < 62) ? 1.f : 0.f;
  const float vm1 = ((c0 + q * 4 + 1) < 62) ? 1.f : 0.f;
  const float vm2 = ((c0 + q * 4 + 2) < 62) ? 1.f : 0.f;
  const float vm3 = ((c0 + q * 4 + 3) < 62) ? 1.f : 0.f;

  float ts = 0.f, tss = 0.f;
  float pp0 = 0.f, pp1 = 0.f;

#define ROWSTEP(r_, sA, sB, sC, sD, sE)                                 \
  {                                                                     \
    ALOADV(sE, (r_) + 4)                                                \
    f32x4 accA = {0.f, 0.f, 0.f, 0.f};                                  \
    f32x4 accB = {0.f, 0.f, 0.f, 0.f};                                  \
    accA = __builtin_amdgcn_mfma_f32_16x16x32_bf16(sA, wf0, accA, 0, 0, 0); \
    accB = __builtin_amdgcn_mfma_f32_16x16x32_bf16(sB, wf1, accB, 0, 0, 0); \
    accA = __builtin_amdgcn_mfma_f32_16x16x32_bf16(sC, wf2, accA, 0, 0, 0); \
    accB = __builtin_amdgcn_mfma_f32_16x16x32_bf16(sD, wf3, accB, 0, 0, 0); \
    accA = __builtin_amdgcn_mfma_f32_16x16x32_bf16(sE, wf4, accA, 0, 0, 0); \
    const float y0 = accA[0] + accB[0] + bias;                          \
    const float y1 = accA[1] + accB[1] + bias;                          \
    const float y2 = accA[2] + accB[2] + bias;                          \
    const float y3 = accA[3] + accB[3] + bias;                          \
    float t0 = y0 * vm0; ts += t0; tss = fmaf(t0, y0, tss);             \
    float t1 = y1 * vm1; ts += t1; tss = fmaf(t1, y1, tss);             \
    float t2 = y2 * vm2; ts += t2; tss = fmaf(t2, y2, tss);             \
    float t3 = y3 * vm3; ts += t3; tss = fmaf(t3, y3, tss);             \
    const float p0v = fmaxf(y0, y1), p1v = fmaxf(y2, y3);               \
    if (((r_) & 1) == 0) {                                              \
      pp0 = p0v; pp1 = p1v;                                             \
    } else if (oc < 10) {                                               \
      const int ph_ = (r_) >> 1;                                        \
      __hip_bfloat16* dst2_ =                                           \
          pool1 + (size_t)n * 9610 + (size_t)(ph_ * 31) * 10 + oc;      \
      const float q0_ = fmaxf(pp0, p0v), q1_ = fmaxf(pp1, p1v);         \
      dst2_[pwb * 10] = __float2bfloat16(q0_);                          \
      if (pwb + 1 < 31) dst2_[(pwb + 1) * 10] = __float2bfloat16(q1_);  \
    }                                                                   \
  }

  bf16x8 s0, s1, s2, s3, s4;
  ALOADV(s0, 0) ALOADV(s1, 1) ALOADV(s2, 2) ALOADV(s3, 3)

  for (int rb = 0; rb < 60; rb += 5) {
    ROWSTEP(rb + 0, s0, s1, s2, s3, s4)
    ROWSTEP(rb + 1, s1, s2, s3, s4, s0)
    ROWSTEP(rb + 2, s2, s3, s4, s0, s1)
    ROWSTEP(rb + 3, s3, s4, s0, s1, s2)
    ROWSTEP(rb + 4, s4, s0, s1, s2, s3)
  }
  // rows 60, 61 (register mapping is back to identity after 12 full turns)
  ROWSTEP(60, s0, s1, s2, s3, s4)
  ROWSTEP(61, s1, s2, s3, s4, s0)
#undef ROWSTEP
#undef ALOADV

  if (oc < 10) {
    atomicAdd(&sred[oc], ts);
    atomicAdd(&sred[10 + oc], tss);
  }
  __syncthreads();
  if (tid < 20) atomicAdd(&stats[tid], sred[tid]);
}

// ---------------- K2: finalize BN scale/shift ------------------------------
__global__ void k_bnfin(const float* __restrict__ bng,
                        const float* __restrict__ bnb,
                        float* __restrict__ stats)
{
  const int c = threadIdx.x;
  if (c < 10) {
    const float Ninv = 1.f / (4096.f * 3844.f);
    const float mean = stats[c] * Ninv;
    const float var = stats[10 + c] * Ninv - mean * mean;
    const float sc = bng[c] * rsqrtf(var + 1e-5f);
    stats[20 + c] = sc;
    stats[30 + c] = bnb[c] - mean * sc;
  }
}

// ---------------- K3: conv2 on MFMA, one image per wave --------------------
// out(r,pos,oc) = sum_{kh} sum_{j<50, j=kw*10+ic} Row[r+kh][pos*10+j] * W[oc][j,kh]
// Row[t][u] (u=pw_pad*10+ic) = BN-relu(pool1[n][t-1][pw_pad-1][ic]), zero borders.
// M=pos(28,pad32), N=oc(20,pad32), K=5 x 64 (j>=50 has zero B).
__global__ __launch_bounds__(TPB, 2) void k_conv2(
    const __hip_bfloat16* __restrict__ pool1, const float* __restrict__ stats,
    const float* __restrict__ w2c, const float* __restrict__ b2c,
    __hip_bfloat16* __restrict__ featb)
{
  __shared__ ushort R[4][4][344];          // [wave-image][slot][u], 11 KB
  __shared__ float ssc[10], ssh[10];
  const int tid = threadIdx.x;
  const int w = tid >> 6, lane = tid & 63;
  const int n = blockIdx.x * 4 + w;
  const int pos = lane & 31, q = lane >> 5;
  ushort (*Rw)[344] = R[w];

  if (tid < 10) { ssc[tid] = stats[20 + tid]; ssh[tid] = stats[30 + tid]; }
  // zero border cols of own 4 slots: u in [0,10) and [320,344)
  for (int i = lane; i < 136; i += 64) {
    const int s = i / 34, uu = i - 34 * s;
    Rw[s][(uu < 10) ? uu : (310 + uu)] = 0;
  }
  // zero fc1 K-pad cols for this image
  if (lane < 60) {
    uint* z = (uint*)((ushort*)featb + (size_t)n * 4160 + 3920);
    z[lane] = 0; z[lane + 60] = 0;
  }
  __syncthreads();

  // weight B-frags in VGPRs (j = kw*10+ic)
  bf16x8 wf[20];
#pragma unroll
  for (int kk = 0; kk < 20; kk++) {
    union { ushort u[8]; bf16x8 v; } bu;
    const int s = kk >> 2;
#pragma unroll
    for (int i = 0; i < 8; i++) {
      const int j = (kk & 3) * 16 + q * 8 + i;
      float wv = 0.f;
      if ((pos < 20) && (j < 50))
        wv = w2c[pos * 250 + (j % 10) * 25 + s * 5 + (j / 10)];
      bu.u[i] = f2b(wv);
    }
    wf[kk] = bu.v;
  }
  const float bias = (pos < 20) ? b2c[pos] : 0.f;

  const ushort* pp = (const ushort*)pool1 + (size_t)n * 9610;
  const int ic0 = (2 * lane) % 10;
  const int pos_e = (pos < 28) ? pos : pos - 16;
  const int pe10q8 = pos_e * 10 + q * 8;

  uint gv0, gv1, gv2;
#define GLOAD(t)                                                        \
  {                                                                     \
    const ushort* s_ = pp + ((t) - 1) * 310;                            \
    gv0 = *(const uint*)(s_ + 2 * lane);                                \
    gv1 = *(const uint*)(s_ + 2 * (lane + 64));                         \
    gv2 = (lane < 27) ? *(const uint*)(s_ + 2 * (lane + 128)) : 0u;     \
  }
#define GS1(c_, gv_)                                                    \
  {                                                                     \
    const int u2_ = lane + 64 * c_;                                     \
    if (c_ < 2 || lane < 27) {                                          \
      const int ia_ = (ic0 + 8 * c_) % 10;                              \
      const int ib_ = (ia_ == 9) ? 0 : ia_ + 1;                         \
      float a0_ = bf2f((ushort)(gv_ & 0xffffu));                        \
      float a1_ = bf2f((ushort)(gv_ >> 16));                            \
      a0_ = fmaxf(fmaf(a0_, ssc[ia_], ssh[ia_]), 0.f);                  \
      a1_ = fmaxf(fmaf(a1_, ssc[ib_], ssh[ib_]), 0.f);                  \
      *(uint*)(dst_ + 2 * u2_) = (uint)f2b(a0_) | ((uint)f2b(a1_) << 16);\
    }                                                                   \
  }
#define GSTORE(t)                                                       \
  {                                                                     \
    ushort* dst_ = &Rw[(t) & 3][10];                                    \
    GS1(0, gv0) GS1(1, gv1) GS1(2, gv2)                                 \
  }
#define FLOAD(t, ss)                                                    \
  {                                                                     \
    const ushort* bp_ = &Rw[(t) & 3][pe10q8];                           \
    _Pragma("unroll")                                                   \
    for (int sub_ = 0; sub_ < 4; sub_++) {                              \
      union { uint u[4]; bf16x8 v; } au_;                               \
      au_.u[0] = *(const uint*)(bp_ + sub_ * 16 + 0);                   \
      au_.u[1] = *(const uint*)(bp_ + sub_ * 16 + 2);                   \
      au_.u[2] = *(const uint*)(bp_ + sub_ * 16 + 4);                   \
      au_.u[3] = *(const uint*)(bp_ + sub_ * 16 + 6);                   \
      sets[ss][sub_] = au_.v;                                           \
    }                                                                   \
  }

  bf16x8 sets[5][4];
  const bf16x8 zfrag = (short)0;
#pragma unroll
  for (int s = 0; s < 4; s++) sets[0][s] = zfrag;   // t=0 border row

  GLOAD(1) GSTORE(1)
  GLOAD(2) GSTORE(2)
  GLOAD(3) GSTORE(3)
  GLOAD(4) GSTORE(4)
  GLOAD(5)
  __asm__ __volatile__("s_waitcnt lgkmcnt(0)" ::: "memory");
  FLOAD(1, 1) FLOAD(2, 2) FLOAD(3, 3)

  float php[8];
  for (int rb = 0; rb < 30; rb += 5) {
#pragma unroll
    for (int rr = 0; rr < 5; rr++) {
      const int r = rb + rr;
      __asm__ __volatile__("s_waitcnt lgkmcnt(0)" ::: "memory");
      if (r <= 27) FLOAD(r + 4, (rr + 4) % 5)
      if (r <= 26) GSTORE(r + 5)
      if (r <= 25) GLOAD(r + 6)
      if (r < 28) {
        f32x16 accA, accB;
#pragma unroll
        for (int z = 0; z < 16; z++) { accA[z] = 0.f; accB[z] = 0.f; }
#pragma unroll
        for (int kh = 0; kh < 5; kh++) {
          const int si = (rr + kh) % 5;
#pragma unroll
          for (int sub = 0; sub < 4; sub++) {
            if (kh & 1)
              accB = __builtin_amdgcn_mfma_f32_32x32x16_bf16(
                  sets[si][sub], wf[kh * 4 + sub], accB, 0, 0, 0);
            else
              accA = __builtin_amdgcn_mfma_f32_32x32x16_bf16(
                  sets[si][sub], wf[kh * 4 + sub], accA, 0, 0, 0);
          }
        }
        float hp[8];
#pragma unroll
        for (int p = 0; p < 8; p++)
          hp[p] = fmaxf(accA[2 * p] + accB[2 * p],
                        accA[2 * p + 1] + accB[2 * p + 1]);
        if ((r & 1) == 0) {
#pragma unroll
          for (int p = 0; p < 8; p++) php[p] = hp[p];
        } else if (pos < 20) {
          const int ph = r >> 1;
          ushort* dst = (ushort*)featb + (size_t)n * 4160 + pos * 196 + ph * 14;
#pragma unroll
          for (int j = 0; j < 4; j++) {
            const int pw = 4 * j + 2 * q;
            if (pw + 1 < 14) {
              const float v0 =
                  fmaxf(fmaxf(php[2 * j], hp[2 * j]) + bias, 0.f);
              const float v1 =
                  fmaxf(fmaxf(php[2 * j + 1], hp[2 * j + 1]) + bias, 0.f);
              *(uint*)(dst + pw) = (uint)f2b(v0) | ((uint)f2b(v1) << 16);
            }
          }
        }
      }
    }
  }
#undef GLOAD
#undef GS1
#undef GSTORE
#undef FLOAD
}

// ---------------- K3b: cast ew1 -> bf16 [1024][4160] -----------------------
__global__ __launch_bounds__(TPB) void k_castw1(
    const float* __restrict__ ew1, ushort* __restrict__ w1b)
{
  const int o = blockIdx.x;
  const int tid = threadIdx.x;
  const float* srow = ew1 + (size_t)o * 3920;
  ushort* drow = w1b + (size_t)o * 4160;
  for (int i = tid; i < 1040; i += TPB) {
    const int k4 = i * 4;
    ushort4 r;
    if (k4 < 3920) {
      const float4 v = *(const float4*)(srow + k4);
      r.x = f2b(v.x); r.y = f2b(v.y); r.z = f2b(v.z); r.w = f2b(v.w);
    } else {
      r.x = 0; r.y = 0; r.z = 0; r.w = 0;
    }
    *(ushort4*)(drow + k4) = r;
  }
}

// ---------------- K4a: gate fc1 partial GEMM (atomic K-split) --------------
__global__ __launch_bounds__(TPB) void k_gate1(
    const ushort* __restrict__ featb, const float* __restrict__ gw1,
    float* __restrict__ graw)
{
  __shared__ float sf[64 * 113];
  __shared__ float sw[64 * 113];
  const int tid = threadIdx.x;
  const int r0 = blockIdx.x * 64;
  const int kz = blockIdx.y;
  const int ty = tid >> 4, tx = tid & 15;
  float acc[4][4] = {{0.f}};
  for (int c = kz; c < 35; c += 4) {
    const int k0 = c * 112;
    for (int i = tid; i < 896; i += TPB) {
      const int row = i / 14, k8 = (i - row * 14) * 8;
      uint4 v = *(const uint4*)(featb + (size_t)(r0 + row) * 4160 + k0 + k8);
      const ushort* pv = (const ushort*)&v;
      float* d = &sf[row * 113 + k8];
#pragma unroll
      for (int t = 0; t < 8; t++) d[t] = bf2f(pv[t]);
    }
    for (int i = tid; i < 1792; i += TPB) {
      const int row = i / 28, c4 = (i - row * 28) * 4;
      float4 u = *(const float4*)(gw1 + (size_t)row * 3920 + k0 + c4);
      float* e = &sw[row * 113 + c4];
      e[0] = u.x; e[1] = u.y; e[2] = u.z; e[3] = u.w;
    }
    __syncthreads();
    for (int k = 0; k < 112; k++) {
      float a_[4], w_[4];
#pragma unroll
      for (int i = 0; i < 4; i++) a_[i] = sf[(ty * 4 + i) * 113 + k];
#pragma unroll
      for (int j = 0; j < 4; j++) w_[j] = sw[(tx * 4 + j) * 113 + k];
#pragma unroll
      for (int i = 0; i < 4; i++)
#pragma unroll
        for (int j = 0; j < 4; j++) acc[i][j] = fmaf(a_[i], w_[j], acc[i][j]);
    }
    __syncthreads();
  }
#pragma unroll
  for (int i = 0; i < 4; i++)
#pragma unroll
    for (int j = 0; j < 4; j++)
      atomicAdd(&graw[(size_t)(r0 + ty * 4 + i) * 64 + tx * 4 + j], acc[i][j]);
}

// ---------------- K4b: gate logits + top2 softmax + expert counts ----------
__global__ __launch_bounds__(TPB) void k_gate2(
    const float* __restrict__ graw, const float* __restrict__ gb1,
    const float* __restrict__ gw2, const float* __restrict__ gb2,
    int* __restrict__ sel0, int* __restrict__ sel1,
    float* __restrict__ wt0, float* __restrict__ wt1, int* __restrict__ counts)
{
  __shared__ float sw2[512], sb1[64], sb2[8];
  const int tid = threadIdx.x;
  for (int i = tid; i < 512; i += TPB) sw2[i] = gw2[i];
  if (tid < 64) sb1[tid] = gb1[tid];
  if (tid < 8) sb2[tid] = gb2[tid];
  __syncthreads();
  const int r = blockIdx.x * TPB + tid;
  float l[8];
#pragma unroll
  for (int c = 0; c < 8; c++) l[c] = sb2[c];
  const float* gr = graw + (size_t)r * 64;
  for (int k = 0; k < 64; k++) {
    const float hv = fmaxf(gr[k] + sb1[k], 0.f);
#pragma unroll
    for (int c = 0; c < 8; c++) l[c] = fmaf(hv, sw2[c * 64 + k], l[c]);
  }
  float v0 = -1e30f, v1 = -1e30f; int i0 = 0, i1 = 0;
#pragma unroll
  for (int c = 0; c < 8; c++) {
    const float lv = l[c];
    if (lv > v0) { v1 = v0; i1 = i0; v0 = lv; i0 = c; }
    else if (lv > v1) { v1 = lv; i1 = c; }
  }
  const float e1 = expf(v1 - v0);
  const float inv = 1.f / (1.f + e1);
  sel0[r] = i0; sel1[r] = i1; wt0[r] = inv; wt1[r] = e1 * inv;
  atomicAdd(&counts[i0], 1);
  atomicAdd(&counts[i1], 1);
}

// ---------------- K5: padded offsets + entry-list init ---------------------
__global__ void k_prep(int* __restrict__ hdrI, int* __restrict__ entrow)
{
  const int tid = threadIdx.x;
  if (tid == 0) {
    int run = 0;
    for (int e = 0; e < 8; e++) {
      const int c = hdrI[e];
      const int pc = (c + 31) & ~31;
      hdrI[16 + e] = pc;
      hdrI[24 + e] = run;
      run += pc;
    }
    hdrI[32] = run;
  }
  if (tid >= 8 && tid < 16) hdrI[tid] = 0;
  for (int i = tid; i < 8448; i += TPB) entrow[i] = -1;
}

// ---------------- K5b: scatter rows to expert entry lists ------------------
__global__ void k_scatter(const int* __restrict__ sel0, const int* __restrict__ sel1,
                          int* __restrict__ hdrI, int* __restrict__ entrow,
                          int* __restrict__ p0, int* __restrict__ p1)
{
  const int r = blockIdx.x * TPB + threadIdx.x;
  const int e0 = sel0[r];
  int pos = atomicAdd(&hdrI[8 + e0], 1) + hdrI[24 + e0];
  entrow[pos] = r; p0[r] = pos;
  const int e1 = sel1[r];
  pos = atomicAdd(&hdrI[8 + e1], 1) + hdrI[24 + e1];
  entrow[pos] = r; p1[r] = pos;
}

// ---------------- K6: dense MFMA fc1 -> h1 bf16 [4096][1024] ---------------
__global__ __launch_bounds__(512) void k_fc1(
    const ushort* __restrict__ featb, const ushort* __restrict__ w1b,
    const float* __restrict__ eb1, __hip_bfloat16* __restrict__ h1b)
{
  __shared__ ushort As[128 * 72];
  __shared__ ushort Bs[128 * 72];
  const int tid = threadIdx.x;
  const int r0 = blockIdx.x * 128;
  const int c0 = blockIdx.y * 128;
  const int w = tid >> 6, lane = tid & 63;
  const int wr = (w >> 1) * 32, wc = (w & 1) * 64;
  const int m = lane & 15, q = lane >> 4;
  f32x4 acc[2][4];
#pragma unroll
  for (int i = 0; i < 2; i++)
#pragma unroll
    for (int j = 0; j < 4; j++) acc[i][j] = 0.f;

  for (int kc = 0; kc < 4096; kc += 64) {
#pragma unroll
    for (int i = 0; i < 2; i++) {
      const int u = tid + 512 * i;
      const int row = u >> 3, k8 = (u & 7) * 8;
      *(uint4*)(&As[row * 72 + k8]) =
          *(const uint4*)(featb + (size_t)(r0 + row) * 4160 + kc + k8);
      *(uint4*)(&Bs[row * 72 + k8]) =
          *(const uint4*)(w1b + (size_t)(c0 + row) * 4160 + kc + k8);
    }
    __syncthreads();
#pragma unroll
    for (int kk = 0; kk < 64; kk += 32) {
      bf16x8 af[2], bf[4];
#pragma unroll
      for (int t = 0; t < 2; t++)
        af[t] = *(const bf16x8*)(&As[(wr + t * 16 + m) * 72 + kk + q * 8]);
#pragma unroll
      for (int t = 0; t < 4; t++)
        bf[t] = *(const bf16x8*)(&Bs[(wc + t * 16 + m) * 72 + kk + q * 8]);
#pragma unroll
      for (int ti = 0; ti < 2; ti++)
#pragma unroll
        for (int tj = 0; tj < 4; tj++)
          acc[ti][tj] = __builtin_amdgcn_mfma_f32_16x16x32_bf16(
              af[ti], bf[tj], acc[ti][tj], 0, 0, 0);
    }
    __syncthreads();
  }
#pragma unroll
  for (int tj = 0; tj < 4; tj++) {
    const int c = c0 + wc + tj * 16 + m;
    const float bb = eb1[c];
#pragma unroll
    for (int ti = 0; ti < 2; ti++) {
      const int rbase = r0 + wr + ti * 16 + q * 4;
#pragma unroll
      for (int i = 0; i < 4; i++) {
        const float v = fmaxf(acc[ti][tj][i] + bb, 0.f);
        h1b[(size_t)(rbase + i) * 1024 + c] = __float2bfloat16(v);
      }
    }
  }
}

// ---------------- K7: dense fc2 -> h2 fp32 [4096][512] ---------------------
__global__ __launch_bounds__(TPB) void k_fc2(
    const __hip_bfloat16* __restrict__ h1b, const float* __restrict__ ew2,
    const float* __restrict__ eb2, float* __restrict__ h2)
{
  __shared__ float h1s[64 * 132];
  __shared__ ushort w2s[128 * 72];
  const int tid = threadIdx.x;
  const int r0 = blockIdx.x * 64;
  const int e = blockIdx.y;
  const ushort* hp = (const ushort*)h1b;
#pragma unroll
  for (int i = 0; i < 4; i++) {
    const int u = tid + 256 * i;
    const int row = u >> 4, k8 = (u & 15) * 8;
    uint4 v = *(const uint4*)(hp + (size_t)(r0 + row) * 1024 + e * 128 + k8);
    const ushort* pv = (const ushort*)&v;
    float* d = &h1s[row * 132 + k8];
#pragma unroll
    for (int t = 0; t < 8; t++) d[t] = bf2f(pv[t]);
  }
#pragma unroll
  for (int i = 0; i < 8; i++) {
    const int u = tid + 256 * i;
    const int nn = u >> 5, k4 = (u & 31) * 4;
    const float4 v = *(const float4*)(ew2 + (size_t)e * 8192 + nn * 128 + k4);
    w2s[(k4 + 0) * 72 + nn] = f2b(v.x);
    w2s[(k4 + 1) * 72 + nn] = f2b(v.y);
    w2s[(k4 + 2) * 72 + nn] = f2b(v.z);
    w2s[(k4 + 3) * 72 + nn] = f2b(v.w);
  }
  __syncthreads();
  const int ty = tid >> 4, tx = tid & 15;
  float acc[4][4] = {{0.f}};
  for (int k4 = 0; k4 < 32; k4++) {
    f32x4 a4[4];
#pragma unroll
    for (int i = 0; i < 4; i++)
      a4[i] = *(const f32x4*)(&h1s[(ty * 4 + i) * 132 + k4 * 4]);
#pragma unroll
    for (int kk = 0; kk < 4; kk++) {
      const ushort4 wu = *(const ushort4*)(&w2s[(k4 * 4 + kk) * 72 + tx * 4]);
      const float w0 = bf2f(wu.x), w1 = bf2f(wu.y);
      const float w2_ = bf2f(wu.z), w3 = bf2f(wu.w);
#pragma unroll
      for (int i = 0; i < 4; i++) {
        acc[i][0] = fmaf(a4[i][kk], w0, acc[i][0]);
        acc[i][1] = fmaf(a4[i][kk], w1, acc[i][1]);
        acc[i][2] = fmaf(a4[i][kk], w2_, acc[i][2]);
        acc[i][3] = fmaf(a4[i][kk], w3, acc[i][3]);
      }
    }
  }
  const f32x4 bb = *(const f32x4*)(eb2 + e * 64 + tx * 4);
#pragma unroll
  for (int i = 0; i < 4; i++) {
    f32x4 r;
#pragma unroll
    for (int j = 0; j < 4; j++) r[j] = fmaxf(acc[i][j] + bb[j], 0.f);
    *(f32x4*)(h2 + (size_t)(r0 + ty * 4 + i) * 512 + e * 64 + tx * 4) = r;
  }
}

// ---------------- K8: grouped fc3 -> eo [pos][1000] ------------------------
__global__ __launch_bounds__(TPB) void k_fc3(
    const float* __restrict__ h2, const float* __restrict__ ew3,
    const float* __restrict__ eb3, const int* __restrict__ hdrI,
    const int* __restrict__ entrow, float* __restrict__ eo)
{
  __shared__ float h2s[32 * 68];
  __shared__ float w3s[64 * 132];
  const int e = blockIdx.y;
  const int pcnt = hdrI[16 + e];
  if ((int)blockIdx.x * 32 >= pcnt) return;
  const int base = hdrI[24 + e] + blockIdx.x * 32;
  const int tid = threadIdx.x;
  for (int i = tid; i < 512; i += TPB) {
    const int row = i >> 4, k4 = (i & 15) * 4;
    const int rr = entrow[base + row];
    f32x4 v = 0.f;
    if (rr >= 0) v = *(const f32x4*)(h2 + (size_t)rr * 512 + e * 64 + k4);
    *(f32x4*)(&h2s[row * 68 + k4]) = v;
  }
  const int ty = tid >> 5, tx = tid & 31;
  const float* w3p = ew3 + (size_t)e * 64000;
  const float* b3p = eb3 + (size_t)e * 1000;
  for (int nc = 0; nc < 8; nc++) {
    const int o0 = nc * 128;
    for (int i = tid; i < 2048; i += TPB) {
      const int oo = i >> 4, k4 = (i & 15) * 4;
      const int o = o0 + oo;
      f32x4 u = 0.f;
      if (o < 1000) u = *(const f32x4*)(w3p + (size_t)o * 64 + k4);
      w3s[(k4 + 0) * 132 + oo] = u[0];
      w3s[(k4 + 1) * 132 + oo] = u[1];
      w3s[(k4 + 2) * 132 + oo] = u[2];
      w3s[(k4 + 3) * 132 + oo] = u[3];
    }
    __syncthreads();
    float acc[4][4] = {{0.f}};
    for (int k4 = 0; k4 < 16; k4++) {
      f32x4 a4[4], w4[4];
#pragma unroll
      for (int i = 0; i < 4; i++)
        a4[i] = *(const f32x4*)(&h2s[(ty * 4 + i) * 68 + k4 * 4]);
#pragma unroll
      for (int kk = 0; kk < 4; kk++)
        w4[kk] = *(const f32x4*)(&w3s[(k4 * 4 + kk) * 132 + tx * 4]);
#pragma unroll
      for (int kk = 0; kk < 4; kk++)
#pragma unroll
        for (int i = 0; i < 4; i++)
#pragma unroll
          for (int j = 0; j < 4; j++)
            acc[i][j] = fmaf(a4[i][kk], w4[kk][j], acc[i][j]);
    }
    const int o = o0 + tx * 4;
    if (o + 3 < 1000) {
      const f32x4 bb = *(const f32x4*)(b3p + o);
#pragma unroll
      for (int i = 0; i < 4; i++) {
        f32x4 r;
#pragma unroll
        for (int j = 0; j < 4; j++) r[j] = acc[i][j] + bb[j];
        *(f32x4*)(eo + (size_t)(base + ty * 4 + i) * 1000 + o) = r;
      }
    }
    __syncthreads();
  }
}

// ---------------- K9: gate-combine + log_softmax(|.|) ----------------------
__global__ __launch_bounds__(TPB) void k_out(
    const float* __restrict__ eo, const int* __restrict__ p0,
    const int* __restrict__ p1, const float* __restrict__ wt0,
    const float* __restrict__ wt1, float* __restrict__ out)
{
  __shared__ float sv[1000];
  __shared__ float sr[8];
  const int r = blockIdx.x, tid = threadIdx.x;
  const float w0 = wt0[r], w1 = wt1[r];
  const float* a = eo + (size_t)p0[r] * 1000;
  const float* b = eo + (size_t)p1[r] * 1000;
  float lmax = -3.4e38f;
  for (int o = tid; o < 1000; o += TPB) {
    const float v = fabsf(w0 * a[o] + w1 * b[o]);
    sv[o] = v;
    lmax = fmaxf(lmax, v);
  }
#pragma unroll
  for (int off = 32; off; off >>= 1) lmax = fmaxf(lmax, __shfl_down(lmax, off));
  if ((tid & 63) == 0) sr[tid >> 6] = lmax;
  __syncthreads();
  const float mx = fmaxf(fmaxf(sr[0], sr[1]), fmaxf(sr[2], sr[3]));
  float lsum = 0.f;
  for (int o = tid; o < 1000; o += TPB) lsum += expf(sv[o] - mx);
#pragma unroll
  for (int off = 32; off; off >>= 1) lsum += __shfl_down(lsum, off);
  if ((tid & 63) == 0) sr[4 + (tid >> 6)] = lsum;
  __syncthreads();
  const float lse = logf(sr[4] + sr[5] + sr[6] + sr[7]);
  const float sub = mx + lse;
  for (int o = tid; o < 1000; o += TPB)
    out[(size_t)r * 1000 + o] = sv[o] - sub;
}

// ---------------------------------------------------------------------------
extern "C" void kernel_launch(void* const* d_in, const int* in_sizes, int n_in,
                              void* d_out, int out_size, void* d_ws, size_t ws_size,
                              hipStream_t stream)
{
  (void)in_sizes; (void)n_in; (void)out_size; (void)ws_size;
  const float* x   = (const float*)d_in[0];
  const float* c1w = (const float*)d_in[1];
  const float* c1b = (const float*)d_in[2];
  const float* bng = (const float*)d_in[3];
  const float* bnb = (const float*)d_in[4];
  const float* c2w = (const float*)d_in[5];
  const float* c2b = (const float*)d_in[6];
  const float* gw1 = (const float*)d_in[7];
  const float* gb1 = (const float*)d_in[8];
  const float* gw2 = (const float*)d_in[9];
  const float* gb2 = (const float*)d_in[10];
  const float* ew1 = (const float*)d_in[11];
  const float* eb1 = (const float*)d_in[12];
  const float* ew2 = (const float*)d_in[13];
  const float* eb2 = (const float*)d_in[14];
  const float* ew3 = (const float*)d_in[15];
  const float* eb3 = (const float*)d_in[16];

  char* ws = (char*)d_ws;
  float* statsF = (float*)ws;
  int*   hdrI   = (int*)(ws + 256);
  int*   sel0   = (int*)(ws + 1024);
  int*   sel1   = (int*)(ws + 17408);
  float* wt0    = (float*)(ws + 33792);
  float* wt1    = (float*)(ws + 50176);
  int*   p0     = (int*)(ws + 66560);
  int*   p1     = (int*)(ws + 82944);
  int*   entrow = (int*)(ws + 99328);
  float* graw   = (float*)(ws + 133120);
  float* eo     = (float*)(ws + 1181696);
  __hip_bfloat16* h1b = (__hip_bfloat16*)(ws + 34973696);
  float* h2     = (float*)(ws + 43362304);
  __hip_bfloat16* pool1 = (__hip_bfloat16*)(ws + 51750912);
  __hip_bfloat16* featb = (__hip_bfloat16*)(ws + 130476032);
  ushort* w1b   = (ushort*)(ws + 164554752);

  hipMemsetAsync(ws, 0, 512, stream);
  hipMemsetAsync(graw, 0, 4096 * 64 * sizeof(float), stream);

  k_castw1 <<<1024, TPB, 0, stream>>>(ew1, w1b);
  k_conv1  <<<4096, TPB, 0, stream>>>(x, c1w, c1b, pool1, statsF);
  k_bnfin  <<<1, 64, 0, stream>>>(bng, bnb, statsF);
  k_conv2  <<<1024, TPB, 0, stream>>>(pool1, statsF, c2w, c2b, featb);
  k_gate1  <<<dim3(64, 4), TPB, 0, stream>>>((const ushort*)featb, gw1, graw);
  k_gate2  <<<16, TPB, 0, stream>>>(graw, gb1, gw2, gb2, sel0, sel1, wt0, wt1, hdrI);
  k_prep   <<<1, TPB, 0, stream>>>(hdrI, entrow);
  k_scatter<<<16, TPB, 0, stream>>>(sel0, sel1, hdrI, entrow, p0, p1);
  k_fc1    <<<dim3(32, 8), 512, 0, stream>>>((const ushort*)featb, w1b, eb1, h1b);
  k_fc2    <<<dim3(64, 8), TPB, 0, stream>>>(h1b, ew2, eb2, h2);
  k_fc3    <<<dim3(128, 8), TPB, 0, stream>>>(h2, ew3, eb3, hdrI, entrow, eo);
  k_out    <<<4096, TPB, 0, stream>>>(eo, p0, p1, wt0, wt1, (float*)d_out);
}

// Round 8
// 867.407 us; speedup vs baseline: 1.7073x; 1.0437x over previous
//
#include <hip/hip_runtime.h>
#include <hip/hip_bf16.h>

// ---------------------------------------------------------------------------
// Net_83674552861196 — round 13: conv1 rotate-6 prefetch + gate1 kz 4->8.
//  - conv1 (146us, VALU 49 / MFMA 24, 27% idle): rotate-5 loaded slice r+4
//    inside the row that consumes it (WAR on dest reg held it back). Rotate-6
//    adds ONE named register so each ds_read issues a full row ahead
//    (~100cy of MFMA+epilogue covers the ~120cy LDS latency). No new
//    address arithmetic (register-cliff lesson from rounds 8-11); fully
//    static 6-row unroll; +1 guard slice in LDS (35.4 KB, still 4 blk/CU).
//  - gate1: grid 256 blocks = 1 blk/CU, ~16k serial FMAs/thread. kz split
//    4->8 (512 blocks, half work/thread); atomicAdd makes split exact.
//  - Everything else unchanged from round 12 (banked 905 us).
// ---------------------------------------------------------------------------

#define TPB 256

typedef __attribute__((ext_vector_type(8))) short bf16x8;
typedef __attribute__((ext_vector_type(4))) float f32x4;
typedef __attribute__((ext_vector_type(16))) float f32x16;

__device__ __forceinline__ float bf2f(unsigned short u) {
  return __uint_as_float(((unsigned)u) << 16);
}
__device__ __forceinline__ ushort f2b(float f) {
  __hip_bfloat16 h = __float2bfloat16(f);
  return *(ushort*)&h;
}

// ---------------- K1: conv1 (MFMA) + raw-maxpool + BN statistics -----------
// out(r,pos,oc) = sum_{kh} sum_{j<20, j=kw*4+ic, ic<3} Row[r+kh][pos*4+j]*W
// Row[t][u] (u = pcol*4+ic) = x[ic][t-1][pcol-1], zero borders.
__global__ __launch_bounds__(TPB, 4) void k_conv1(
    const float* __restrict__ x, const float* __restrict__ w1c,
    const float* __restrict__ b1c, __hip_bfloat16* __restrict__ pool1,
    float* __restrict__ stats)
{
  __shared__ uint4 imgI4[2214];          // 35424 B (67 slices incl. prefetch guard)
  __shared__ float sred[20];
  ushort* imgI = (ushort*)imgI4;
  const int tid = threadIdx.x;
  const int lane = tid & 63;
  const int w = tid >> 6;
  const int n = blockIdx.x;
  const int oc = lane & 15;
  const int q = lane >> 4;
  const int c0 = w * 16;

  {
    const uint4 z = {0u, 0u, 0u, 0u};
    for (int i = tid; i < 2214; i += TPB) imgI4[i] = z;
    if (tid < 20) sred[tid] = 0.f;
  }
  __syncthreads();

  // stage image: rows 1..64, cols 1..64, channel-interleaved (ic slot 3 = 0)
  {
    const float* xp = x + (size_t)n * 12288;
#pragma unroll
    for (int it = 0; it < 4; it++) {
      const int g = tid + 256 * it;              // 0..1023
      const int row = g >> 4, col0 = (g & 15) * 4;
      const float4 v0 = *(const float4*)(xp + row * 64 + col0);
      const float4 v1 = *(const float4*)(xp + 4096 + row * 64 + col0);
      const float4 v2 = *(const float4*)(xp + 8192 + row * 64 + col0);
      ushort* d = &imgI[((row + 1) * 66 + (col0 + 1)) * 4];
      uint2 t0, t1, t2, t3;
      t0.x = (uint)f2b(v0.x) | ((uint)f2b(v1.x) << 16); t0.y = (uint)f2b(v2.x);
      t1.x = (uint)f2b(v0.y) | ((uint)f2b(v1.y) << 16); t1.y = (uint)f2b(v2.y);
      t2.x = (uint)f2b(v0.z) | ((uint)f2b(v1.z) << 16); t2.y = (uint)f2b(v2.z);
      t3.x = (uint)f2b(v0.w) | ((uint)f2b(v1.w) << 16); t3.y = (uint)f2b(v2.w);
      *(uint2*)(d + 0)  = t0;
      *(uint2*)(d + 4)  = t1;
      *(uint2*)(d + 8)  = t2;
      *(uint2*)(d + 12) = t3;
    }
  }

  // weight B-frags: 5 kh K-steps, named registers (no arrays!).
  // slot j = kw*4+ic (j<20, ic<3 real), K padded to 32 with zeros.
  bf16x8 wf0, wf1, wf2, wf3, wf4;
#define WLOAD(dst_, kh_)                                                \
  {                                                                     \
    union { ushort u[8]; bf16x8 v; } bu_;                               \
    _Pragma("unroll")                                                   \
    for (int i = 0; i < 8; i++) {                                       \
      const int j = q * 8 + i;                                          \
      float wv = 0.f;                                                   \
      if (oc < 10 && j < 20 && (j & 3) < 3)                             \
        wv = w1c[oc * 75 + (j & 3) * 25 + (kh_) * 5 + (j >> 2)];        \
      bu_.u[i] = f2b(wv);                                               \
    }                                                                   \
    dst_ = bu_.v;                                                       \
  }
  WLOAD(wf0, 0) WLOAD(wf1, 1) WLOAD(wf2, 2) WLOAD(wf3, 3) WLOAD(wf4, 4)
#undef WLOAD
  const float bias = (oc < 10) ? b1c[oc] : 0.f;

  __syncthreads();

  const int pos_A = c0 + oc;                    // A-matrix row (output col)
  const ushort* abase = &imgI[pos_A * 4 + q * 8];
  const int pwb = (c0 >> 1) + q * 2;

#define ALOADV(dst_, t_)                                                \
  {                                                                     \
    const ushort* p_ = abase + (t_) * 264;                              \
    union { uint u[4]; bf16x8 v; } au_;                                 \
    const uint2 lo_ = *(const uint2*)(p_);                              \
    const uint2 hi_ = *(const uint2*)(p_ + 4);                          \
    au_.u[0] = lo_.x; au_.u[1] = lo_.y;                                 \
    au_.u[2] = hi_.x; au_.u[3] = hi_.y;                                 \
    dst_ = au_.v;                                                       \
  }

  const float vm0 = ((c0 + q * 4 + 0) < 62) ? 1.f : 0.f;
  const float vm1 = ((c0 + q * 4 + 1) < 62) ? 1.f : 0.f;
  const float vm2 = ((c0 + q * 4 + 2) < 62) ? 1.f : 0.f;
  const float vm3 = ((c0 + q * 4 + 3) < 62) ? 1.f : 0.f;

  float ts = 0.f, tss = 0.f;
  float pp0 = 0.f, pp1 = 0.f;

  // rotate-6: row r consumes slices r..r+4 (sA..sE) and PREFETCHES slice
  // r+5 into sF (the register freed after row r-1). The ds_read result is
  // first needed at row r+1's LAST MFMA -> a full row of MFMA+epilogue
  // hides the LDS latency.
#define ROWSTEP(r_, sA, sB, sC, sD, sE, sF)                             \
  {                                                                     \
    ALOADV(sF, (r_) + 5)                                                \
    f32x4 accA = {0.f, 0.f, 0.f, 0.f};                                  \
    f32x4 accB = {0.f, 0.f, 0.f, 0.f};                                  \
    accA = __builtin_amdgcn_mfma_f32_16x16x32_bf16(sA, wf0, accA, 0, 0, 0); \
    accB = __builtin_amdgcn_mfma_f32_16x16x32_bf16(sB, wf1, accB, 0, 0, 0); \
    accA = __builtin_amdgcn_mfma_f32_16x16x32_bf16(sC, wf2, accA, 0, 0, 0); \
    accB = __builtin_amdgcn_mfma_f32_16x16x32_bf16(sD, wf3, accB, 0, 0, 0); \
    accA = __builtin_amdgcn_mfma_f32_16x16x32_bf16(sE, wf4, accA, 0, 0, 0); \
    const float y0 = accA[0] + accB[0] + bias;                          \
    const float y1 = accA[1] + accB[1] + bias;                          \
    const float y2 = accA[2] + accB[2] + bias;                          \
    const float y3 = accA[3] + accB[3] + bias;                          \
    float t0 = y0 * vm0; ts += t0; tss = fmaf(t0, y0, tss);             \
    float t1 = y1 * vm1; ts += t1; tss = fmaf(t1, y1, tss);             \
    float t2 = y2 * vm2; ts += t2; tss = fmaf(t2, y2, tss);             \
    float t3 = y3 * vm3; ts += t3; tss = fmaf(t3, y3, tss);             \
    const float p0v = fmaxf(y0, y1), p1v = fmaxf(y2, y3);               \
    if (((r_) & 1) == 0) {                                              \
      pp0 = p0v; pp1 = p1v;                                             \
    } else if (oc < 10) {                                               \
      const int ph_ = (r_) >> 1;                                        \
      __hip_bfloat16* dst2_ =                                           \
          pool1 + (size_t)n * 9610 + (size_t)(ph_ * 31) * 10 + oc;      \
      const float q0_ = fmaxf(pp0, p0v), q1_ = fmaxf(pp1, p1v);         \
      dst2_[pwb * 10] = __float2bfloat16(q0_);                          \
      if (pwb + 1 < 31) dst2_[(pwb + 1) * 10] = __float2bfloat16(q1_);  \
    }                                                                   \
  }

  bf16x8 s0, s1, s2, s3, s4, s5;
  ALOADV(s0, 0) ALOADV(s1, 1) ALOADV(s2, 2) ALOADV(s3, 3) ALOADV(s4, 4)

  for (int rb = 0; rb < 60; rb += 6) {
    ROWSTEP(rb + 0, s0, s1, s2, s3, s4, s5)
    ROWSTEP(rb + 1, s1, s2, s3, s4, s5, s0)
    ROWSTEP(rb + 2, s2, s3, s4, s5, s0, s1)
    ROWSTEP(rb + 3, s3, s4, s5, s0, s1, s2)
    ROWSTEP(rb + 4, s4, s5, s0, s1, s2, s3)
    ROWSTEP(rb + 5, s5, s0, s1, s2, s3, s4)
  }
  // rows 60, 61: after 10 full turns s0..s4 hold slices 60..64.
  // Row 61's prefetch targets slice 66 (zeroed guard, result unused).
  ROWSTEP(60, s0, s1, s2, s3, s4, s5)
  ROWSTEP(61, s1, s2, s3, s4, s5, s0)
#undef ROWSTEP
#undef ALOADV

  if (oc < 10) {
    atomicAdd(&sred[oc], ts);
    atomicAdd(&sred[10 + oc], tss);
  }
  __syncthreads();
  if (tid < 20) atomicAdd(&stats[tid], sred[tid]);
}

// ---------------- K2: finalize BN scale/shift ------------------------------
__global__ void k_bnfin(const float* __restrict__ bng,
                        const float* __restrict__ bnb,
                        float* __restrict__ stats)
{
  const int c = threadIdx.x;
  if (c < 10) {
    const float Ninv = 1.f / (4096.f * 3844.f);
    const float mean = stats[c] * Ninv;
    const float var = stats[10 + c] * Ninv - mean * mean;
    const float sc = bng[c] * rsqrtf(var + 1e-5f);
    stats[20 + c] = sc;
    stats[30 + c] = bnb[c] - mean * sc;
  }
}

// ---------------- K3: conv2 on MFMA, one image per wave --------------------
// out(r,pos,oc) = sum_{kh} sum_{j<50, j=kw*10+ic} Row[r+kh][pos*10+j] * W[oc][j,kh]
// Row[t][u] (u=pw_pad*10+ic) = BN-relu(pool1[n][t-1][pw_pad-1][ic]), zero borders.
// M=pos(28,pad32), N=oc(20,pad32), K=5 x 64 (j>=50 has zero B).
__global__ __launch_bounds__(TPB, 2) void k_conv2(
    const __hip_bfloat16* __restrict__ pool1, const float* __restrict__ stats,
    const float* __restrict__ w2c, const float* __restrict__ b2c,
    __hip_bfloat16* __restrict__ featb)
{
  __shared__ ushort R[4][4][344];          // [wave-image][slot][u], 11 KB
  __shared__ float ssc[10], ssh[10];
  const int tid = threadIdx.x;
  const int w = tid >> 6, lane = tid & 63;
  const int n = blockIdx.x * 4 + w;
  const int pos = lane & 31, q = lane >> 5;
  ushort (*Rw)[344] = R[w];

  if (tid < 10) { ssc[tid] = stats[20 + tid]; ssh[tid] = stats[30 + tid]; }
  // zero border cols of own 4 slots: u in [0,10) and [320,344)
  for (int i = lane; i < 136; i += 64) {
    const int s = i / 34, uu = i - 34 * s;
    Rw[s][(uu < 10) ? uu : (310 + uu)] = 0;
  }
  // zero fc1 K-pad cols for this image
  if (lane < 60) {
    uint* z = (uint*)((ushort*)featb + (size_t)n * 4160 + 3920);
    z[lane] = 0; z[lane + 60] = 0;
  }
  __syncthreads();

  // weight B-frags in VGPRs (j = kw*10+ic)
  bf16x8 wf[20];
#pragma unroll
  for (int kk = 0; kk < 20; kk++) {
    union { ushort u[8]; bf16x8 v; } bu;
    const int s = kk >> 2;
#pragma unroll
    for (int i = 0; i < 8; i++) {
      const int j = (kk & 3) * 16 + q * 8 + i;
      float wv = 0.f;
      if ((pos < 20) && (j < 50))
        wv = w2c[pos * 250 + (j % 10) * 25 + s * 5 + (j / 10)];
      bu.u[i] = f2b(wv);
    }
    wf[kk] = bu.v;
  }
  const float bias = (pos < 20) ? b2c[pos] : 0.f;

  const ushort* pp = (const ushort*)pool1 + (size_t)n * 9610;
  const int ic0 = (2 * lane) % 10;
  const int pos_e = (pos < 28) ? pos : pos - 16;
  const int pe10q8 = pos_e * 10 + q * 8;

  uint gv0, gv1, gv2;
#define GLOAD(t)                                                        \
  {                                                                     \
    const ushort* s_ = pp + ((t) - 1) * 310;                            \
    gv0 = *(const uint*)(s_ + 2 * lane);                                \
    gv1 = *(const uint*)(s_ + 2 * (lane + 64));                         \
    gv2 = (lane < 27) ? *(const uint*)(s_ + 2 * (lane + 128)) : 0u;     \
  }
#define GS1(c_, gv_)                                                    \
  {                                                                     \
    const int u2_ = lane + 64 * c_;                                     \
    if (c_ < 2 || lane < 27) {                                          \
      const int ia_ = (ic0 + 8 * c_) % 10;                              \
      const int ib_ = (ia_ == 9) ? 0 : ia_ + 1;                         \
      float a0_ = bf2f((ushort)(gv_ & 0xffffu));                        \
      float a1_ = bf2f((ushort)(gv_ >> 16));                            \
      a0_ = fmaxf(fmaf(a0_, ssc[ia_], ssh[ia_]), 0.f);                  \
      a1_ = fmaxf(fmaf(a1_, ssc[ib_], ssh[ib_]), 0.f);                  \
      *(uint*)(dst_ + 2 * u2_) = (uint)f2b(a0_) | ((uint)f2b(a1_) << 16);\
    }                                                                   \
  }
#define GSTORE(t)                                                       \
  {                                                                     \
    ushort* dst_ = &Rw[(t) & 3][10];                                    \
    GS1(0, gv0) GS1(1, gv1) GS1(2, gv2)                                 \
  }
#define FLOAD(t, ss)                                                    \
  {                                                                     \
    const ushort* bp_ = &Rw[(t) & 3][pe10q8];                           \
    _Pragma("unroll")                                                   \
    for (int sub_ = 0; sub_ < 4; sub_++) {                              \
      union { uint u[4]; bf16x8 v; } au_;                               \
      au_.u[0] = *(const uint*)(bp_ + sub_ * 16 + 0);                   \
      au_.u[1] = *(const uint*)(bp_ + sub_ * 16 + 2);                   \
      au_.u[2] = *(const uint*)(bp_ + sub_ * 16 + 4);                   \
      au_.u[3] = *(const uint*)(bp_ + sub_ * 16 + 6);                   \
      sets[ss][sub_] = au_.v;                                           \
    }                                                                   \
  }

  bf16x8 sets[5][4];
  const bf16x8 zfrag = (short)0;
#pragma unroll
  for (int s = 0; s < 4; s++) sets[0][s] = zfrag;   // t=0 border row

  GLOAD(1) GSTORE(1)
  GLOAD(2) GSTORE(2)
  GLOAD(3) GSTORE(3)
  GLOAD(4) GSTORE(4)
  GLOAD(5)
  __asm__ __volatile__("s_waitcnt lgkmcnt(0)" ::: "memory");
  FLOAD(1, 1) FLOAD(2, 2) FLOAD(3, 3)

  float php[8];
  for (int rb = 0; rb < 30; rb += 5) {
#pragma unroll
    for (int rr = 0; rr < 5; rr++) {
      const int r = rb + rr;
      __asm__ __volatile__("s_waitcnt lgkmcnt(0)" ::: "memory");
      if (r <= 27) FLOAD(r + 4, (rr + 4) % 5)
      if (r <= 26) GSTORE(r + 5)
      if (r <= 25) GLOAD(r + 6)
      if (r < 28) {
        f32x16 accA, accB;
#pragma unroll
        for (int z = 0; z < 16; z++) { accA[z] = 0.f; accB[z] = 0.f; }
#pragma unroll
        for (int kh = 0; kh < 5; kh++) {
          const int si = (rr + kh) % 5;
#pragma unroll
          for (int sub = 0; sub < 4; sub++) {
            if (kh & 1)
              accB = __builtin_amdgcn_mfma_f32_32x32x16_bf16(
                  sets[si][sub], wf[kh * 4 + sub], accB, 0, 0, 0);
            else
              accA = __builtin_amdgcn_mfma_f32_32x32x16_bf16(
                  sets[si][sub], wf[kh * 4 + sub], accA, 0, 0, 0);
          }
        }
        float hp[8];
#pragma unroll
        for (int p = 0; p < 8; p++)
          hp[p] = fmaxf(accA[2 * p] + accB[2 * p],
                        accA[2 * p + 1] + accB[2 * p + 1]);
        if ((r & 1) == 0) {
#pragma unroll
          for (int p = 0; p < 8; p++) php[p] = hp[p];
        } else if (pos < 20) {
          const int ph = r >> 1;
          ushort* dst = (ushort*)featb + (size_t)n * 4160 + pos * 196 + ph * 14;
#pragma unroll
          for (int j = 0; j < 4; j++) {
            const int pw = 4 * j + 2 * q;
            if (pw + 1 < 14) {
              const float v0 =
                  fmaxf(fmaxf(php[2 * j], hp[2 * j]) + bias, 0.f);
              const float v1 =
                  fmaxf(fmaxf(php[2 * j + 1], hp[2 * j + 1]) + bias, 0.f);
              *(uint*)(dst + pw) = (uint)f2b(v0) | ((uint)f2b(v1) << 16);
            }
          }
        }
      }
    }
  }
#undef GLOAD
#undef GS1
#undef GSTORE
#undef FLOAD
}

// ---------------- K3b: cast ew1 -> bf16 [1024][4160] -----------------------
__global__ __launch_bounds__(TPB) void k_castw1(
    const float* __restrict__ ew1, ushort* __restrict__ w1b)
{
  const int o = blockIdx.x;
  const int tid = threadIdx.x;
  const float* srow = ew1 + (size_t)o * 3920;
  ushort* drow = w1b + (size_t)o * 4160;
  for (int i = tid; i < 1040; i += TPB) {
    const int k4 = i * 4;
    ushort4 r;
    if (k4 < 3920) {
      const float4 v = *(const float4*)(srow + k4);
      r.x = f2b(v.x); r.y = f2b(v.y); r.z = f2b(v.z); r.w = f2b(v.w);
    } else {
      r.x = 0; r.y = 0; r.z = 0; r.w = 0;
    }
    *(ushort4*)(drow + k4) = r;
  }
}

// ---------------- K4a: gate fc1 partial GEMM (atomic K-split) --------------
__global__ __launch_bounds__(TPB) void k_gate1(
    const ushort* __restrict__ featb, const float* __restrict__ gw1,
    float* __restrict__ graw)
{
  __shared__ float sf[64 * 113];
  __shared__ float sw[64 * 113];
  const int tid = threadIdx.x;
  const int r0 = blockIdx.x * 64;
  const int kz = blockIdx.y;
  const int ty = tid >> 4, tx = tid & 15;
  float acc[4][4] = {{0.f}};
  for (int c = kz; c < 35; c += 8) {
    const int k0 = c * 112;
    for (int i = tid; i < 896; i += TPB) {
      const int row = i / 14, k8 = (i - row * 14) * 8;
      uint4 v = *(const uint4*)(featb + (size_t)(r0 + row) * 4160 + k0 + k8);
      const ushort* pv = (const ushort*)&v;
      float* d = &sf[row * 113 + k8];
#pragma unroll
      for (int t = 0; t < 8; t++) d[t] = bf2f(pv[t]);
    }
    for (int i = tid; i < 1792; i += TPB) {
      const int row = i / 28, c4 = (i - row * 28) * 4;
      float4 u = *(const float4*)(gw1 + (size_t)row * 3920 + k0 + c4);
      float* e = &sw[row * 113 + c4];
      e[0] = u.x; e[1] = u.y; e[2] = u.z; e[3] = u.w;
    }
    __syncthreads();
    for (int k = 0; k < 112; k++) {
      float a_[4], w_[4];
#pragma unroll
      for (int i = 0; i < 4; i++) a_[i] = sf[(ty * 4 + i) * 113 + k];
#pragma unroll
      for (int j = 0; j < 4; j++) w_[j] = sw[(tx * 4 + j) * 113 + k];
#pragma unroll
      for (int i = 0; i < 4; i++)
#pragma unroll
        for (int j = 0; j < 4; j++) acc[i][j] = fmaf(a_[i], w_[j], acc[i][j]);
    }
    __syncthreads();
  }
#pragma unroll
  for (int i = 0; i < 4; i++)
#pragma unroll
    for (int j = 0; j < 4; j++)
      atomicAdd(&graw[(size_t)(r0 + ty * 4 + i) * 64 + tx * 4 + j], acc[i][j]);
}

// ---------------- K4b: gate logits + top2 softmax + expert counts ----------
__global__ __launch_bounds__(TPB) void k_gate2(
    const float* __restrict__ graw, const float* __restrict__ gb1,
    const float* __restrict__ gw2, const float* __restrict__ gb2,
    int* __restrict__ sel0, int* __restrict__ sel1,
    float* __restrict__ wt0, float* __restrict__ wt1, int* __restrict__ counts)
{
  __shared__ float sw2[512], sb1[64], sb2[8];
  const int tid = threadIdx.x;
  for (int i = tid; i < 512; i += TPB) sw2[i] = gw2[i];
  if (tid < 64) sb1[tid] = gb1[tid];
  if (tid < 8) sb2[tid] = gb2[tid];
  __syncthreads();
  const int r = blockIdx.x * TPB + tid;
  float l[8];
#pragma unroll
  for (int c = 0; c < 8; c++) l[c] = sb2[c];
  const float* gr = graw + (size_t)r * 64;
  for (int k = 0; k < 64; k++) {
    const float hv = fmaxf(gr[k] + sb1[k], 0.f);
#pragma unroll
    for (int c = 0; c < 8; c++) l[c] = fmaf(hv, sw2[c * 64 + k], l[c]);
  }
  float v0 = -1e30f, v1 = -1e30f; int i0 = 0, i1 = 0;
#pragma unroll
  for (int c = 0; c < 8; c++) {
    const float lv = l[c];
    if (lv > v0) { v1 = v0; i1 = i0; v0 = lv; i0 = c; }
    else if (lv > v1) { v1 = lv; i1 = c; }
  }
  const float e1 = expf(v1 - v0);
  const float inv = 1.f / (1.f + e1);
  sel0[r] = i0; sel1[r] = i1; wt0[r] = inv; wt1[r] = e1 * inv;
  atomicAdd(&counts[i0], 1);
  atomicAdd(&counts[i1], 1);
}

// ---------------- K5: padded offsets + entry-list init ---------------------
__global__ void k_prep(int* __restrict__ hdrI, int* __restrict__ entrow)
{
  const int tid = threadIdx.x;
  if (tid == 0) {
    int run = 0;
    for (int e = 0; e < 8; e++) {
      const int c = hdrI[e];
      const int pc = (c + 31) & ~31;
      hdrI[16 + e] = pc;
      hdrI[24 + e] = run;
      run += pc;
    }
    hdrI[32] = run;
  }
  if (tid >= 8 && tid < 16) hdrI[tid] = 0;
  for (int i = tid; i < 8448; i += TPB) entrow[i] = -1;
}

// ---------------- K5b: scatter rows to expert entry lists ------------------
__global__ void k_scatter(const int* __restrict__ sel0, const int* __restrict__ sel1,
                          int* __restrict__ hdrI, int* __restrict__ entrow,
                          int* __restrict__ p0, int* __restrict__ p1)
{
  const int r = blockIdx.x * TPB + threadIdx.x;
  const int e0 = sel0[r];
  int pos = atomicAdd(&hdrI[8 + e0], 1) + hdrI[24 + e0];
  entrow[pos] = r; p0[r] = pos;
  const int e1 = sel1[r];
  pos = atomicAdd(&hdrI[8 + e1], 1) + hdrI[24 + e1];
  entrow[pos] = r; p1[r] = pos;
}

// ---------------- K6: dense MFMA fc1 -> h1 bf16 [4096][1024] ---------------
__global__ __launch_bounds__(512) void k_fc1(
    const ushort* __restrict__ featb, const ushort* __restrict__ w1b,
    const float* __restrict__ eb1, __hip_bfloat16* __restrict__ h1b)
{
  __shared__ ushort As[128 * 72];
  __shared__ ushort Bs[128 * 72];
  const int tid = threadIdx.x;
  const int r0 = blockIdx.x * 128;
  const int c0 = blockIdx.y * 128;
  const int w = tid >> 6, lane = tid & 63;
  const int wr = (w >> 1) * 32, wc = (w & 1) * 64;
  const int m = lane & 15, q = lane >> 4;
  f32x4 acc[2][4];
#pragma unroll
  for (int i = 0; i < 2; i++)
#pragma unroll
    for (int j = 0; j < 4; j++) acc[i][j] = 0.f;

  for (int kc = 0; kc < 4096; kc += 64) {
#pragma unroll
    for (int i = 0; i < 2; i++) {
      const int u = tid + 512 * i;
      const int row = u >> 3, k8 = (u & 7) * 8;
      *(uint4*)(&As[row * 72 + k8]) =
          *(const uint4*)(featb + (size_t)(r0 + row) * 4160 + kc + k8);
      *(uint4*)(&Bs[row * 72 + k8]) =
          *(const uint4*)(w1b + (size_t)(c0 + row) * 4160 + kc + k8);
    }
    __syncthreads();
#pragma unroll
    for (int kk = 0; kk < 64; kk += 32) {
      bf16x8 af[2], bf[4];
#pragma unroll
      for (int t = 0; t < 2; t++)
        af[t] = *(const bf16x8*)(&As[(wr + t * 16 + m) * 72 + kk + q * 8]);
#pragma unroll
      for (int t = 0; t < 4; t++)
        bf[t] = *(const bf16x8*)(&Bs[(wc + t * 16 + m) * 72 + kk + q * 8]);
#pragma unroll
      for (int ti = 0; ti < 2; ti++)
#pragma unroll
        for (int tj = 0; tj < 4; tj++)
          acc[ti][tj] = __builtin_amdgcn_mfma_f32_16x16x32_bf16(
              af[ti], bf[tj], acc[ti][tj], 0, 0, 0);
    }
    __syncthreads();
  }
#pragma unroll
  for (int tj = 0; tj < 4; tj++) {
    const int c = c0 + wc + tj * 16 + m;
    const float bb = eb1[c];
#pragma unroll
    for (int ti = 0; ti < 2; ti++) {
      const int rbase = r0 + wr + ti * 16 + q * 4;
#pragma unroll
      for (int i = 0; i < 4; i++) {
        const float v = fmaxf(acc[ti][tj][i] + bb, 0.f);
        h1b[(size_t)(rbase + i) * 1024 + c] = __float2bfloat16(v);
      }
    }
  }
}

// ---------------- K7: dense fc2 -> h2 fp32 [4096][512] ---------------------
__global__ __launch_bounds__(TPB) void k_fc2(
    const __hip_bfloat16* __restrict__ h1b, const float* __restrict__ ew2,
    const float* __restrict__ eb2, float* __restrict__ h2)
{
  __shared__ float h1s[64 * 132];
  __shared__ ushort w2s[128 * 72];
  const int tid = threadIdx.x;
  const int r0 = blockIdx.x * 64;
  const int e = blockIdx.y;
  const ushort* hp = (const ushort*)h1b;
#pragma unroll
  for (int i = 0; i < 4; i++) {
    const int u = tid + 256 * i;
    const int row = u >> 4, k8 = (u & 15) * 8;
    uint4 v = *(const uint4*)(hp + (size_t)(r0 + row) * 1024 + e * 128 + k8);
    const ushort* pv = (const ushort*)&v;
    float* d = &h1s[row * 132 + k8];
#pragma unroll
    for (int t = 0; t < 8; t++) d[t] = bf2f(pv[t]);
  }
#pragma unroll
  for (int i = 0; i < 8; i++) {
    const int u = tid + 256 * i;
    const int nn = u >> 5, k4 = (u & 31) * 4;
    const float4 v = *(const float4*)(ew2 + (size_t)e * 8192 + nn * 128 + k4);
    w2s[(k4 + 0) * 72 + nn] = f2b(v.x);
    w2s[(k4 + 1) * 72 + nn] = f2b(v.y);
    w2s[(k4 + 2) * 72 + nn] = f2b(v.z);
    w2s[(k4 + 3) * 72 + nn] = f2b(v.w);
  }
  __syncthreads();
  const int ty = tid >> 4, tx = tid & 15;
  float acc[4][4] = {{0.f}};
  for (int k4 = 0; k4 < 32; k4++) {
    f32x4 a4[4];
#pragma unroll
    for (int i = 0; i < 4; i++)
      a4[i] = *(const f32x4*)(&h1s[(ty * 4 + i) * 132 + k4 * 4]);
#pragma unroll
    for (int kk = 0; kk < 4; kk++) {
      const ushort4 wu = *(const ushort4*)(&w2s[(k4 * 4 + kk) * 72 + tx * 4]);
      const float w0 = bf2f(wu.x), w1 = bf2f(wu.y);
      const float w2_ = bf2f(wu.z), w3 = bf2f(wu.w);
#pragma unroll
      for (int i = 0; i < 4; i++) {
        acc[i][0] = fmaf(a4[i][kk], w0, acc[i][0]);
        acc[i][1] = fmaf(a4[i][kk], w1, acc[i][1]);
        acc[i][2] = fmaf(a4[i][kk], w2_, acc[i][2]);
        acc[i][3] = fmaf(a4[i][kk], w3, acc[i][3]);
      }
    }
  }
  const f32x4 bb = *(const f32x4*)(eb2 + e * 64 + tx * 4);
#pragma unroll
  for (int i = 0; i < 4; i++) {
    f32x4 r;
#pragma unroll
    for (int j = 0; j < 4; j++) r[j] = fmaxf(acc[i][j] + bb[j], 0.f);
    *(f32x4*)(h2 + (size_t)(r0 + ty * 4 + i) * 512 + e * 64 + tx * 4) = r;
  }
}

// ---------------- K8: grouped fc3 -> eo [pos][1000] ------------------------
__global__ __launch_bounds__(TPB) void k_fc3(
    const float* __restrict__ h2, const float* __restrict__ ew3,
    const float* __restrict__ eb3, const int* __restrict__ hdrI,
    const int* __restrict__ entrow, float* __restrict__ eo)
{
  __shared__ float h2s[32 * 68];
  __shared__ float w3s[64 * 132];
  const int e = blockIdx.y;
  const int pcnt = hdrI[16 + e];
  if ((int)blockIdx.x * 32 >= pcnt) return;
  const int base = hdrI[24 + e] + blockIdx.x * 32;
  const int tid = threadIdx.x;
  for (int i = tid; i < 512; i += TPB) {
    const int row = i >> 4, k4 = (i & 15) * 4;
    const int rr = entrow[base + row];
    f32x4 v = 0.f;
    if (rr >= 0) v = *(const f32x4*)(h2 + (size_t)rr * 512 + e * 64 + k4);
    *(f32x4*)(&h2s[row * 68 + k4]) = v;
  }
  const int ty = tid >> 5, tx = tid & 31;
  const float* w3p = ew3 + (size_t)e * 64000;
  const float* b3p = eb3 + (size_t)e * 1000;
  for (int nc = 0; nc < 8; nc++) {
    const int o0 = nc * 128;
    for (int i = tid; i < 2048; i += TPB) {
      const int oo = i >> 4, k4 = (i & 15) * 4;
      const int o = o0 + oo;
      f32x4 u = 0.f;
      if (o < 1000) u = *(const f32x4*)(w3p + (size_t)o * 64 + k4);
      w3s[(k4 + 0) * 132 + oo] = u[0];
      w3s[(k4 + 1) * 132 + oo] = u[1];
      w3s[(k4 + 2) * 132 + oo] = u[2];
      w3s[(k4 + 3) * 132 + oo] = u[3];
    }
    __syncthreads();
    float acc[4][4] = {{0.f}};
    for (int k4 = 0; k4 < 16; k4++) {
      f32x4 a4[4], w4[4];
#pragma unroll
      for (int i = 0; i < 4; i++)
        a4[i] = *(const f32x4*)(&h2s[(ty * 4 + i) * 68 + k4 * 4]);
#pragma unroll
      for (int kk = 0; kk < 4; kk++)
        w4[kk] = *(const f32x4*)(&w3s[(k4 * 4 + kk) * 132 + tx * 4]);
#pragma unroll
      for (int kk = 0; kk < 4; kk++)
#pragma unroll
        for (int i = 0; i < 4; i++)
#pragma unroll
          for (int j = 0; j < 4; j++)
            acc[i][j] = fmaf(a4[i][kk], w4[kk][j], acc[i][j]);
    }
    const int o = o0 + tx * 4;
    if (o + 3 < 1000) {
      const f32x4 bb = *(const f32x4*)(b3p + o);
#pragma unroll
      for (int i = 0; i < 4; i++) {
        f32x4 r;
#pragma unroll
        for (int j = 0; j < 4; j++) r[j] = acc[i][j] + bb[j];
        *(f32x4*)(eo + (size_t)(base + ty * 4 + i) * 1000 + o) = r;
      }
    }
    __syncthreads();
  }
}

// ---------------- K9: gate-combine + log_softmax(|.|) ----------------------
__global__ __launch_bounds__(TPB) void k_out(
    const float* __restrict__ eo, const int* __restrict__ p0,
    const int* __restrict__ p1, const float* __restrict__ wt0,
    const float* __restrict__ wt1, float* __restrict__ out)
{
  __shared__ float sv[1000];
  __shared__ float sr[8];
  const int r = blockIdx.x, tid = threadIdx.x;
  const float w0 = wt0[r], w1 = wt1[r];
  const float* a = eo + (size_t)p0[r] * 1000;
  const float* b = eo + (size_t)p1[r] * 1000;
  float lmax = -3.4e38f;
  for (int o = tid; o < 1000; o += TPB) {
    const float v = fabsf(w0 * a[o] + w1 * b[o]);
    sv[o] = v;
    lmax = fmaxf(lmax, v);
  }
#pragma unroll
  for (int off = 32; off; off >>= 1) lmax = fmaxf(lmax, __shfl_down(lmax, off));
  if ((tid & 63) == 0) sr[tid >> 6] = lmax;
  __syncthreads();
  const float mx = fmaxf(fmaxf(sr[0], sr[1]), fmaxf(sr[2], sr[3]));
  float lsum = 0.f;
  for (int o = tid; o < 1000; o += TPB) lsum += expf(sv[o] - mx);
#pragma unroll
  for (int off = 32; off; off >>= 1) lsum += __shfl_down(lsum, off);
  if ((tid & 63) == 0) sr[4 + (tid >> 6)] = lsum;
  __syncthreads();
  const float lse = logf(sr[4] + sr[5] + sr[6] + sr[7]);
  const float sub = mx + lse;
  for (int o = tid; o < 1000; o += TPB)
    out[(size_t)r * 1000 + o] = sv[o] - sub;
}

// ---------------------------------------------------------------------------
extern "C" void kernel_launch(void* const* d_in, const int* in_sizes, int n_in,
                              void* d_out, int out_size, void* d_ws, size_t ws_size,
                              hipStream_t stream)
{
  (void)in_sizes; (void)n_in; (void)out_size; (void)ws_size;
  const float* x   = (const float*)d_in[0];
  const float* c1w = (const float*)d_in[1];
  const float* c1b = (const float*)d_in[2];
  const float* bng = (const float*)d_in[3];
  const float* bnb = (const float*)d_in[4];
  const float* c2w = (const float*)d_in[5];
  const float* c2b = (const float*)d_in[6];
  const float* gw1 = (const float*)d_in[7];
  const float* gb1 = (const float*)d_in[8];
  const float* gw2 = (const float*)d_in[9];
  const float* gb2 = (const float*)d_in[10];
  const float* ew1 = (const float*)d_in[11];
  const float* eb1 = (const float*)d_in[12];
  const float* ew2 = (const float*)d_in[13];
  const float* eb2 = (const float*)d_in[14];
  const float* ew3 = (const float*)d_in[15];
  const float* eb3 = (const float*)d_in[16];

  char* ws = (char*)d_ws;
  float* statsF = (float*)ws;
  int*   hdrI   = (int*)(ws + 256);
  int*   sel0   = (int*)(ws + 1024);
  int*   sel1   = (int*)(ws + 17408);
  float* wt0    = (float*)(ws + 33792);
  float* wt1    = (float*)(ws + 50176);
  int*   p0     = (int*)(ws + 66560);
  int*   p1     = (int*)(ws + 82944);
  int*   entrow = (int*)(ws + 99328);
  float* graw   = (float*)(ws + 133120);
  float* eo     = (float*)(ws + 1181696);
  __hip_bfloat16* h1b = (__hip_bfloat16*)(ws + 34973696);
  float* h2     = (float*)(ws + 43362304);
  __hip_bfloat16* pool1 = (__hip_bfloat16*)(ws + 51750912);
  __hip_bfloat16* featb = (__hip_bfloat16*)(ws + 130476032);
  ushort* w1b   = (ushort*)(ws + 164554752);

  hipMemsetAsync(ws, 0, 512, stream);
  hipMemsetAsync(graw, 0, 4096 * 64 * sizeof(float), stream);

  k_castw1 <<<1024, TPB, 0, stream>>>(ew1, w1b);
  k_conv1  <<<4096, TPB, 0, stream>>>(x, c1w, c1b, pool1, statsF);
  k_bnfin  <<<1, 64, 0, stream>>>(bng, bnb, statsF);
  k_conv2  <<<1024, TPB, 0, stream>>>(pool1, statsF, c2w, c2b, featb);
  k_gate1  <<<dim3(64, 8), TPB, 0, stream>>>((const ushort*)featb, gw1, graw);
  k_gate2  <<<16, TPB, 0, stream>>>(graw, gb1, gw2, gb2, sel0, sel1, wt0, wt1, hdrI);
  k_prep   <<<1, TPB, 0, stream>>>(hdrI, entrow);
  k_scatter<<<16, TPB, 0, stream>>>(sel0, sel1, hdrI, entrow, p0, p1);
  k_fc1    <<<dim3(32, 8), 512, 0, stream>>>((const ushort*)featb, w1b, eb1, h1b);
  k_fc2    <<<dim3(64, 8), TPB, 0, stream>>>(h1b, ew2, eb2, h2);
  k_fc3    <<<dim3(128, 8), TPB, 0, stream>>>(h2, ew3, eb3, hdrI, entrow, eo);
  k_out    <<<4096, TPB, 0, stream>>>(eo, p0, p1, wt0, wt1, (float*)d_out);
}